// Round 5
// baseline (5009.476 us; speedup 1.0000x reference)
//
#include <hip/hip_runtime.h>
#include <hip/hip_bf16.h>
#include <cstdint>

#define B_ 32
#define L_ 196
#define D_ 512
#define H_ 512
#define E_ 256
#define T_ 128
#define V_ 512
#define GRID_ 256
#define NBARS 8192
// bars layout (ints): slot(blk)=blk*16 [0..4095] (init grid barrier only);
// per-group lines (gb<32, stride 16): SCORE_ARR 4096, SCORE_REL 4608,
// Z_ARR 5120, Z_REL 5632, H_ARR 6144, H_REL 6656.
#define SCORE_ARR 4096
#define SCORE_REL 4608
#define Z_ARR 5120
#define Z_REL 5632
#define H_ARR 6144
#define H_REL 6656

using u16 = unsigned short;

__device__ __forceinline__ float bf2f(u16 u) { return __uint_as_float(((unsigned)u) << 16); }
__device__ __forceinline__ u16 f2bf(float f) {
    unsigned u = __float_as_uint(f);
    return (u16)((u + 0x7FFFu + ((u >> 16) & 1u)) >> 16);
}
__device__ __forceinline__ float2 bfp(unsigned u) {
    return make_float2(__uint_as_float(u << 16), __uint_as_float(u & 0xffff0000u));
}
__device__ __forceinline__ float sigm(float x) { return 1.f / (1.f + __expf(-x)); }
__device__ __forceinline__ float tanh_fast(float x) { return 1.f - 2.f / (__expf(2.f * x) + 1.f); }

// v_dot2_f32_bf16: acc += a.lo*b.lo + a.hi*b.hi (bf16 pairs, f32 accumulate).
__device__ __forceinline__ void dot2bf(float& acc, unsigned a, unsigned b) {
    asm("v_dot2_f32_bf16 %0, %1, %2, %0" : "+v"(acc) : "v"(a), "v"(b));
}

// --- coherent (cache-bypass) payload access: relaxed agent-scope atomics.
__device__ __forceinline__ float ldcf(const float* p) {
    return __hip_atomic_load((float*)p, __ATOMIC_RELAXED, __HIP_MEMORY_SCOPE_AGENT);
}
__device__ __forceinline__ int ldci(const int* p) {
    return __hip_atomic_load((int*)p, __ATOMIC_RELAXED, __HIP_MEMORY_SCOPE_AGENT);
}
__device__ __forceinline__ unsigned ldc32(const void* p) {
    return __hip_atomic_load((unsigned*)p, __ATOMIC_RELAXED, __HIP_MEMORY_SCOPE_AGENT);
}
__device__ __forceinline__ void stcf(float* p, float v) {
    __hip_atomic_store(p, v, __ATOMIC_RELAXED, __HIP_MEMORY_SCOPE_AGENT);
}
__device__ __forceinline__ void stci(int* p, int v) {
    __hip_atomic_store(p, v, __ATOMIC_RELAXED, __HIP_MEMORY_SCOPE_AGENT);
}
__device__ __forceinline__ void stcu(unsigned* p, unsigned v) {
    __hip_atomic_store(p, v, __ATOMIC_RELAXED, __HIP_MEMORY_SCOPE_AGENT);
}

// ---------------- dtype detect + barrier reset ----------------
__global__ void detect_kernel(const u16* __restrict__ w, int* __restrict__ flg,
                              int* __restrict__ bars) {
    for (int i = threadIdx.x; i < NBARS; i += 64) bars[i] = 0;
    if (threadIdx.x == 0) {
        int cnt = 0;
        for (int i = 0; i < 64; ++i) {
            int e = (w[i] >> 7) & 0xFF;
            cnt += (e >= 100 && e <= 130);
        }
        flg[0] = (cnt >= 56) ? 1 : 0;
    }
}

// ---------------- convert all float tensors to internal bf16 ----------------
struct ConvPtrs { const void* p[19]; };

__global__ __launch_bounds__(256) void conv_kernel(ConvPtrs cp, const int* __restrict__ flg,
                                                   u16* __restrict__ dst) {
    constexpr int NT = 19;
    constexpr unsigned off[NT + 1] = {
        0u, 3211264u, 3227648u, 3244032u, 3506176u, 3506432u, 3539200u, 3539328u,
        3539456u, 5112320u, 6160896u, 6162944u, 6164992u, 6296064u, 6754304u,
        6754664u, 6882832u, 6883192u, 7066488u, 7067000u};
    constexpr unsigned realN[NT] = {
        3211264u, 16384u, 16384u, 262144u, 256u, 32768u, 128u, 128u,
        1572864u, 1048576u, 2048u, 2048u, 131072u, 458240u, 358u,
        128164u, 358u, 183296u, 512u};
    unsigned pos = (blockIdx.x * 256u + threadIdx.x) * 4u;
    if (pos >= off[NT]) return;
    int t = 0;
#pragma unroll
    for (int i = 1; i < NT; ++i) t += (pos >= off[i]);
    unsigned local = pos - off[t];
    int bf = flg[0];
    const void* src = cp.p[t];
    u16* d = dst + off[t];
#pragma unroll
    for (int j = 0; j < 4; ++j) {
        unsigned l = local + j;
        u16 v = 0;
        if (l < realN[t]) v = bf ? ((const u16*)src)[l] : f2bf(((const float*)src)[l]);
        d[l] = v;
    }
}

// ---------------- weight prep: wTk4 (K-pair-major gate weights), w1hT, w2T ----
// wTk4 u32 layout: word ((k8*2048 + col)*4 + w) holds bf16 pair (K=k8*8+2w, +1)
// of gate column col. K order: 0..511 z, 512..767 e, 768..1279 h.
__global__ __launch_bounds__(256) void prep_kernel(const u16* __restrict__ w_ih,
                                                   const u16* __restrict__ w_hh,
                                                   const u16* __restrict__ att_w1,
                                                   const u16* __restrict__ att_w2,
                                                   u16* __restrict__ wTk4,
                                                   u16* __restrict__ w1hT,
                                                   u16* __restrict__ w2T) {
    int c = blockIdx.x, t = threadIdx.x;
    if (c < 2048) {
        if (t < 160) {
            unsigned* dst = (unsigned*)wTk4;
#pragma unroll
            for (int w = 0; w < 4; ++w) {
                int k0 = t * 8 + 2 * w;
                unsigned a = (k0 < 768) ? w_ih[(size_t)k0 * 2048 + c]
                                        : w_hh[(size_t)(k0 - 768) * 2048 + c];
                unsigned b = (k0 + 1 < 768) ? w_ih[(size_t)(k0 + 1) * 2048 + c]
                                            : w_hh[(size_t)(k0 + 1 - 768) * 2048 + c];
                dst[((size_t)t * 2048 + c) * 4 + w] = a | (b << 16);
            }
        }
    } else if (c < 2304) {
        int c2 = c - 2048;
#pragma unroll
        for (int i = 0; i < 2; ++i) {
            int k = i * 256 + t;
            w1hT[(size_t)c2 * 512 + k] = att_w1[(size_t)(512 + k) * 256 + c2];
        }
    } else {
        int c3 = c - 2304;
        w2T[c3 * 256 + t] = att_w2[(size_t)t * 128 + c3];
    }
}

// ---------------- embedding (shifted y) -> hze e-part ----------------
__global__ __launch_bounds__(256) void embed_kernel(const int* __restrict__ y,
                                                    const u16* __restrict__ emb,
                                                    u16* __restrict__ hze) {
    int t = threadIdx.x;
    int row0 = blockIdx.x * 4;
    for (int i = 0; i < 4; ++i) {
        int row = row0 + i;
        int b = row >> 7, tt = row & 127;
        int yin = tt ? y[b * T_ + tt - 1] : 0;
        hze[(size_t)row * 1280 + 1024 + t] = emb[yin * E_ + t];
    }
}

// ---------------- generic tiled GEMM: C = act(A @ Bw + bias) ----------------
template <bool TANH, int OMODE>
__global__ __launch_bounds__(256) void gemm_kernel(const u16* __restrict__ A, int lda,
                                                   const u16* __restrict__ Bw, int ldb,
                                                   const u16* __restrict__ bias,
                                                   void* __restrict__ Cv, int ldc,
                                                   int M, int N, int K,
                                                   const int* __restrict__ flg) {
    __shared__ float As[16][132];
    __shared__ float Bs[16][68];
    int t = threadIdx.x;
    int n0 = blockIdx.x * 64;
    int m0 = blockIdx.y * 128;
    int tx = t & 15, ty = t >> 4;
    float acc[8][4];
#pragma unroll
    for (int i = 0; i < 8; ++i)
#pragma unroll
        for (int j = 0; j < 4; ++j) acc[i][j] = 0.f;

    int ar = t >> 1, akb = (t & 1) * 8;
    int bn = t & 63, bkg = t >> 6;

    for (int k0 = 0; k0 < K; k0 += 16) {
        const u16* Ap = A + (size_t)(m0 + ar) * lda + k0 + akb;
        if (k0 + 16 <= K) {
#pragma unroll
            for (int i = 0; i < 8; ++i) As[akb + i][ar] = bf2f(Ap[i]);
        } else {
#pragma unroll
            for (int i = 0; i < 8; ++i) As[akb + i][ar] = (k0 + akb + i < K) ? bf2f(Ap[i]) : 0.f;
        }
#pragma unroll
        for (int i = 0; i < 4; ++i) {
            int kk = bkg * 4 + i;
            int kg = k0 + kk, ng = n0 + bn;
            Bs[kk][bn] = (kg < K && ng < N) ? bf2f(Bw[(size_t)kg * ldb + ng]) : 0.f;
        }
        __syncthreads();
#pragma unroll
        for (int kk = 0; kk < 16; ++kk) {
            float4 aA = *(const float4*)&As[kk][ty * 8];
            float4 aB = *(const float4*)&As[kk][ty * 8 + 4];
            float4 bv = *(const float4*)&Bs[kk][tx * 4];
            float av[8] = {aA.x, aA.y, aA.z, aA.w, aB.x, aB.y, aB.z, aB.w};
            float bb[4] = {bv.x, bv.y, bv.z, bv.w};
#pragma unroll
            for (int i = 0; i < 8; ++i)
#pragma unroll
                for (int j = 0; j < 4; ++j) acc[i][j] += av[i] * bb[j];
        }
        __syncthreads();
    }
    int obf = (OMODE == 2) ? flg[0] : 1;
    float bb[4];
#pragma unroll
    for (int j = 0; j < 4; ++j) {
        int n = n0 + tx * 4 + j;
        bb[j] = (n < N) ? bf2f(bias[n]) : 0.f;
    }
#pragma unroll
    for (int i = 0; i < 8; ++i) {
        int m = m0 + ty * 8 + i;
#pragma unroll
        for (int j = 0; j < 4; ++j) {
            int n = n0 + tx * 4 + j;
            if (n < N) {
                float v = acc[i][j] + bb[j];
                if (TANH) v = tanhf(v);
                if (OMODE == 1 || obf)
                    ((u16*)Cv)[(size_t)m * ldc + n] = f2bf(v);
                else
                    ((float*)Cv)[(size_t)m * ldc + n] = v;
            }
        }
    }
}

// ---------------- persistent decoder ----------------
struct DecArgs {
    const u16 *h0, *c0, *pre1, *w2T, *att_b2, *att_w3, *w1hT, *wT, *bih, *bhh, *a;
    u16 *hze, *h0b;
    float *s_buf, *c_buf;
    int* bars;
};

// x1p: packed bf16 pairs along K (256 -> 128 u32/row). Stride 136 words: rows
// 16B-aligned; row-groups 4 apart differ by 544 words = 0 mod 32 banks -> only
// the 2 broadcast groups of a wave alias a bank (2-way = free).
struct SA { unsigned x1p[28][136]; float part[28][36]; };
struct SB { float red[256]; float alpha[200]; float zred[64][5]; };
union SU { SA a; SB b; };

// Init-only grid barrier: all-poll. Payload safety: producer's __syncthreads
// drains vmcnt before its slot store; consumers observe all 256 slots >= epoch.
__device__ __forceinline__ void gridbar(int* bars, int blk, int t, int epoch) {
    __syncthreads();
    if (t == 0) stci(&bars[blk << 4], epoch);
    for (;;) {
        int v = ldci(&bars[t << 4]);
        if (__syncthreads_count(v < epoch) == 0) break;
        __builtin_amdgcn_s_sleep(2);
    }
}

// Per-step sync is now entirely GROUP-LOCAL (8 blocks, one XCD): batches are
// independent; each group owns one batch end-to-end. Group barrier = arrival
// fetch_add + release line on an XCD-local L2 cacheline.

__global__ __launch_bounds__(256) void decoder_kernel(DecArgs g) {
    int blk = blockIdx.x, t = threadIdx.x;
    __shared__ SU su;
    __shared__ float w3s[128], b2s[128];
    __shared__ unsigned hsp[256];   // h(t-1) packed bf16 pairs
    __shared__ unsigned einp[128];  // e_t packed pairs
    __shared__ unsigned zinp[256];  // z_t packed pairs
    __shared__ float htvs[256];     // per-column hterm exchange
    __shared__ float gacc[4][68];   // gate partials (i,f,g,o) x 64 dims
    __shared__ float hsh[64];
    __shared__ u16 w2s[128 * 256];  // w2T staged; k-unit (16B) XOR-swizzled by row>>2

    // XCD-aware mapping: group ab = 8 blocks with equal blk%8 -> same XCD.
    int ab = (blk & 7) * 4 + (blk >> 6);
    int ach = (blk >> 3) & 7;
    int abL = ab << 4;

    if (t < 128) {
        w3s[t] = bf2f(g.att_w3[t]);
        b2s[t] = bf2f(g.att_b2[t]);
    }
    // stage w2T (64KB) into LDS: unit u (16B) of row r stored at u ^ (r>>2).
    {
        int r = t >> 1, hf = (t & 1) * 16;
#pragma unroll
        for (int u = hf; u < hf + 16; ++u) {
            *(uint4*)&w2s[(size_t)r * 256 + ((u ^ (r >> 2)) & 31) * 8] =
                *(const uint4*)(g.w2T + (size_t)r * 256 + u * 8);
        }
    }
    // this block owns batch ab, hidden dims [ach*64, ach*64+64), all 4 gates.
    // thread t -> gate q = t>>6, dim j = t&63, gate column col.
    int col = (t >> 6) * 512 + ach * 64 + (t & 63);
    float bsum1 = bf2f(g.bih[col]) + bf2f(g.bhh[col]);
    float creg = (t < 64) ? bf2f(g.c0[ab * 512 + ach * 64 + t]) : 0.f;

    if (blk < 32) {
        unsigned pk = (unsigned)g.h0[blk * 512 + 2 * t] |
                      ((unsigned)g.h0[blk * 512 + 2 * t + 1] << 16);
        stcu((unsigned*)(g.h0b + blk * 512 + 2 * t), pk);
    }

    int anrows = (ach == 7) ? 21 : 25;
    int arow0 = ab * 196 + ach * 25;
    int c2l = (t & 127) * 2, rh = (t >> 7) * 14;  // column-pair / row-half split

    // step-invariant register caches: pre1 (14 rows x 2 adjacent cols packed)
    // and the z-gather `a` values (49 floats, stride-512 column slice).
    unsigned p1p[14];
#pragma unroll
    for (int i = 0; i < 14; ++i) {
        int r = min(arow0 + rh + i, 6271);
        unsigned lo = g.pre1[(size_t)r * 256 + c2l];
        unsigned hi = g.pre1[(size_t)r * 256 + c2l + 1];
        p1p[i] = lo | (hi << 16);
    }
    float areg[49];
    {
        int dl = t >> 2, lq = t & 3;
        const u16* ap = g.a + (size_t)ab * L_ * 512 + ach * 64 + dl;
        int l0 = lq * 49;
#pragma unroll
        for (int li = 0; li < 49; ++li) areg[li] = bf2f(ap[(size_t)(l0 + li) * 512]);
    }
    gridbar(g.bars, blk, t, 1);  // h0b visible; groups now run independently

    const uint4* wb = (const uint4*)g.wT;  // wTk4

    for (int step = 0; step < T_; ++step) {
        int ep = step + 1;
        size_t row = (size_t)ab * T_ + step;
        const u16* hz = g.hze + row * 1280;
        // ================= stage A: staging + hterm + attention scores =========
        const u16* hsrcA = step ? (g.hze + (row - 1) * 1280) : (g.h0b + ab * 512);
        hsp[t] = ldc32(hsrcA + 2 * t);
        if (t < 128) einp[t] = *(const unsigned*)(hz + 1024 + 2 * t);
        __syncthreads();
        float htv;
        {
            float ha0 = 0.f, ha1 = 0.f, ha2 = 0.f, ha3 = 0.f;
            const u16* wp = g.w1hT + (size_t)t * 512;
#pragma unroll 4
            for (int k = 0; k < 512; k += 8) {
                uint4 wv = *(const uint4*)(wp + k);
                uint4 hv = *(const uint4*)&hsp[k >> 1];
                dot2bf(ha0, hv.x, wv.x);
                dot2bf(ha1, hv.y, wv.y);
                dot2bf(ha2, hv.z, wv.z);
                dot2bf(ha3, hv.w, wv.w);
            }
            htv = (ha0 + ha1) + (ha2 + ha3);
        }
        htvs[t] = htv;
        __syncthreads();
        {
            float hv0 = htvs[c2l], hv1 = htvs[c2l + 1];
#pragma unroll
            for (int i = 0; i < 14; ++i) {
                float2 pv = bfp(p1p[i]);
                int r = rh + i;
                unsigned pk = 0u;
                if (r < anrows)
                    pk = (unsigned)f2bf(tanh_fast(pv.x + hv0)) |
                         ((unsigned)f2bf(tanh_fast(pv.y + hv1)) << 16);
                su.a.x1p[r][t & 127] = pk;
            }
        }
        __syncthreads();
        if (t < 224) {
            int r0 = (t >> 5) * 4, c0v = (t & 31) * 4;
            int lswz = t & 31;  // (c0v+j)>>2 for all j
            float acc[4][4];
#pragma unroll
            for (int i = 0; i < 4; ++i)
#pragma unroll
                for (int j = 0; j < 4; ++j) acc[i][j] = 0.f;
            for (int k8 = 0; k8 < 256; k8 += 8) {
                int ru = (((k8 >> 3) ^ lswz) & 31) * 8;
                uint4 wv[4];
#pragma unroll
                for (int j = 0; j < 4; ++j)
                    wv[j] = *(const uint4*)&w2s[(size_t)(c0v + j) * 256 + ru];
                uint4 xv[4];
#pragma unroll
                for (int i = 0; i < 4; ++i)
                    xv[i] = *(const uint4*)&su.a.x1p[r0 + i][k8 >> 1];
#pragma unroll
                for (int j = 0; j < 4; ++j) {
#pragma unroll
                    for (int i = 0; i < 4; ++i) {
                        dot2bf(acc[i][j], xv[i].x, wv[j].x);
                        dot2bf(acc[i][j], xv[i].y, wv[j].y);
                        dot2bf(acc[i][j], xv[i].z, wv[j].z);
                        dot2bf(acc[i][j], xv[i].w, wv[j].w);
                    }
                }
            }
#pragma unroll
            for (int i = 0; i < 4; ++i) {
                float p = 0.f;
#pragma unroll
                for (int j = 0; j < 4; ++j)
                    p += tanh_fast(acc[i][j] + b2s[c0v + j]) * w3s[c0v + j];
                su.a.part[r0 + i][t & 31] = p;
            }
        }
        __syncthreads();
        if (t < anrows) {
            float s = 0.f;
#pragma unroll
            for (int cg = 0; cg < 32; ++cg) s += su.a.part[t][cg];
            stcf(&g.s_buf[arow0 + t], s);  // att_b3 omitted: softmax-invariant
        }
        // --- score-bar post (group) ---
        __syncthreads();
        if (t == 0) {
            int old = __hip_atomic_fetch_add(&g.bars[SCORE_ARR + abL], 1, __ATOMIC_RELAXED,
                                             __HIP_MEMORY_SCOPE_AGENT);
            if (old == ep * 8 - 1) stci(&g.bars[SCORE_REL + abL], ep);
        }
        // --- hidden work: gate-GEMV e and h segments (inputs already in LDS) ---
        float acc4[4] = {0.f, 0.f, 0.f, 0.f};
#pragma unroll 4
        for (int k8 = 0; k8 < 32; ++k8) {
            uint4 wv = wb[(size_t)(64 + k8) * 2048 + col];
            uint4 iv = *(const uint4*)&einp[k8 * 4];
            dot2bf(acc4[0], iv.x, wv.x);
            dot2bf(acc4[1], iv.y, wv.y);
            dot2bf(acc4[2], iv.z, wv.z);
            dot2bf(acc4[3], iv.w, wv.w);
        }
#pragma unroll 4
        for (int k8 = 0; k8 < 64; ++k8) {
            uint4 wv = wb[(size_t)(96 + k8) * 2048 + col];
            uint4 iv = *(const uint4*)&hsp[k8 * 4];
            dot2bf(acc4[0], iv.x, wv.x);
            dot2bf(acc4[1], iv.y, wv.y);
            dot2bf(acc4[2], iv.z, wv.z);
            dot2bf(acc4[3], iv.w, wv.w);
        }
        // --- score-bar wait ---
        if (t == 0) {
            while (ldci(&g.bars[SCORE_REL + abL]) < ep) __builtin_amdgcn_s_sleep(2);
        }
        __syncthreads();
        // ================= stage B: softmax + context z-slice =================
        {
            float v = (t < L_) ? ldcf(&g.s_buf[ab * L_ + t]) : -1e30f;
            float m = v;
#pragma unroll
            for (int off = 32; off > 0; off >>= 1) m = fmaxf(m, __shfl_xor(m, off));
            int wid = t >> 6;
            if ((t & 63) == 0) su.b.red[wid] = m;
            __syncthreads();
            float mx = fmaxf(fmaxf(su.b.red[0], su.b.red[1]),
                             fmaxf(su.b.red[2], su.b.red[3]));
            float e = (t < L_) ? __expf(v - mx) : 0.f;
            float s = e;
#pragma unroll
            for (int off = 32; off > 0; off >>= 1) s += __shfl_xor(s, off);
            if ((t & 63) == 0) su.b.red[4 + wid] = s;
            __syncthreads();
            float inv = 1.f / (((su.b.red[4] + su.b.red[5]) + (su.b.red[6] + su.b.red[7])));
            if (t < L_) su.b.alpha[t] = e * inv;
            __syncthreads();
            int dl = t >> 2, lq = t & 3;
            int l0 = lq * 49;
            float zp0 = 0.f, zp1 = 0.f, zp2 = 0.f, zp3 = 0.f;
#pragma unroll
            for (int li = 0; li < 48; li += 4) {
                zp0 += su.b.alpha[l0 + li] * areg[li];
                zp1 += su.b.alpha[l0 + li + 1] * areg[li + 1];
                zp2 += su.b.alpha[l0 + li + 2] * areg[li + 2];
                zp3 += su.b.alpha[l0 + li + 3] * areg[li + 3];
            }
            zp0 += su.b.alpha[l0 + 48] * areg[48];
            su.b.zred[dl][lq] = (zp0 + zp1) + (zp2 + zp3);
            __syncthreads();
            if (t < 32) {
                float z0 = su.b.zred[2 * t][0] + su.b.zred[2 * t][1] +
                           su.b.zred[2 * t][2] + su.b.zred[2 * t][3];
                float z1 = su.b.zred[2 * t + 1][0] + su.b.zred[2 * t + 1][1] +
                           su.b.zred[2 * t + 1][2] + su.b.zred[2 * t + 1][3];
                unsigned pk = (unsigned)f2bf(z0) | ((unsigned)f2bf(z1) << 16);
                stcu((unsigned*)(hz + 512 + ach * 64 + 2 * t), pk);
            }
        }
        // --- z-bar (group, combined post+wait) ---
        __syncthreads();
        if (t == 0) {
            int old = __hip_atomic_fetch_add(&g.bars[Z_ARR + abL], 1, __ATOMIC_RELAXED,
                                             __HIP_MEMORY_SCOPE_AGENT);
            if (old == ep * 8 - 1) stci(&g.bars[Z_REL + abL], ep);
            while (ldci(&g.bars[Z_REL + abL]) < ep) __builtin_amdgcn_s_sleep(2);
        }
        __syncthreads();
        // ================= stage C: z-segment GEMV + LSTM update ==============
        zinp[t] = ldc32(hz + 512 + 2 * t);
        __syncthreads();
#pragma unroll 4
        for (int k8 = 0; k8 < 64; ++k8) {
            uint4 wv = wb[(size_t)k8 * 2048 + col];
            uint4 iv = *(const uint4*)&zinp[k8 * 4];
            dot2bf(acc4[0], iv.x, wv.x);
            dot2bf(acc4[1], iv.y, wv.y);
            dot2bf(acc4[2], iv.z, wv.z);
            dot2bf(acc4[3], iv.w, wv.w);
        }
        gacc[t >> 6][t & 63] = ((acc4[0] + acc4[1]) + (acc4[2] + acc4[3])) + bsum1;
        __syncthreads();
        if (t < 64) {
            float gi = sigm(gacc[0][t]), gf = sigm(gacc[1][t]);
            float gn = tanh_fast(gacc[2][t]), go = sigm(gacc[3][t]);
            float cn = gf * creg + gi * gn;
            creg = cn;  // c-state lives in a register (block-private)
            hsh[t] = go * tanh_fast(cn);
        }
        __syncthreads();
        if (t < 32) {
            unsigned pk = (unsigned)f2bf(hsh[2 * t]) | ((unsigned)f2bf(hsh[2 * t + 1]) << 16);
            stcu((unsigned*)(hz + ach * 64 + 2 * t), pk);
        }
        // --- h-bar (group); skip at last step ---
        if (step + 1 < T_) {
            __syncthreads();
            if (t == 0) {
                int old = __hip_atomic_fetch_add(&g.bars[H_ARR + abL], 1, __ATOMIC_RELAXED,
                                                 __HIP_MEMORY_SCOPE_AGENT);
                if (old == ep * 8 - 1) stci(&g.bars[H_REL + abL], ep);
                while (ldci(&g.bars[H_REL + abL]) < ep) __builtin_amdgcn_s_sleep(2);
            }
            __syncthreads();
        }
    }
}

extern "C" void kernel_launch(void* const* d_in, const int* in_sizes, int n_in,
                              void* d_out, int out_size, void* d_ws, size_t ws_size,
                              hipStream_t stream) {
    (void)in_sizes; (void)n_in; (void)out_size; (void)ws_size;
    const int* y = (const int*)d_in[3];

    char* base = (char*)d_ws;
    size_t off = 0;
    auto alloc = [&](size_t bytes) {
        void* p = base + off;
        off = (off + bytes + 63) & ~(size_t)63;
        return p;
    };
    // Total footprint ~33.6 MB — must stay <= 34.34 MB (round-2 proven bound).
    int* flg   = (int*)alloc(64);
    int* bars  = (int*)alloc(NBARS * 4);
    u16* conv  = (u16*)alloc((size_t)7067000 * 2);
    u16* pre1  = (u16*)alloc((size_t)6272 * 256 * 2);   // t2 aliases after decoder
    u16* hze   = (u16*)alloc((size_t)4096 * 1280 * 2);
    u16* wTk4  = (u16*)alloc((size_t)2048 * 1280 * 2);  // t1 aliases after decoder
    u16* w1hT  = (u16*)alloc((size_t)256 * 512 * 2);
    u16* w2T   = (u16*)alloc((size_t)128 * 256 * 2);
    u16* h0b   = (u16*)alloc((size_t)32 * 512 * 2);
    float* s_buf = (float*)alloc(32 * 196 * 4);
    float* c_buf = (float*)alloc(32 * 512 * 4);
    u16* t1 = wTk4;  // wTk4 dead after decoder; 5.24MB >= 2.93MB
    u16* t2 = pre1;  // pre1 dead after decoder; 3.21MB >= 2.93MB

    u16* c_a     = conv + 0;
    u16* c_h0    = conv + 3211264;
    u16* c_c0    = conv + 3227648;
    u16* c_attw1 = conv + 3244032;
    u16* c_attb1 = conv + 3506176;
    u16* c_attw2 = conv + 3506432;
    u16* c_attb2 = conv + 3539200;
    u16* c_attw3 = conv + 3539328;
    u16* c_wih   = conv + 3539456;
    u16* c_whh   = conv + 5112320;
    u16* c_bih   = conv + 6160896;
    u16* c_bhh   = conv + 6162944;
    u16* c_emb   = conv + 6164992;
    u16* c_ow1   = conv + 6296064;
    u16* c_ob1   = conv + 6754304;
    u16* c_ow2   = conv + 6754664;
    u16* c_ob2   = conv + 6882832;
    u16* c_ow3   = conv + 6883192;
    u16* c_ob3   = conv + 7066488;

    ConvPtrs cp;
    {
        const int idx[19] = {0, 1, 2, 4, 5, 6, 7, 8, 10, 11, 12, 13, 14, 15, 16, 17, 18, 19, 20};
        for (int i = 0; i < 19; ++i) cp.p[i] = d_in[idx[i]];
    }

    detect_kernel<<<1, 64, 0, stream>>>((const u16*)d_in[4], flg, bars);
    conv_kernel<<<6902, 256, 0, stream>>>(cp, flg, conv);
    prep_kernel<<<2432, 256, 0, stream>>>(c_wih, c_whh, c_attw1, c_attw2, wTk4, w1hT, w2T);
    embed_kernel<<<1024, 256, 0, stream>>>(y, c_emb, hze);
    gemm_kernel<false, 1><<<dim3(4, 49), 256, 0, stream>>>(
        c_a, 512, c_attw1, 256, c_attb1, pre1, 256, 6272, 256, 512, flg);

    DecArgs g;
    g.h0 = c_h0; g.c0 = c_c0; g.pre1 = pre1; g.w2T = w2T; g.att_b2 = c_attb2;
    g.att_w3 = c_attw3; g.w1hT = w1hT; g.wT = wTk4; g.bih = c_bih; g.bhh = c_bhh;
    g.a = c_a; g.hze = hze; g.h0b = h0b; g.s_buf = s_buf; g.c_buf = c_buf; g.bars = bars;
    decoder_kernel<<<GRID_, 256, 0, stream>>>(g);

    gemm_kernel<true, 1><<<dim3(6, 32), 256, 0, stream>>>(
        hze, 1280, c_ow1, 358, c_ob1, t1, 358, 4096, 358, 1280, flg);
    gemm_kernel<true, 1><<<dim3(6, 32), 256, 0, stream>>>(
        t1, 358, c_ow2, 358, c_ob2, t2, 358, 4096, 358, 358, flg);
    gemm_kernel<false, 2><<<dim3(8, 32), 256, 0, stream>>>(
        t2, 358, c_ow3, 512, c_ob3, d_out, 512, 4096, 512, 358, flg);
}

// Round 6
// 4142.219 us; speedup vs baseline: 1.2094x; 1.2094x over previous
//
#include <hip/hip_runtime.h>
#include <hip/hip_bf16.h>
#include <cstdint>

#define B_ 32
#define L_ 196
#define D_ 512
#define H_ 512
#define E_ 256
#define T_ 128
#define V_ 512
#define GRID_ 256
#define NBARS 8192
// bars layout (ints): slot(blk)=blk*16 [0..4095] (init grid barrier only);
// per-group lines (gb<32, stride 16): SCORE_ARR 4096, SCORE_REL 4608,
// Z_ARR 5120, Z_REL 5632, H_ARR 6144, H_REL 6656.
#define SCORE_ARR 4096
#define SCORE_REL 4608
#define Z_ARR 5120
#define Z_REL 5632
#define H_ARR 6144
#define H_REL 6656

using u16 = unsigned short;

__device__ __forceinline__ float bf2f(u16 u) { return __uint_as_float(((unsigned)u) << 16); }
__device__ __forceinline__ u16 f2bf(float f) {
    unsigned u = __float_as_uint(f);
    return (u16)((u + 0x7FFFu + ((u >> 16) & 1u)) >> 16);
}
__device__ __forceinline__ float2 bfp(unsigned u) {
    return make_float2(__uint_as_float(u << 16), __uint_as_float(u & 0xffff0000u));
}
__device__ __forceinline__ float sigm(float x) { return 1.f / (1.f + __expf(-x)); }
__device__ __forceinline__ float tanh_fast(float x) { return 1.f - 2.f / (__expf(2.f * x) + 1.f); }

// v_dot2_f32_bf16: acc += a.lo*b.lo + a.hi*b.hi (bf16 pairs, f32 accumulate).
__device__ __forceinline__ void dot2bf(float& acc, unsigned a, unsigned b) {
    asm("v_dot2_f32_bf16 %0, %1, %2, %0" : "+v"(acc) : "v"(a), "v"(b));
}

// --- coherent (cache-bypass) payload access: relaxed agent-scope atomics.
__device__ __forceinline__ float ldcf(const float* p) {
    return __hip_atomic_load((float*)p, __ATOMIC_RELAXED, __HIP_MEMORY_SCOPE_AGENT);
}
__device__ __forceinline__ int ldci(const int* p) {
    return __hip_atomic_load((int*)p, __ATOMIC_RELAXED, __HIP_MEMORY_SCOPE_AGENT);
}
__device__ __forceinline__ unsigned ldc32(const void* p) {
    return __hip_atomic_load((unsigned*)p, __ATOMIC_RELAXED, __HIP_MEMORY_SCOPE_AGENT);
}
__device__ __forceinline__ void stcf(float* p, float v) {
    __hip_atomic_store(p, v, __ATOMIC_RELAXED, __HIP_MEMORY_SCOPE_AGENT);
}
__device__ __forceinline__ void stci(int* p, int v) {
    __hip_atomic_store(p, v, __ATOMIC_RELAXED, __HIP_MEMORY_SCOPE_AGENT);
}
__device__ __forceinline__ void stcu(unsigned* p, unsigned v) {
    __hip_atomic_store(p, v, __ATOMIC_RELAXED, __HIP_MEMORY_SCOPE_AGENT);
}

// ---------------- dtype detect + barrier reset ----------------
__global__ void detect_kernel(const u16* __restrict__ w, int* __restrict__ flg,
                              int* __restrict__ bars) {
    for (int i = threadIdx.x; i < NBARS; i += 64) bars[i] = 0;
    if (threadIdx.x == 0) {
        int cnt = 0;
        for (int i = 0; i < 64; ++i) {
            int e = (w[i] >> 7) & 0xFF;
            cnt += (e >= 100 && e <= 130);
        }
        flg[0] = (cnt >= 56) ? 1 : 0;
    }
}

// ---------------- convert all float tensors to internal bf16 ----------------
struct ConvPtrs { const void* p[19]; };

__global__ __launch_bounds__(256) void conv_kernel(ConvPtrs cp, const int* __restrict__ flg,
                                                   u16* __restrict__ dst) {
    constexpr int NT = 19;
    constexpr unsigned off[NT + 1] = {
        0u, 3211264u, 3227648u, 3244032u, 3506176u, 3506432u, 3539200u, 3539328u,
        3539456u, 5112320u, 6160896u, 6162944u, 6164992u, 6296064u, 6754304u,
        6754664u, 6882832u, 6883192u, 7066488u, 7067000u};
    constexpr unsigned realN[NT] = {
        3211264u, 16384u, 16384u, 262144u, 256u, 32768u, 128u, 128u,
        1572864u, 1048576u, 2048u, 2048u, 131072u, 458240u, 358u,
        128164u, 358u, 183296u, 512u};
    unsigned pos = (blockIdx.x * 256u + threadIdx.x) * 4u;
    if (pos >= off[NT]) return;
    int t = 0;
#pragma unroll
    for (int i = 1; i < NT; ++i) t += (pos >= off[i]);
    unsigned local = pos - off[t];
    int bf = flg[0];
    const void* src = cp.p[t];
    u16* d = dst + off[t];
#pragma unroll
    for (int j = 0; j < 4; ++j) {
        unsigned l = local + j;
        u16 v = 0;
        if (l < realN[t]) v = bf ? ((const u16*)src)[l] : f2bf(((const float*)src)[l]);
        d[l] = v;
    }
}

// ---------------- weight prep: wTk4 (K-pair-major gate weights), w1hT, w2T ----
// wTk4 u32 layout: word ((k8*2048 + col)*4 + w) holds bf16 pair (K=k8*8+2w, +1)
// of gate column col. K order: 0..511 z, 512..767 e, 768..1279 h.
__global__ __launch_bounds__(256) void prep_kernel(const u16* __restrict__ w_ih,
                                                   const u16* __restrict__ w_hh,
                                                   const u16* __restrict__ att_w1,
                                                   const u16* __restrict__ att_w2,
                                                   u16* __restrict__ wTk4,
                                                   u16* __restrict__ w1hT,
                                                   u16* __restrict__ w2T) {
    int c = blockIdx.x, t = threadIdx.x;
    if (c < 2048) {
        if (t < 160) {
            unsigned* dst = (unsigned*)wTk4;
#pragma unroll
            for (int w = 0; w < 4; ++w) {
                int k0 = t * 8 + 2 * w;
                unsigned a = (k0 < 768) ? w_ih[(size_t)k0 * 2048 + c]
                                        : w_hh[(size_t)(k0 - 768) * 2048 + c];
                unsigned b = (k0 + 1 < 768) ? w_ih[(size_t)(k0 + 1) * 2048 + c]
                                            : w_hh[(size_t)(k0 + 1 - 768) * 2048 + c];
                dst[((size_t)t * 2048 + c) * 4 + w] = a | (b << 16);
            }
        }
    } else if (c < 2304) {
        int c2 = c - 2048;
#pragma unroll
        for (int i = 0; i < 2; ++i) {
            int k = i * 256 + t;
            w1hT[(size_t)c2 * 512 + k] = att_w1[(size_t)(512 + k) * 256 + c2];
        }
    } else {
        int c3 = c - 2304;
        w2T[c3 * 256 + t] = att_w2[(size_t)t * 128 + c3];
    }
}

// ---------------- embedding (shifted y) -> hze e-part ----------------
__global__ __launch_bounds__(256) void embed_kernel(const int* __restrict__ y,
                                                    const u16* __restrict__ emb,
                                                    u16* __restrict__ hze) {
    int t = threadIdx.x;
    int row0 = blockIdx.x * 4;
    for (int i = 0; i < 4; ++i) {
        int row = row0 + i;
        int b = row >> 7, tt = row & 127;
        int yin = tt ? y[b * T_ + tt - 1] : 0;
        hze[(size_t)row * 1280 + 1024 + t] = emb[yin * E_ + t];
    }
}

// ---------------- generic tiled GEMM: C = act(A @ Bw + bias) ----------------
template <bool TANH, int OMODE>
__global__ __launch_bounds__(256) void gemm_kernel(const u16* __restrict__ A, int lda,
                                                   const u16* __restrict__ Bw, int ldb,
                                                   const u16* __restrict__ bias,
                                                   void* __restrict__ Cv, int ldc,
                                                   int M, int N, int K,
                                                   const int* __restrict__ flg) {
    __shared__ float As[16][132];
    __shared__ float Bs[16][68];
    int t = threadIdx.x;
    int n0 = blockIdx.x * 64;
    int m0 = blockIdx.y * 128;
    int tx = t & 15, ty = t >> 4;
    float acc[8][4];
#pragma unroll
    for (int i = 0; i < 8; ++i)
#pragma unroll
        for (int j = 0; j < 4; ++j) acc[i][j] = 0.f;

    int ar = t >> 1, akb = (t & 1) * 8;
    int bn = t & 63, bkg = t >> 6;

    for (int k0 = 0; k0 < K; k0 += 16) {
        const u16* Ap = A + (size_t)(m0 + ar) * lda + k0 + akb;
        if (k0 + 16 <= K) {
#pragma unroll
            for (int i = 0; i < 8; ++i) As[akb + i][ar] = bf2f(Ap[i]);
        } else {
#pragma unroll
            for (int i = 0; i < 8; ++i) As[akb + i][ar] = (k0 + akb + i < K) ? bf2f(Ap[i]) : 0.f;
        }
#pragma unroll
        for (int i = 0; i < 4; ++i) {
            int kk = bkg * 4 + i;
            int kg = k0 + kk, ng = n0 + bn;
            Bs[kk][bn] = (kg < K && ng < N) ? bf2f(Bw[(size_t)kg * ldb + ng]) : 0.f;
        }
        __syncthreads();
#pragma unroll
        for (int kk = 0; kk < 16; ++kk) {
            float4 aA = *(const float4*)&As[kk][ty * 8];
            float4 aB = *(const float4*)&As[kk][ty * 8 + 4];
            float4 bv = *(const float4*)&Bs[kk][tx * 4];
            float av[8] = {aA.x, aA.y, aA.z, aA.w, aB.x, aB.y, aB.z, aB.w};
            float bb[4] = {bv.x, bv.y, bv.z, bv.w};
#pragma unroll
            for (int i = 0; i < 8; ++i)
#pragma unroll
                for (int j = 0; j < 4; ++j) acc[i][j] += av[i] * bb[j];
        }
        __syncthreads();
    }
    int obf = (OMODE == 2) ? flg[0] : 1;
    float bb[4];
#pragma unroll
    for (int j = 0; j < 4; ++j) {
        int n = n0 + tx * 4 + j;
        bb[j] = (n < N) ? bf2f(bias[n]) : 0.f;
    }
#pragma unroll
    for (int i = 0; i < 8; ++i) {
        int m = m0 + ty * 8 + i;
#pragma unroll
        for (int j = 0; j < 4; ++j) {
            int n = n0 + tx * 4 + j;
            if (n < N) {
                float v = acc[i][j] + bb[j];
                if (TANH) v = tanhf(v);
                if (OMODE == 1 || obf)
                    ((u16*)Cv)[(size_t)m * ldc + n] = f2bf(v);
                else
                    ((float*)Cv)[(size_t)m * ldc + n] = v;
            }
        }
    }
}

// ---------------- persistent decoder ----------------
struct DecArgs {
    const u16 *h0, *c0, *pre1, *w2T, *att_b2, *att_w3, *w1hT, *wT, *bih, *bhh, *a;
    u16 *hze, *h0b;
    float *s_buf, *c_buf;
    int* bars;
};

// x1p: packed bf16 pairs along K (256 -> 128 u32/row). Stride 136 words: rows
// 16B-aligned; row-groups 4 apart differ by 544 words = 0 mod 32 banks -> only
// the 2 broadcast groups of a wave alias a bank (2-way = free).
struct SA { unsigned x1p[28][136]; float part[28][36]; };
struct SB { float red[256]; float alpha[200]; float zred[64][5]; };
union SU { SA a; SB b; };

// Init-only grid barrier: all-poll. Payload safety: producer's __syncthreads
// drains vmcnt before its slot store; consumers observe all 256 slots >= epoch.
__device__ __forceinline__ void gridbar(int* bars, int blk, int t, int epoch) {
    __syncthreads();
    if (t == 0) stci(&bars[blk << 4], epoch);
    for (;;) {
        int v = ldci(&bars[t << 4]);
        if (__syncthreads_count(v < epoch) == 0) break;
        __builtin_amdgcn_s_sleep(2);
    }
}

// Per-step sync: GROUP (8 blocks, one per XCD) barriers on LLC lines.
// WEIGHT LOCALITY: ach = blk%8 = XCD id -> all 32 blocks of an XCD read the
// SAME 640KB gate-weight slice (L2-resident, 32x reuse). Round-5's mapping
// (group on one XCD) put the full 5.24MB on every XCD -> L2 thrash -> 2.77GB
// HBM fetch/dispatch. This mapping trades that for cheap 8-way LLC barriers.

__global__ __launch_bounds__(256) void decoder_kernel(DecArgs g) {
    int blk = blockIdx.x, t = threadIdx.x;
    __shared__ SU su;
    __shared__ float w3s[128], b2s[128];
    __shared__ unsigned hsp[256];   // h(t-1) packed bf16 pairs
    __shared__ unsigned einp[128];  // e_t packed pairs
    __shared__ unsigned zinp[256];  // z_t packed pairs
    __shared__ float htvs[256];     // per-column hterm exchange
    __shared__ float gacc[4][68];   // gate partials (i,f,g,o) x 64 dims
    __shared__ float hsh[64];
    __shared__ u16 w2s[128 * 256];  // w2T staged; k-unit (16B) XOR-swizzled by row>>2

    int ab = blk >> 3;   // batch (group of 8 consecutive blocks, one per XCD)
    int ach = blk & 7;   // hidden-dim slice == XCD id (weight L2 locality)
    int abL = ab << 4;

    if (t < 128) {
        w3s[t] = bf2f(g.att_w3[t]);
        b2s[t] = bf2f(g.att_b2[t]);
    }
    // stage w2T (64KB) into LDS: unit u (16B) of row r stored at u ^ (r>>2).
    {
        int r = t >> 1, hf = (t & 1) * 16;
#pragma unroll
        for (int u = hf; u < hf + 16; ++u) {
            *(uint4*)&w2s[(size_t)r * 256 + ((u ^ (r >> 2)) & 31) * 8] =
                *(const uint4*)(g.w2T + (size_t)r * 256 + u * 8);
        }
    }
    // this block owns batch ab, hidden dims [ach*64, ach*64+64), all 4 gates.
    int col = (t >> 6) * 512 + ach * 64 + (t & 63);
    float bsum1 = bf2f(g.bih[col]) + bf2f(g.bhh[col]);
    float creg = (t < 64) ? bf2f(g.c0[ab * 512 + ach * 64 + t]) : 0.f;

    if (blk < 32) {
        unsigned pk = (unsigned)g.h0[blk * 512 + 2 * t] |
                      ((unsigned)g.h0[blk * 512 + 2 * t + 1] << 16);
        stcu((unsigned*)(g.h0b + blk * 512 + 2 * t), pk);
    }

    int anrows = (ach == 7) ? 21 : 25;
    int arow0 = ab * 196 + ach * 25;
    int c2l = (t & 127) * 2, rh = (t >> 7) * 14;  // column-pair / row-half split

    // step-invariant register caches: pre1 (14 rows x 2 adjacent cols packed)
    // and the z-gather `a` values (49 floats, stride-512 column slice).
    unsigned p1p[14];
#pragma unroll
    for (int i = 0; i < 14; ++i) {
        int r = min(arow0 + rh + i, 6271);
        unsigned lo = g.pre1[(size_t)r * 256 + c2l];
        unsigned hi = g.pre1[(size_t)r * 256 + c2l + 1];
        p1p[i] = lo | (hi << 16);
    }
    float areg[49];
    {
        int dl = t >> 2, lq = t & 3;
        const u16* ap = g.a + (size_t)ab * L_ * 512 + ach * 64 + dl;
        int l0 = lq * 49;
#pragma unroll
        for (int li = 0; li < 49; ++li) areg[li] = bf2f(ap[(size_t)(l0 + li) * 512]);
    }
    gridbar(g.bars, blk, t, 1);  // h0b visible; groups now run loosely coupled

    const uint4* wb = (const uint4*)g.wT;  // wTk4
    float acc4[4] = {0.f, 0.f, 0.f, 0.f};

    // prologue: e-GEMV for step 0 (e is static)
    if (t < 128) einp[t] = *(const unsigned*)(g.hze + (size_t)ab * T_ * 1280 + 1024 + 2 * t);
    __syncthreads();
#pragma unroll 4
    for (int k8 = 0; k8 < 32; ++k8) {
        uint4 wv = wb[(size_t)(64 + k8) * 2048 + col];
        uint4 iv = *(const uint4*)&einp[k8 * 4];
        dot2bf(acc4[0], iv.x, wv.x);
        dot2bf(acc4[1], iv.y, wv.y);
        dot2bf(acc4[2], iv.z, wv.z);
        dot2bf(acc4[3], iv.w, wv.w);
    }

    for (int step = 0; step < T_; ++step) {
        int ep = step + 1;
        size_t row = (size_t)ab * T_ + step;
        const u16* hz = g.hze + row * 1280;
        // ================= stage A: staging + hterm + attention scores =========
        const u16* hsrcA = step ? (g.hze + (row - 1) * 1280) : (g.h0b + ab * 512);
        hsp[t] = ldc32(hsrcA + 2 * t);
        __syncthreads();
        float htv;
        {
            float ha0 = 0.f, ha1 = 0.f, ha2 = 0.f, ha3 = 0.f;
            const u16* wp = g.w1hT + (size_t)t * 512;
#pragma unroll 4
            for (int k = 0; k < 512; k += 8) {
                uint4 wv = *(const uint4*)(wp + k);
                uint4 hv = *(const uint4*)&hsp[k >> 1];
                dot2bf(ha0, hv.x, wv.x);
                dot2bf(ha1, hv.y, wv.y);
                dot2bf(ha2, hv.z, wv.z);
                dot2bf(ha3, hv.w, wv.w);
            }
            htv = (ha0 + ha1) + (ha2 + ha3);
        }
        htvs[t] = htv;
        __syncthreads();
        {
            float hv0 = htvs[c2l], hv1 = htvs[c2l + 1];
#pragma unroll
            for (int i = 0; i < 14; ++i) {
                float2 pv = bfp(p1p[i]);
                int r = rh + i;
                unsigned pk = 0u;
                if (r < anrows)
                    pk = (unsigned)f2bf(tanh_fast(pv.x + hv0)) |
                         ((unsigned)f2bf(tanh_fast(pv.y + hv1)) << 16);
                su.a.x1p[r][t & 127] = pk;
            }
        }
        __syncthreads();
        if (t < 224) {
            int r0 = (t >> 5) * 4, c0v = (t & 31) * 4;
            int lswz = t & 31;  // (c0v+j)>>2 for all j
            float acc[4][4];
#pragma unroll
            for (int i = 0; i < 4; ++i)
#pragma unroll
                for (int j = 0; j < 4; ++j) acc[i][j] = 0.f;
            for (int k8 = 0; k8 < 256; k8 += 8) {
                int ru = (((k8 >> 3) ^ lswz) & 31) * 8;
                uint4 wv[4];
#pragma unroll
                for (int j = 0; j < 4; ++j)
                    wv[j] = *(const uint4*)&w2s[(size_t)(c0v + j) * 256 + ru];
                uint4 xv[4];
#pragma unroll
                for (int i = 0; i < 4; ++i)
                    xv[i] = *(const uint4*)&su.a.x1p[r0 + i][k8 >> 1];
#pragma unroll
                for (int j = 0; j < 4; ++j) {
#pragma unroll
                    for (int i = 0; i < 4; ++i) {
                        dot2bf(acc[i][j], xv[i].x, wv[j].x);
                        dot2bf(acc[i][j], xv[i].y, wv[j].y);
                        dot2bf(acc[i][j], xv[i].z, wv[j].z);
                        dot2bf(acc[i][j], xv[i].w, wv[j].w);
                    }
                }
            }
#pragma unroll
            for (int i = 0; i < 4; ++i) {
                float p = 0.f;
#pragma unroll
                for (int j = 0; j < 4; ++j)
                    p += tanh_fast(acc[i][j] + b2s[c0v + j]) * w3s[c0v + j];
                su.a.part[r0 + i][t & 31] = p;
            }
        }
        __syncthreads();
        if (t < anrows) {
            float s = 0.f;
#pragma unroll
            for (int cg = 0; cg < 32; ++cg) s += su.a.part[t][cg];
            stcf(&g.s_buf[arow0 + t], s);  // att_b3 omitted: softmax-invariant
        }
        // --- score-bar post (group) ---
        __syncthreads();
        if (t == 0) {
            int old = __hip_atomic_fetch_add(&g.bars[SCORE_ARR + abL], 1, __ATOMIC_RELAXED,
                                             __HIP_MEMORY_SCOPE_AGENT);
            if (old == ep * 8 - 1) stci(&g.bars[SCORE_REL + abL], ep);
        }
        // --- hidden work: gate-GEMV h segment (L2-resident weights) ---
#pragma unroll 4
        for (int k8 = 0; k8 < 64; ++k8) {
            uint4 wv = wb[(size_t)(96 + k8) * 2048 + col];
            uint4 iv = *(const uint4*)&hsp[k8 * 4];
            dot2bf(acc4[0], iv.x, wv.x);
            dot2bf(acc4[1], iv.y, wv.y);
            dot2bf(acc4[2], iv.z, wv.z);
            dot2bf(acc4[3], iv.w, wv.w);
        }
        // --- score-bar wait ---
        if (t == 0) {
            while (ldci(&g.bars[SCORE_REL + abL]) < ep) __builtin_amdgcn_s_sleep(2);
        }
        __syncthreads();
        // ================= stage B: softmax + context z-slice =================
        {
            float v = (t < L_) ? ldcf(&g.s_buf[ab * L_ + t]) : -1e30f;
            float m = v;
#pragma unroll
            for (int off = 32; off > 0; off >>= 1) m = fmaxf(m, __shfl_xor(m, off));
            int wid = t >> 6;
            if ((t & 63) == 0) su.b.red[wid] = m;
            __syncthreads();
            float mx = fmaxf(fmaxf(su.b.red[0], su.b.red[1]),
                             fmaxf(su.b.red[2], su.b.red[3]));
            float e = (t < L_) ? __expf(v - mx) : 0.f;
            float s = e;
#pragma unroll
            for (int off = 32; off > 0; off >>= 1) s += __shfl_xor(s, off);
            if ((t & 63) == 0) su.b.red[4 + wid] = s;
            __syncthreads();
            float inv = 1.f / (((su.b.red[4] + su.b.red[5]) + (su.b.red[6] + su.b.red[7])));
            if (t < L_) su.b.alpha[t] = e * inv;
            __syncthreads();
            int dl = t >> 2, lq = t & 3;
            int l0 = lq * 49;
            float zp0 = 0.f, zp1 = 0.f, zp2 = 0.f, zp3 = 0.f;
#pragma unroll
            for (int li = 0; li < 48; li += 4) {
                zp0 += su.b.alpha[l0 + li] * areg[li];
                zp1 += su.b.alpha[l0 + li + 1] * areg[li + 1];
                zp2 += su.b.alpha[l0 + li + 2] * areg[li + 2];
                zp3 += su.b.alpha[l0 + li + 3] * areg[li + 3];
            }
            zp0 += su.b.alpha[l0 + 48] * areg[48];
            su.b.zred[dl][lq] = (zp0 + zp1) + (zp2 + zp3);
            __syncthreads();
            if (t < 32) {
                float z0 = su.b.zred[2 * t][0] + su.b.zred[2 * t][1] +
                           su.b.zred[2 * t][2] + su.b.zred[2 * t][3];
                float z1 = su.b.zred[2 * t + 1][0] + su.b.zred[2 * t + 1][1] +
                           su.b.zred[2 * t + 1][2] + su.b.zred[2 * t + 1][3];
                unsigned pk = (unsigned)f2bf(z0) | ((unsigned)f2bf(z1) << 16);
                stcu((unsigned*)(hz + 512 + ach * 64 + 2 * t), pk);
            }
        }
        // --- z-bar (group, combined post+wait) ---
        __syncthreads();
        if (t == 0) {
            int old = __hip_atomic_fetch_add(&g.bars[Z_ARR + abL], 1, __ATOMIC_RELAXED,
                                             __HIP_MEMORY_SCOPE_AGENT);
            if (old == ep * 8 - 1) stci(&g.bars[Z_REL + abL], ep);
            while (ldci(&g.bars[Z_REL + abL]) < ep) __builtin_amdgcn_s_sleep(2);
        }
        __syncthreads();
        // ================= stage C: z-segment GEMV + LSTM update ==============
        zinp[t] = ldc32(hz + 512 + 2 * t);
        __syncthreads();
#pragma unroll 4
        for (int k8 = 0; k8 < 64; ++k8) {
            uint4 wv = wb[(size_t)k8 * 2048 + col];
            uint4 iv = *(const uint4*)&zinp[k8 * 4];
            dot2bf(acc4[0], iv.x, wv.x);
            dot2bf(acc4[1], iv.y, wv.y);
            dot2bf(acc4[2], iv.z, wv.z);
            dot2bf(acc4[3], iv.w, wv.w);
        }
        gacc[t >> 6][t & 63] = ((acc4[0] + acc4[1]) + (acc4[2] + acc4[3])) + bsum1;
        __syncthreads();
        if (t < 64) {
            float gi = sigm(gacc[0][t]), gf = sigm(gacc[1][t]);
            float gn = tanh_fast(gacc[2][t]), go = sigm(gacc[3][t]);
            float cn = gf * creg + gi * gn;
            creg = cn;  // c-state lives in a register (block-private)
            hsh[t] = go * tanh_fast(cn);
        }
        __syncthreads();
        if (t < 32) {
            unsigned pk = (unsigned)f2bf(hsh[2 * t]) | ((unsigned)f2bf(hsh[2 * t + 1]) << 16);
            stcu((unsigned*)(hz + ach * 64 + 2 * t), pk);
        }
        // --- h-bar (group); next step's e-GEMV hidden in the window; skip last ---
        if (step + 1 < T_) {
            __syncthreads();  // drain h stores before arrival
            if (t == 0) {
                int old = __hip_atomic_fetch_add(&g.bars[H_ARR + abL], 1, __ATOMIC_RELAXED,
                                                 __HIP_MEMORY_SCOPE_AGENT);
                if (old == ep * 8 - 1) stci(&g.bars[H_REL + abL], ep);
            }
#pragma unroll
            for (int i = 0; i < 4; ++i) acc4[i] = 0.f;
            if (t < 128) einp[t] = *(const unsigned*)(hz + 1280 + 1024 + 2 * t);
            __syncthreads();
#pragma unroll 4
            for (int k8 = 0; k8 < 32; ++k8) {
                uint4 wv = wb[(size_t)(64 + k8) * 2048 + col];
                uint4 iv = *(const uint4*)&einp[k8 * 4];
                dot2bf(acc4[0], iv.x, wv.x);
                dot2bf(acc4[1], iv.y, wv.y);
                dot2bf(acc4[2], iv.z, wv.z);
                dot2bf(acc4[3], iv.w, wv.w);
            }
            if (t == 0) {
                while (ldci(&g.bars[H_REL + abL]) < ep) __builtin_amdgcn_s_sleep(2);
            }
            __syncthreads();
        }
    }
}

extern "C" void kernel_launch(void* const* d_in, const int* in_sizes, int n_in,
                              void* d_out, int out_size, void* d_ws, size_t ws_size,
                              hipStream_t stream) {
    (void)in_sizes; (void)n_in; (void)out_size; (void)ws_size;
    const int* y = (const int*)d_in[3];

    char* base = (char*)d_ws;
    size_t off = 0;
    auto alloc = [&](size_t bytes) {
        void* p = base + off;
        off = (off + bytes + 63) & ~(size_t)63;
        return p;
    };
    // Total footprint ~33.6 MB — must stay <= 34.34 MB (round-2 proven bound).
    int* flg   = (int*)alloc(64);
    int* bars  = (int*)alloc(NBARS * 4);
    u16* conv  = (u16*)alloc((size_t)7067000 * 2);
    u16* pre1  = (u16*)alloc((size_t)6272 * 256 * 2);   // t2 aliases after decoder
    u16* hze   = (u16*)alloc((size_t)4096 * 1280 * 2);
    u16* wTk4  = (u16*)alloc((size_t)2048 * 1280 * 2);  // t1 aliases after decoder
    u16* w1hT  = (u16*)alloc((size_t)256 * 512 * 2);
    u16* w2T   = (u16*)alloc((size_t)128 * 256 * 2);
    u16* h0b   = (u16*)alloc((size_t)32 * 512 * 2);
    float* s_buf = (float*)alloc(32 * 196 * 4);
    float* c_buf = (float*)alloc(32 * 512 * 4);
    u16* t1 = wTk4;  // wTk4 dead after decoder; 5.24MB >= 2.93MB
    u16* t2 = pre1;  // pre1 dead after decoder; 3.21MB >= 2.93MB

    u16* c_a     = conv + 0;
    u16* c_h0    = conv + 3211264;
    u16* c_c0    = conv + 3227648;
    u16* c_attw1 = conv + 3244032;
    u16* c_attb1 = conv + 3506176;
    u16* c_attw2 = conv + 3506432;
    u16* c_attb2 = conv + 3539200;
    u16* c_attw3 = conv + 3539328;
    u16* c_wih   = conv + 3539456;
    u16* c_whh   = conv + 5112320;
    u16* c_bih   = conv + 6160896;
    u16* c_bhh   = conv + 6162944;
    u16* c_emb   = conv + 6164992;
    u16* c_ow1   = conv + 6296064;
    u16* c_ob1   = conv + 6754304;
    u16* c_ow2   = conv + 6754664;
    u16* c_ob2   = conv + 6882832;
    u16* c_ow3   = conv + 6883192;
    u16* c_ob3   = conv + 7066488;

    ConvPtrs cp;
    {
        const int idx[19] = {0, 1, 2, 4, 5, 6, 7, 8, 10, 11, 12, 13, 14, 15, 16, 17, 18, 19, 20};
        for (int i = 0; i < 19; ++i) cp.p[i] = d_in[idx[i]];
    }

    detect_kernel<<<1, 64, 0, stream>>>((const u16*)d_in[4], flg, bars);
    conv_kernel<<<6902, 256, 0, stream>>>(cp, flg, conv);
    prep_kernel<<<2432, 256, 0, stream>>>(c_wih, c_whh, c_attw1, c_attw2, wTk4, w1hT, w2T);
    embed_kernel<<<1024, 256, 0, stream>>>(y, c_emb, hze);
    gemm_kernel<false, 1><<<dim3(4, 49), 256, 0, stream>>>(
        c_a, 512, c_attw1, 256, c_attb1, pre1, 256, 6272, 256, 512, flg);

    DecArgs g;
    g.h0 = c_h0; g.c0 = c_c0; g.pre1 = pre1; g.w2T = w2T; g.att_b2 = c_attb2;
    g.att_w3 = c_attw3; g.w1hT = w1hT; g.wT = wTk4; g.bih = c_bih; g.bhh = c_bhh;
    g.a = c_a; g.hze = hze; g.h0b = h0b; g.s_buf = s_buf; g.c_buf = c_buf; g.bars = bars;
    decoder_kernel<<<GRID_, 256, 0, stream>>>(g);

    gemm_kernel<true, 1><<<dim3(6, 32), 256, 0, stream>>>(
        hze, 1280, c_ow1, 358, c_ob1, t1, 358, 4096, 358, 1280, flg);
    gemm_kernel<true, 1><<<dim3(6, 32), 256, 0, stream>>>(
        t1, 358, c_ow2, 358, c_ob2, t2, 358, 4096, 358, 358, flg);
    gemm_kernel<false, 2><<<dim3(8, 32), 256, 0, stream>>>(
        t2, 358, c_ow3, 512, c_ob3, d_out, 512, 4096, 512, 358, flg);
}

// Round 7
// 3911.522 us; speedup vs baseline: 1.2807x; 1.0590x over previous
//
#include <hip/hip_runtime.h>
#include <hip/hip_bf16.h>
#include <cstdint>

#define B_ 32
#define L_ 196
#define D_ 512
#define H_ 512
#define E_ 256
#define T_ 128
#define V_ 512
#define GRID_ 256
#define NBARS 8192
// bars layout (ints): slot(blk)=blk*16 [0..4095] (init grid barrier only);
// per-group lines (gb<32, stride 16): ZP_ARR 4096, ZP_REL 4608,
// H_ARR 6144, H_REL 6656.
#define ZP_ARR 4096
#define ZP_REL 4608
#define H_ARR 6144
#define H_REL 6656

using u16 = unsigned short;

__device__ __forceinline__ float bf2f(u16 u) { return __uint_as_float(((unsigned)u) << 16); }
__device__ __forceinline__ u16 f2bf(float f) {
    unsigned u = __float_as_uint(f);
    return (u16)((u + 0x7FFFu + ((u >> 16) & 1u)) >> 16);
}
__device__ __forceinline__ float2 bfp(unsigned u) {
    return make_float2(__uint_as_float(u << 16), __uint_as_float(u & 0xffff0000u));
}
__device__ __forceinline__ float sigm(float x) { return 1.f / (1.f + __expf(-x)); }
__device__ __forceinline__ float tanh_fast(float x) { return 1.f - 2.f / (__expf(2.f * x) + 1.f); }

// v_dot2_f32_bf16: acc += a.lo*b.lo + a.hi*b.hi (bf16 pairs, f32 accumulate).
__device__ __forceinline__ void dot2bf(float& acc, unsigned a, unsigned b) {
    asm("v_dot2_f32_bf16 %0, %1, %2, %0" : "+v"(acc) : "v"(a), "v"(b));
}

// --- coherent (cache-bypass) payload access: relaxed agent-scope atomics.
__device__ __forceinline__ float ldcf(const float* p) {
    return __hip_atomic_load((float*)p, __ATOMIC_RELAXED, __HIP_MEMORY_SCOPE_AGENT);
}
__device__ __forceinline__ int ldci(const int* p) {
    return __hip_atomic_load((int*)p, __ATOMIC_RELAXED, __HIP_MEMORY_SCOPE_AGENT);
}
__device__ __forceinline__ unsigned ldc32(const void* p) {
    return __hip_atomic_load((unsigned*)p, __ATOMIC_RELAXED, __HIP_MEMORY_SCOPE_AGENT);
}
__device__ __forceinline__ double ldc64(const void* p) {
    return __hip_atomic_load((double*)p, __ATOMIC_RELAXED, __HIP_MEMORY_SCOPE_AGENT);
}
__device__ __forceinline__ void stcf(float* p, float v) {
    __hip_atomic_store(p, v, __ATOMIC_RELAXED, __HIP_MEMORY_SCOPE_AGENT);
}
__device__ __forceinline__ void stcd(double* p, double v) {
    __hip_atomic_store(p, v, __ATOMIC_RELAXED, __HIP_MEMORY_SCOPE_AGENT);
}
__device__ __forceinline__ void stci(int* p, int v) {
    __hip_atomic_store(p, v, __ATOMIC_RELAXED, __HIP_MEMORY_SCOPE_AGENT);
}
__device__ __forceinline__ void stcu(unsigned* p, unsigned v) {
    __hip_atomic_store(p, v, __ATOMIC_RELAXED, __HIP_MEMORY_SCOPE_AGENT);
}

// ---------------- dtype detect + barrier reset ----------------
__global__ void detect_kernel(const u16* __restrict__ w, int* __restrict__ flg,
                              int* __restrict__ bars) {
    for (int i = threadIdx.x; i < NBARS; i += 64) bars[i] = 0;
    if (threadIdx.x == 0) {
        int cnt = 0;
        for (int i = 0; i < 64; ++i) {
            int e = (w[i] >> 7) & 0xFF;
            cnt += (e >= 100 && e <= 130);
        }
        flg[0] = (cnt >= 56) ? 1 : 0;
    }
}

// ---------------- convert all float tensors to internal bf16 ----------------
struct ConvPtrs { const void* p[19]; };

__global__ __launch_bounds__(256) void conv_kernel(ConvPtrs cp, const int* __restrict__ flg,
                                                   u16* __restrict__ dst) {
    constexpr int NT = 19;
    constexpr unsigned off[NT + 1] = {
        0u, 3211264u, 3227648u, 3244032u, 3506176u, 3506432u, 3539200u, 3539328u,
        3539456u, 5112320u, 6160896u, 6162944u, 6164992u, 6296064u, 6754304u,
        6754664u, 6882832u, 6883192u, 7066488u, 7067000u};
    constexpr unsigned realN[NT] = {
        3211264u, 16384u, 16384u, 262144u, 256u, 32768u, 128u, 128u,
        1572864u, 1048576u, 2048u, 2048u, 131072u, 458240u, 358u,
        128164u, 358u, 183296u, 512u};
    unsigned pos = (blockIdx.x * 256u + threadIdx.x) * 4u;
    if (pos >= off[NT]) return;
    int t = 0;
#pragma unroll
    for (int i = 1; i < NT; ++i) t += (pos >= off[i]);
    unsigned local = pos - off[t];
    int bf = flg[0];
    const void* src = cp.p[t];
    u16* d = dst + off[t];
#pragma unroll
    for (int j = 0; j < 4; ++j) {
        unsigned l = local + j;
        u16 v = 0;
        if (l < realN[t]) v = bf ? ((const u16*)src)[l] : f2bf(((const float*)src)[l]);
        d[l] = v;
    }
}

// ---------------- weight prep: wTk4 (K-pair-major gate weights), w1hT, w2T ----
// wTk4 u32 layout: word ((k8*2048 + col)*4 + w) holds bf16 pair (K=k8*8+2w, +1)
// of gate column col. K order: 0..511 z, 512..767 e, 768..1279 h.
__global__ __launch_bounds__(256) void prep_kernel(const u16* __restrict__ w_ih,
                                                   const u16* __restrict__ w_hh,
                                                   const u16* __restrict__ att_w1,
                                                   const u16* __restrict__ att_w2,
                                                   u16* __restrict__ wTk4,
                                                   u16* __restrict__ w1hT,
                                                   u16* __restrict__ w2T) {
    int c = blockIdx.x, t = threadIdx.x;
    if (c < 2048) {
        if (t < 160) {
            unsigned* dst = (unsigned*)wTk4;
#pragma unroll
            for (int w = 0; w < 4; ++w) {
                int k0 = t * 8 + 2 * w;
                unsigned a = (k0 < 768) ? w_ih[(size_t)k0 * 2048 + c]
                                        : w_hh[(size_t)(k0 - 768) * 2048 + c];
                unsigned b = (k0 + 1 < 768) ? w_ih[(size_t)(k0 + 1) * 2048 + c]
                                            : w_hh[(size_t)(k0 + 1 - 768) * 2048 + c];
                dst[((size_t)t * 2048 + c) * 4 + w] = a | (b << 16);
            }
        }
    } else if (c < 2304) {
        int c2 = c - 2048;
#pragma unroll
        for (int i = 0; i < 2; ++i) {
            int k = i * 256 + t;
            w1hT[(size_t)c2 * 512 + k] = att_w1[(size_t)(512 + k) * 256 + c2];
        }
    } else {
        int c3 = c - 2304;
        w2T[c3 * 256 + t] = att_w2[(size_t)t * 128 + c3];
    }
}

// ---------------- embedding (shifted y) -> hze e-part ----------------
__global__ __launch_bounds__(256) void embed_kernel(const int* __restrict__ y,
                                                    const u16* __restrict__ emb,
                                                    u16* __restrict__ hze) {
    int t = threadIdx.x;
    int row0 = blockIdx.x * 4;
    for (int i = 0; i < 4; ++i) {
        int row = row0 + i;
        int b = row >> 7, tt = row & 127;
        int yin = tt ? y[b * T_ + tt - 1] : 0;
        hze[(size_t)row * 1280 + 1024 + t] = emb[yin * E_ + t];
    }
}

// ---------------- generic tiled GEMM: C = act(A @ Bw + bias) ----------------
template <bool TANH, int OMODE>
__global__ __launch_bounds__(256) void gemm_kernel(const u16* __restrict__ A, int lda,
                                                   const u16* __restrict__ Bw, int ldb,
                                                   const u16* __restrict__ bias,
                                                   void* __restrict__ Cv, int ldc,
                                                   int M, int N, int K,
                                                   const int* __restrict__ flg) {
    __shared__ float As[16][132];
    __shared__ float Bs[16][68];
    int t = threadIdx.x;
    int n0 = blockIdx.x * 64;
    int m0 = blockIdx.y * 128;
    int tx = t & 15, ty = t >> 4;
    float acc[8][4];
#pragma unroll
    for (int i = 0; i < 8; ++i)
#pragma unroll
        for (int j = 0; j < 4; ++j) acc[i][j] = 0.f;

    int ar = t >> 1, akb = (t & 1) * 8;
    int bn = t & 63, bkg = t >> 6;

    for (int k0 = 0; k0 < K; k0 += 16) {
        const u16* Ap = A + (size_t)(m0 + ar) * lda + k0 + akb;
        if (k0 + 16 <= K) {
#pragma unroll
            for (int i = 0; i < 8; ++i) As[akb + i][ar] = bf2f(Ap[i]);
        } else {
#pragma unroll
            for (int i = 0; i < 8; ++i) As[akb + i][ar] = (k0 + akb + i < K) ? bf2f(Ap[i]) : 0.f;
        }
#pragma unroll
        for (int i = 0; i < 4; ++i) {
            int kk = bkg * 4 + i;
            int kg = k0 + kk, ng = n0 + bn;
            Bs[kk][bn] = (kg < K && ng < N) ? bf2f(Bw[(size_t)kg * ldb + ng]) : 0.f;
        }
        __syncthreads();
#pragma unroll
        for (int kk = 0; kk < 16; ++kk) {
            float4 aA = *(const float4*)&As[kk][ty * 8];
            float4 aB = *(const float4*)&As[kk][ty * 8 + 4];
            float4 bv = *(const float4*)&Bs[kk][tx * 4];
            float av[8] = {aA.x, aA.y, aA.z, aA.w, aB.x, aB.y, aB.z, aB.w};
            float bb[4] = {bv.x, bv.y, bv.z, bv.w};
#pragma unroll
            for (int i = 0; i < 8; ++i)
#pragma unroll
                for (int j = 0; j < 4; ++j) acc[i][j] += av[i] * bb[j];
        }
        __syncthreads();
    }
    int obf = (OMODE == 2) ? flg[0] : 1;
    float bb[4];
#pragma unroll
    for (int j = 0; j < 4; ++j) {
        int n = n0 + tx * 4 + j;
        bb[j] = (n < N) ? bf2f(bias[n]) : 0.f;
    }
#pragma unroll
    for (int i = 0; i < 8; ++i) {
        int m = m0 + ty * 8 + i;
#pragma unroll
        for (int j = 0; j < 4; ++j) {
            int n = n0 + tx * 4 + j;
            if (n < N) {
                float v = acc[i][j] + bb[j];
                if (TANH) v = tanhf(v);
                if (OMODE == 1 || obf)
                    ((u16*)Cv)[(size_t)m * ldc + n] = f2bf(v);
                else
                    ((float*)Cv)[(size_t)m * ldc + n] = v;
            }
        }
    }
}

// ---------------- persistent decoder ----------------
struct DecArgs {
    const u16 *h0, *c0, *pre1, *w2T, *att_b2, *att_w3, *w1hT, *wT, *bih, *bhh, *a;
    u16 *hze, *h0b;
    float *zp;  // partial-z exchange: [32 groups][8 blocks][528] f32 (512 num + den)
    int* bars;
};

// x1p: packed bf16 pairs along K (256 -> 128 u32/row). Stride 136 words: rows
// 16B-aligned; row-groups 4 apart differ by 544 words = 0 mod 32 banks -> only
// the 2 broadcast groups of a wave alias a bank (2-way = free).
struct SA { unsigned x1p[28][136]; float part[28][36]; };

// Init-only grid barrier: all-poll. Payload safety: producer's __syncthreads
// drains vmcnt before its slot store; consumers observe all 256 slots >= epoch.
__device__ __forceinline__ void gridbar(int* bars, int blk, int t, int epoch) {
    __syncthreads();
    if (t == 0) stci(&bars[blk << 4], epoch);
    for (;;) {
        int v = ldci(&bars[t << 4]);
        if (__syncthreads_count(v < epoch) == 0) break;
        __builtin_amdgcn_s_sleep(2);
    }
}

// Per-step sync: 2 group barriers (8 blocks, one per XCD) on LLC lines.
// SOFTMAX FUSION: scores are bounded (|s| <= sum|w3| ~= 2), so exp needs no
// global max. Each block computes exp(s) over its 25 rows and publishes
// PARTIAL z numerator [512] + denominator; one ZP barrier replaces the old
// score-bar + z-bar pair. WEIGHT LOCALITY: ach = blk%8 = XCD id -> all 32
// blocks of an XCD read the same 640KB gate-weight slice (L2-resident).

__global__ __launch_bounds__(256) void decoder_kernel(DecArgs g) {
    int blk = blockIdx.x, t = threadIdx.x;
    __shared__ SA su;
    __shared__ float w3s[128], b2s[128];
    __shared__ unsigned hsp[256];   // h(t-1) packed bf16 pairs
    __shared__ unsigned einp[128];  // e_t packed pairs
    __shared__ unsigned zinp[256];  // z_t packed pairs
    __shared__ float htvs[256];     // per-column hterm exchange
    __shared__ float gacc[4][68];   // gate partials (i,f,g,o) x 64 dims
    __shared__ float hsh[64];
    __shared__ float esh[28];       // exp(score) for this block's rows
    __shared__ float dsh[8];        // partial denominators
    __shared__ u16 w2s[128 * 256];  // w2T staged; k-unit (16B) XOR-swizzled by row>>2

    int ab = blk >> 3;   // batch (group of 8 consecutive blocks, one per XCD)
    int ach = blk & 7;   // hidden-dim slice == XCD id (weight L2 locality)
    int abL = ab << 4;

    if (t < 128) {
        w3s[t] = bf2f(g.att_w3[t]);
        b2s[t] = bf2f(g.att_b2[t]);
    }
    // stage w2T (64KB) into LDS: unit u (16B) of row r stored at u ^ (r>>2).
    {
        int r = t >> 1, hf = (t & 1) * 16;
#pragma unroll
        for (int u = hf; u < hf + 16; ++u) {
            *(uint4*)&w2s[(size_t)r * 256 + ((u ^ (r >> 2)) & 31) * 8] =
                *(const uint4*)(g.w2T + (size_t)r * 256 + u * 8);
        }
    }
    // this block owns batch ab, hidden dims [ach*64, ach*64+64), all 4 gates.
    int col = (t >> 6) * 512 + ach * 64 + (t & 63);
    float bsum1 = bf2f(g.bih[col]) + bf2f(g.bhh[col]);
    float creg = (t < 64) ? bf2f(g.c0[ab * 512 + ach * 64 + t]) : 0.f;

    if (blk < 32) {
        unsigned pk = (unsigned)g.h0[blk * 512 + 2 * t] |
                      ((unsigned)g.h0[blk * 512 + 2 * t + 1] << 16);
        stcu((unsigned*)(g.h0b + blk * 512 + 2 * t), pk);
    }

    int anrows = (ach == 7) ? 21 : 25;
    int arow0 = ab * 196 + ach * 25;
    int c2l = (t & 127) * 2, rh = (t >> 7) * 14;  // column-pair / row-half split

    // step-invariant register caches: pre1 (14 rows x 2 adjacent cols packed)
    // and areg2: a[row, dims 2t..2t+1] for this block's 25 rows (partial-z).
    unsigned p1p[14];
#pragma unroll
    for (int i = 0; i < 14; ++i) {
        int r = min(arow0 + rh + i, 6271);
        unsigned lo = g.pre1[(size_t)r * 256 + c2l];
        unsigned hi = g.pre1[(size_t)r * 256 + c2l + 1];
        p1p[i] = lo | (hi << 16);
    }
    unsigned areg2[25];
#pragma unroll
    for (int r = 0; r < 25; ++r) {
        int rr = min(arow0 + r, 6271);  // clamped rows have esh==0 (no effect)
        areg2[r] = *(const unsigned*)(g.a + (size_t)rr * 512 + 2 * t);
    }
    gridbar(g.bars, blk, t, 1);  // h0b visible; groups now run loosely coupled

    const uint4* wb = (const uint4*)g.wT;  // wTk4
    float* zpb = g.zp + (size_t)(ab * 8 + ach) * 528;
    float acc4[4] = {0.f, 0.f, 0.f, 0.f};

    // prologue: e-GEMV for step 0 (e is static)
    if (t < 128) einp[t] = *(const unsigned*)(g.hze + (size_t)ab * T_ * 1280 + 1024 + 2 * t);
    __syncthreads();
#pragma unroll 4
    for (int k8 = 0; k8 < 32; ++k8) {
        uint4 wv = wb[(size_t)(64 + k8) * 2048 + col];
        uint4 iv = *(const uint4*)&einp[k8 * 4];
        dot2bf(acc4[0], iv.x, wv.x);
        dot2bf(acc4[1], iv.y, wv.y);
        dot2bf(acc4[2], iv.z, wv.z);
        dot2bf(acc4[3], iv.w, wv.w);
    }

    for (int step = 0; step < T_; ++step) {
        int ep = step + 1;
        size_t row = (size_t)ab * T_ + step;
        const u16* hz = g.hze + row * 1280;
        // ================= stage A: staging + hterm + attention scores =========
        const u16* hsrcA = step ? (g.hze + (row - 1) * 1280) : (g.h0b + ab * 512);
        hsp[t] = ldc32(hsrcA + 2 * t);
        __syncthreads();
        float htv;
        {
            float ha0 = 0.f, ha1 = 0.f, ha2 = 0.f, ha3 = 0.f;
            const u16* wp = g.w1hT + (size_t)t * 512;
#pragma unroll 4
            for (int k = 0; k < 512; k += 8) {
                uint4 wv = *(const uint4*)(wp + k);
                uint4 hv = *(const uint4*)&hsp[k >> 1];
                dot2bf(ha0, hv.x, wv.x);
                dot2bf(ha1, hv.y, wv.y);
                dot2bf(ha2, hv.z, wv.z);
                dot2bf(ha3, hv.w, wv.w);
            }
            htv = (ha0 + ha1) + (ha2 + ha3);
        }
        htvs[t] = htv;
        __syncthreads();
        {
            float hv0 = htvs[c2l], hv1 = htvs[c2l + 1];
#pragma unroll
            for (int i = 0; i < 14; ++i) {
                float2 pv = bfp(p1p[i]);
                int r = rh + i;
                unsigned pk = 0u;
                if (r < anrows)
                    pk = (unsigned)f2bf(tanh_fast(pv.x + hv0)) |
                         ((unsigned)f2bf(tanh_fast(pv.y + hv1)) << 16);
                su.x1p[r][t & 127] = pk;
            }
        }
        __syncthreads();
        if (t < 224) {
            int r0 = (t >> 5) * 4, c0v = (t & 31) * 4;
            int lswz = t & 31;  // (c0v+j)>>2 for all j
            float acc[4][4];
#pragma unroll
            for (int i = 0; i < 4; ++i)
#pragma unroll
                for (int j = 0; j < 4; ++j) acc[i][j] = 0.f;
            for (int k8 = 0; k8 < 256; k8 += 8) {
                int ru = (((k8 >> 3) ^ lswz) & 31) * 8;
                uint4 wv[4];
#pragma unroll
                for (int j = 0; j < 4; ++j)
                    wv[j] = *(const uint4*)&w2s[(size_t)(c0v + j) * 256 + ru];
                uint4 xv[4];
#pragma unroll
                for (int i = 0; i < 4; ++i)
                    xv[i] = *(const uint4*)&su.x1p[r0 + i][k8 >> 1];
#pragma unroll
                for (int j = 0; j < 4; ++j) {
#pragma unroll
                    for (int i = 0; i < 4; ++i) {
                        dot2bf(acc[i][j], xv[i].x, wv[j].x);
                        dot2bf(acc[i][j], xv[i].y, wv[j].y);
                        dot2bf(acc[i][j], xv[i].z, wv[j].z);
                        dot2bf(acc[i][j], xv[i].w, wv[j].w);
                    }
                }
            }
#pragma unroll
            for (int i = 0; i < 4; ++i) {
                float p = 0.f;
#pragma unroll
                for (int j = 0; j < 4; ++j)
                    p += tanh_fast(acc[i][j] + b2s[c0v + j]) * w3s[c0v + j];
                su.part[r0 + i][t & 31] = p;
            }
        }
        __syncthreads();
        // scores -> exp (no max: |s| bounded ~2; softmax shift-invariant)
        if (t < 25) {
            float s = 0.f;
            if (t < anrows) {
#pragma unroll
                for (int cg = 0; cg < 32; ++cg) s += su.part[t][cg];
                esh[t] = __expf(s);
            } else {
                esh[t] = 0.f;
            }
        }
        __syncthreads();
        // partial z numerator (dims 2t, 2t+1) + denominator
        {
            float zpx = 0.f, zpy = 0.f, dp = 0.f;
#pragma unroll
            for (int r = 0; r < 25; ++r) {
                float er = esh[r];
                float2 av = bfp(areg2[r]);
                zpx += er * av.x;
                zpy += er * av.y;
                dp += er;
            }
            union { double d; float2 f; } u;
            u.f = make_float2(zpx, zpy);
            stcd((double*)(zpb + 2 * t), u.d);
            if (t == 0) stcf(zpb + 512, dp);
        }
        // --- ZP-bar post (group) ---
        __syncthreads();
        if (t == 0) {
            int old = __hip_atomic_fetch_add(&g.bars[ZP_ARR + abL], 1, __ATOMIC_RELAXED,
                                             __HIP_MEMORY_SCOPE_AGENT);
            if (old == ep * 8 - 1) stci(&g.bars[ZP_REL + abL], ep);
        }
        // --- hidden work: gate-GEMV h segment (L2-resident weights) ---
#pragma unroll 4
        for (int k8 = 0; k8 < 64; ++k8) {
            uint4 wv = wb[(size_t)(96 + k8) * 2048 + col];
            uint4 iv = *(const uint4*)&hsp[k8 * 4];
            dot2bf(acc4[0], iv.x, wv.x);
            dot2bf(acc4[1], iv.y, wv.y);
            dot2bf(acc4[2], iv.z, wv.z);
            dot2bf(acc4[3], iv.w, wv.w);
        }
        // --- ZP-bar wait ---
        if (t == 0) {
            while (ldci(&g.bars[ZP_REL + abL]) < ep) __builtin_amdgcn_s_sleep(2);
        }
        __syncthreads();
        // ================= stage B: combine partials -> z =====================
        {
            if (t < 8) dsh[t] = ldcf(g.zp + (size_t)(ab * 8 + t) * 528 + 512);
            float zx = 0.f, zy = 0.f;
#pragma unroll
            for (int i = 0; i < 8; ++i) {
                union { double d; float2 f; } u;
                u.d = ldc64(g.zp + (size_t)(ab * 8 + i) * 528 + 2 * t);
                zx += u.f.x;
                zy += u.f.y;
            }
            __syncthreads();
            float inv = 1.f / (((dsh[0] + dsh[1]) + (dsh[2] + dsh[3])) +
                               ((dsh[4] + dsh[5]) + (dsh[6] + dsh[7])));
            unsigned pk = (unsigned)f2bf(zx * inv) | ((unsigned)f2bf(zy * inv) << 16);
            zinp[t] = pk;
            if ((t >> 5) == ach) stcu((unsigned*)(hz + 512 + 2 * t), pk);
        }
        __syncthreads();
        // ================= stage C: z-segment GEMV + LSTM update ==============
#pragma unroll 4
        for (int k8 = 0; k8 < 64; ++k8) {
            uint4 wv = wb[(size_t)k8 * 2048 + col];
            uint4 iv = *(const uint4*)&zinp[k8 * 4];
            dot2bf(acc4[0], iv.x, wv.x);
            dot2bf(acc4[1], iv.y, wv.y);
            dot2bf(acc4[2], iv.z, wv.z);
            dot2bf(acc4[3], iv.w, wv.w);
        }
        gacc[t >> 6][t & 63] = ((acc4[0] + acc4[1]) + (acc4[2] + acc4[3])) + bsum1;
        __syncthreads();
        if (t < 64) {
            float gi = sigm(gacc[0][t]), gf = sigm(gacc[1][t]);
            float gn = tanh_fast(gacc[2][t]), go = sigm(gacc[3][t]);
            float cn = gf * creg + gi * gn;
            creg = cn;  // c-state lives in a register (block-private)
            hsh[t] = go * tanh_fast(cn);
        }
        __syncthreads();
        if (t < 32) {
            unsigned pk = (unsigned)f2bf(hsh[2 * t]) | ((unsigned)f2bf(hsh[2 * t + 1]) << 16);
            stcu((unsigned*)(hz + ach * 64 + 2 * t), pk);
        }
        // --- h-bar (group); next step's e-GEMV hidden in the window; skip last ---
        if (step + 1 < T_) {
            __syncthreads();  // drain h stores before arrival
            if (t == 0) {
                int old = __hip_atomic_fetch_add(&g.bars[H_ARR + abL], 1, __ATOMIC_RELAXED,
                                                 __HIP_MEMORY_SCOPE_AGENT);
                if (old == ep * 8 - 1) stci(&g.bars[H_REL + abL], ep);
            }
#pragma unroll
            for (int i = 0; i < 4; ++i) acc4[i] = 0.f;
            if (t < 128) einp[t] = *(const unsigned*)(hz + 1280 + 1024 + 2 * t);
            __syncthreads();
#pragma unroll 4
            for (int k8 = 0; k8 < 32; ++k8) {
                uint4 wv = wb[(size_t)(64 + k8) * 2048 + col];
                uint4 iv = *(const uint4*)&einp[k8 * 4];
                dot2bf(acc4[0], iv.x, wv.x);
                dot2bf(acc4[1], iv.y, wv.y);
                dot2bf(acc4[2], iv.z, wv.z);
                dot2bf(acc4[3], iv.w, wv.w);
            }
            if (t == 0) {
                while (ldci(&g.bars[H_REL + abL]) < ep) __builtin_amdgcn_s_sleep(2);
            }
            __syncthreads();
        }
    }
}

extern "C" void kernel_launch(void* const* d_in, const int* in_sizes, int n_in,
                              void* d_out, int out_size, void* d_ws, size_t ws_size,
                              hipStream_t stream) {
    (void)in_sizes; (void)n_in; (void)out_size; (void)ws_size;
    const int* y = (const int*)d_in[3];

    char* base = (char*)d_ws;
    size_t off = 0;
    auto alloc = [&](size_t bytes) {
        void* p = base + off;
        off = (off + bytes + 63) & ~(size_t)63;
        return p;
    };
    // Total footprint ~34.0 MB — must stay <= 34.34 MB (round-2 proven bound).
    int* flg   = (int*)alloc(64);
    int* bars  = (int*)alloc(NBARS * 4);
    u16* conv  = (u16*)alloc((size_t)7067000 * 2);
    u16* pre1  = (u16*)alloc((size_t)6272 * 256 * 2);   // t2 aliases after decoder
    u16* hze   = (u16*)alloc((size_t)4096 * 1280 * 2);
    u16* wTk4  = (u16*)alloc((size_t)2048 * 1280 * 2);  // t1 aliases after decoder
    u16* w1hT  = (u16*)alloc((size_t)256 * 512 * 2);
    u16* w2T   = (u16*)alloc((size_t)128 * 256 * 2);
    u16* h0b   = (u16*)alloc((size_t)32 * 512 * 2);
    float* zp  = (float*)alloc((size_t)32 * 8 * 528 * 4);  // partial-z exchange
    u16* t1 = wTk4;  // wTk4 dead after decoder; 5.24MB >= 2.93MB
    u16* t2 = pre1;  // pre1 dead after decoder; 3.21MB >= 2.93MB

    u16* c_a     = conv + 0;
    u16* c_h0    = conv + 3211264;
    u16* c_c0    = conv + 3227648;
    u16* c_attw1 = conv + 3244032;
    u16* c_attb1 = conv + 3506176;
    u16* c_attw2 = conv + 3506432;
    u16* c_attb2 = conv + 3539200;
    u16* c_attw3 = conv + 3539328;
    u16* c_wih   = conv + 3539456;
    u16* c_whh   = conv + 5112320;
    u16* c_bih   = conv + 6160896;
    u16* c_bhh   = conv + 6162944;
    u16* c_emb   = conv + 6164992;
    u16* c_ow1   = conv + 6296064;
    u16* c_ob1   = conv + 6754304;
    u16* c_ow2   = conv + 6754664;
    u16* c_ob2   = conv + 6882832;
    u16* c_ow3   = conv + 6883192;
    u16* c_ob3   = conv + 7066488;

    ConvPtrs cp;
    {
        const int idx[19] = {0, 1, 2, 4, 5, 6, 7, 8, 10, 11, 12, 13, 14, 15, 16, 17, 18, 19, 20};
        for (int i = 0; i < 19; ++i) cp.p[i] = d_in[idx[i]];
    }

    detect_kernel<<<1, 64, 0, stream>>>((const u16*)d_in[4], flg, bars);
    conv_kernel<<<6902, 256, 0, stream>>>(cp, flg, conv);
    prep_kernel<<<2432, 256, 0, stream>>>(c_wih, c_whh, c_attw1, c_attw2, wTk4, w1hT, w2T);
    embed_kernel<<<1024, 256, 0, stream>>>(y, c_emb, hze);
    gemm_kernel<false, 1><<<dim3(4, 49), 256, 0, stream>>>(
        c_a, 512, c_attw1, 256, c_attb1, pre1, 256, 6272, 256, 512, flg);

    DecArgs g;
    g.h0 = c_h0; g.c0 = c_c0; g.pre1 = pre1; g.w2T = w2T; g.att_b2 = c_attb2;
    g.att_w3 = c_attw3; g.w1hT = w1hT; g.wT = wTk4; g.bih = c_bih; g.bhh = c_bhh;
    g.a = c_a; g.hze = hze; g.h0b = h0b; g.zp = zp; g.bars = bars;
    decoder_kernel<<<GRID_, 256, 0, stream>>>(g);

    gemm_kernel<true, 1><<<dim3(6, 32), 256, 0, stream>>>(
        hze, 1280, c_ow1, 358, c_ob1, t1, 358, 4096, 358, 1280, flg);
    gemm_kernel<true, 1><<<dim3(6, 32), 256, 0, stream>>>(
        t1, 358, c_ow2, 358, c_ob2, t2, 358, 4096, 358, 358, flg);
    gemm_kernel<false, 2><<<dim3(8, 32), 256, 0, stream>>>(
        t2, 358, c_ow3, 512, c_ob3, d_out, 512, 4096, 512, 358, flg);
}

// Round 8
// 3512.723 us; speedup vs baseline: 1.4261x; 1.1135x over previous
//
#include <hip/hip_runtime.h>
#include <hip/hip_bf16.h>
#include <cstdint>

#define B_ 32
#define L_ 196
#define D_ 512
#define H_ 512
#define E_ 256
#define T_ 128
#define V_ 512
#define GRID_ 256
#define NBARS 8192
// bars layout (ints): slot(blk)=blk*16 [0..4095] (init grid barrier only);
// per-group lines (gb<32, stride 16): ZP_ARR 4096, ZP_REL 4608,
// H_ARR 6144, H_REL 6656.
#define ZP_ARR 4096
#define ZP_REL 4608
#define H_ARR 6144
#define H_REL 6656

using u16 = unsigned short;

__device__ __forceinline__ float bf2f(u16 u) { return __uint_as_float(((unsigned)u) << 16); }
__device__ __forceinline__ u16 f2bf(float f) {
    unsigned u = __float_as_uint(f);
    return (u16)((u + 0x7FFFu + ((u >> 16) & 1u)) >> 16);
}
__device__ __forceinline__ float2 bfp(unsigned u) {
    return make_float2(__uint_as_float(u << 16), __uint_as_float(u & 0xffff0000u));
}
__device__ __forceinline__ float sigm(float x) { return 1.f / (1.f + __expf(-x)); }
__device__ __forceinline__ float tanh_fast(float x) { return 1.f - 2.f / (__expf(2.f * x) + 1.f); }

// v_dot2_f32_bf16: acc += a.lo*b.lo + a.hi*b.hi (bf16 pairs, f32 accumulate).
__device__ __forceinline__ void dot2bf(float& acc, unsigned a, unsigned b) {
    asm("v_dot2_f32_bf16 %0, %1, %2, %0" : "+v"(acc) : "v"(a), "v"(b));
}

// --- coherent (cache-bypass) payload access: relaxed agent-scope atomics.
__device__ __forceinline__ float ldcf(const float* p) {
    return __hip_atomic_load((float*)p, __ATOMIC_RELAXED, __HIP_MEMORY_SCOPE_AGENT);
}
__device__ __forceinline__ int ldci(const int* p) {
    return __hip_atomic_load((int*)p, __ATOMIC_RELAXED, __HIP_MEMORY_SCOPE_AGENT);
}
__device__ __forceinline__ unsigned ldc32(const void* p) {
    return __hip_atomic_load((unsigned*)p, __ATOMIC_RELAXED, __HIP_MEMORY_SCOPE_AGENT);
}
__device__ __forceinline__ double ldc64(const void* p) {
    return __hip_atomic_load((double*)p, __ATOMIC_RELAXED, __HIP_MEMORY_SCOPE_AGENT);
}
__device__ __forceinline__ void stcf(float* p, float v) {
    __hip_atomic_store(p, v, __ATOMIC_RELAXED, __HIP_MEMORY_SCOPE_AGENT);
}
__device__ __forceinline__ void stcd(double* p, double v) {
    __hip_atomic_store(p, v, __ATOMIC_RELAXED, __HIP_MEMORY_SCOPE_AGENT);
}
__device__ __forceinline__ void stci(int* p, int v) {
    __hip_atomic_store(p, v, __ATOMIC_RELAXED, __HIP_MEMORY_SCOPE_AGENT);
}
__device__ __forceinline__ void stcu(unsigned* p, unsigned v) {
    __hip_atomic_store(p, v, __ATOMIC_RELAXED, __HIP_MEMORY_SCOPE_AGENT);
}

// ---------------- dtype detect + barrier reset ----------------
__global__ void detect_kernel(const u16* __restrict__ w, int* __restrict__ flg,
                              int* __restrict__ bars) {
    for (int i = threadIdx.x; i < NBARS; i += 64) bars[i] = 0;
    if (threadIdx.x == 0) {
        int cnt = 0;
        for (int i = 0; i < 64; ++i) {
            int e = (w[i] >> 7) & 0xFF;
            cnt += (e >= 100 && e <= 130);
        }
        flg[0] = (cnt >= 56) ? 1 : 0;
    }
}

// ---------------- convert all float tensors to internal bf16 ----------------
struct ConvPtrs { const void* p[19]; };

__global__ __launch_bounds__(256) void conv_kernel(ConvPtrs cp, const int* __restrict__ flg,
                                                   u16* __restrict__ dst) {
    constexpr int NT = 19;
    constexpr unsigned off[NT + 1] = {
        0u, 3211264u, 3227648u, 3244032u, 3506176u, 3506432u, 3539200u, 3539328u,
        3539456u, 5112320u, 6160896u, 6162944u, 6164992u, 6296064u, 6754304u,
        6754664u, 6882832u, 6883192u, 7066488u, 7067000u};
    constexpr unsigned realN[NT] = {
        3211264u, 16384u, 16384u, 262144u, 256u, 32768u, 128u, 128u,
        1572864u, 1048576u, 2048u, 2048u, 131072u, 458240u, 358u,
        128164u, 358u, 183296u, 512u};
    unsigned pos = (blockIdx.x * 256u + threadIdx.x) * 4u;
    if (pos >= off[NT]) return;
    int t = 0;
#pragma unroll
    for (int i = 1; i < NT; ++i) t += (pos >= off[i]);
    unsigned local = pos - off[t];
    int bf = flg[0];
    const void* src = cp.p[t];
    u16* d = dst + off[t];
#pragma unroll
    for (int j = 0; j < 4; ++j) {
        unsigned l = local + j;
        u16 v = 0;
        if (l < realN[t]) v = bf ? ((const u16*)src)[l] : f2bf(((const float*)src)[l]);
        d[l] = v;
    }
}

// ---------------- weight prep: wTk4 (K-pair-major gate weights), w1hT, w2T ----
// wTk4 u32 layout: word ((k8*2048 + col)*4 + w) holds bf16 pair (K=k8*8+2w, +1)
// of gate column col. K order: 0..511 z, 512..767 e, 768..1279 h.
__global__ __launch_bounds__(256) void prep_kernel(const u16* __restrict__ w_ih,
                                                   const u16* __restrict__ w_hh,
                                                   const u16* __restrict__ att_w1,
                                                   const u16* __restrict__ att_w2,
                                                   u16* __restrict__ wTk4,
                                                   u16* __restrict__ w1hT,
                                                   u16* __restrict__ w2T) {
    int c = blockIdx.x, t = threadIdx.x;
    if (c < 2048) {
        if (t < 160) {
            unsigned* dst = (unsigned*)wTk4;
#pragma unroll
            for (int w = 0; w < 4; ++w) {
                int k0 = t * 8 + 2 * w;
                unsigned a = (k0 < 768) ? w_ih[(size_t)k0 * 2048 + c]
                                        : w_hh[(size_t)(k0 - 768) * 2048 + c];
                unsigned b = (k0 + 1 < 768) ? w_ih[(size_t)(k0 + 1) * 2048 + c]
                                            : w_hh[(size_t)(k0 + 1 - 768) * 2048 + c];
                dst[((size_t)t * 2048 + c) * 4 + w] = a | (b << 16);
            }
        }
    } else if (c < 2304) {
        int c2 = c - 2048;
#pragma unroll
        for (int i = 0; i < 2; ++i) {
            int k = i * 256 + t;
            w1hT[(size_t)c2 * 512 + k] = att_w1[(size_t)(512 + k) * 256 + c2];
        }
    } else {
        int c3 = c - 2304;
        w2T[c3 * 256 + t] = att_w2[(size_t)t * 128 + c3];
    }
}

// ---------------- embedding (shifted y) -> hze e-part ----------------
__global__ __launch_bounds__(256) void embed_kernel(const int* __restrict__ y,
                                                    const u16* __restrict__ emb,
                                                    u16* __restrict__ hze) {
    int t = threadIdx.x;
    int row0 = blockIdx.x * 4;
    for (int i = 0; i < 4; ++i) {
        int row = row0 + i;
        int b = row >> 7, tt = row & 127;
        int yin = tt ? y[b * T_ + tt - 1] : 0;
        hze[(size_t)row * 1280 + 1024 + t] = emb[yin * E_ + t];
    }
}

// ---------------- generic tiled GEMM: C = act(A @ Bw + bias) ----------------
template <bool TANH, int OMODE>
__global__ __launch_bounds__(256) void gemm_kernel(const u16* __restrict__ A, int lda,
                                                   const u16* __restrict__ Bw, int ldb,
                                                   const u16* __restrict__ bias,
                                                   void* __restrict__ Cv, int ldc,
                                                   int M, int N, int K,
                                                   const int* __restrict__ flg) {
    __shared__ float As[16][132];
    __shared__ float Bs[16][68];
    int t = threadIdx.x;
    int n0 = blockIdx.x * 64;
    int m0 = blockIdx.y * 128;
    int tx = t & 15, ty = t >> 4;
    float acc[8][4];
#pragma unroll
    for (int i = 0; i < 8; ++i)
#pragma unroll
        for (int j = 0; j < 4; ++j) acc[i][j] = 0.f;

    int ar = t >> 1, akb = (t & 1) * 8;
    int bn = t & 63, bkg = t >> 6;

    for (int k0 = 0; k0 < K; k0 += 16) {
        const u16* Ap = A + (size_t)(m0 + ar) * lda + k0 + akb;
        if (k0 + 16 <= K) {
#pragma unroll
            for (int i = 0; i < 8; ++i) As[akb + i][ar] = bf2f(Ap[i]);
        } else {
#pragma unroll
            for (int i = 0; i < 8; ++i) As[akb + i][ar] = (k0 + akb + i < K) ? bf2f(Ap[i]) : 0.f;
        }
#pragma unroll
        for (int i = 0; i < 4; ++i) {
            int kk = bkg * 4 + i;
            int kg = k0 + kk, ng = n0 + bn;
            Bs[kk][bn] = (kg < K && ng < N) ? bf2f(Bw[(size_t)kg * ldb + ng]) : 0.f;
        }
        __syncthreads();
#pragma unroll
        for (int kk = 0; kk < 16; ++kk) {
            float4 aA = *(const float4*)&As[kk][ty * 8];
            float4 aB = *(const float4*)&As[kk][ty * 8 + 4];
            float4 bv = *(const float4*)&Bs[kk][tx * 4];
            float av[8] = {aA.x, aA.y, aA.z, aA.w, aB.x, aB.y, aB.z, aB.w};
            float bb[4] = {bv.x, bv.y, bv.z, bv.w};
#pragma unroll
            for (int i = 0; i < 8; ++i)
#pragma unroll
                for (int j = 0; j < 4; ++j) acc[i][j] += av[i] * bb[j];
        }
        __syncthreads();
    }
    int obf = (OMODE == 2) ? flg[0] : 1;
    float bb[4];
#pragma unroll
    for (int j = 0; j < 4; ++j) {
        int n = n0 + tx * 4 + j;
        bb[j] = (n < N) ? bf2f(bias[n]) : 0.f;
    }
#pragma unroll
    for (int i = 0; i < 8; ++i) {
        int m = m0 + ty * 8 + i;
#pragma unroll
        for (int j = 0; j < 4; ++j) {
            int n = n0 + tx * 4 + j;
            if (n < N) {
                float v = acc[i][j] + bb[j];
                if (TANH) v = tanhf(v);
                if (OMODE == 1 || obf)
                    ((u16*)Cv)[(size_t)m * ldc + n] = f2bf(v);
                else
                    ((float*)Cv)[(size_t)m * ldc + n] = v;
            }
        }
    }
}

// ---------------- persistent decoder ----------------
struct DecArgs {
    const u16 *h0, *c0, *pre1, *w2T, *att_b2, *att_w3, *w1hT, *wT, *bih, *bhh, *a;
    u16 *hze, *h0b;
    float *zp;  // partial-z exchange: [32 groups][8 blocks][528] f32 (512 num + den)
    int* bars;
};

// x1p: packed bf16 pairs along K (256 -> 128 u32/row). Stride 136 words: rows
// 16B-aligned; row-groups 4 apart differ by 544 words = 0 mod 32 banks.
struct SA { unsigned x1p[28][136]; float part[28][36]; };

// Init-only grid barrier: all-poll (512 threads poll 256 slots, duplicated).
__device__ __forceinline__ void gridbar(int* bars, int blk, int t, int epoch) {
    __syncthreads();
    if (t == 0) stci(&bars[blk << 4], epoch);
    for (;;) {
        int v = ldci(&bars[(t & 255) << 4]);
        if (__syncthreads_count(v < epoch) == 0) break;
        __builtin_amdgcn_s_sleep(2);
    }
}

// 512-thread blocks (8 waves -> 2 waves/SIMD, double the round-7 occupancy):
// thread halves split every GEMV K-range / GEMM row-range; partials combine in
// LDS (htp, gacc2). Group/barrier/weight-locality structure identical to r7.

__global__ __launch_bounds__(512) void decoder_kernel(DecArgs g) {
    int blk = blockIdx.x, t = threadIdx.x;
    int tt = t & 255, half = t >> 8;
    __shared__ SA su;
    __shared__ float w3s[128], b2s[128], bsh[256];
    __shared__ unsigned hsp[256];   // h(t-1) packed bf16 pairs
    __shared__ unsigned einp[128];  // e_t packed pairs
    __shared__ unsigned zinp[256];  // z_t packed pairs
    __shared__ float htp[512];      // hterm partials [half*256 + col]
    __shared__ float gacc2[2][4][66];  // gate partials per K-half
    __shared__ float hsh[64];
    __shared__ float esh[28];       // exp(score) for this block's rows
    __shared__ float dsh[8];        // partial denominators
    __shared__ u16 w2s[128 * 256];  // w2T staged; k-unit (16B) XOR-swizzled by row>>2

    int ab = blk >> 3;   // batch (group of 8 consecutive blocks, one per XCD)
    int ach = blk & 7;   // hidden-dim slice == XCD id (weight L2 locality)
    int abL = ab << 4;

    if (t < 128) {
        w3s[t] = bf2f(g.att_w3[t]);
        b2s[t] = bf2f(g.att_b2[t]);
    }
    // stage w2T (64KB): 512 threads, 8 units (16B) each; unit u of row r at u^(r>>2).
    {
        int r = t >> 2, q8 = (t & 3) * 8;
#pragma unroll
        for (int u = q8; u < q8 + 8; ++u) {
            *(uint4*)&w2s[(size_t)r * 256 + ((u ^ (r >> 2)) & 31) * 8] =
                *(const uint4*)(g.w2T + (size_t)r * 256 + u * 8);
        }
    }
    // gate column for this thread's half: col, K-half = half.
    int col = (tt >> 6) * 512 + ach * 64 + (tt & 63);
    if (half == 0) bsh[tt] = bf2f(g.bih[col]) + bf2f(g.bhh[col]);
    float creg = (t < 64) ? bf2f(g.c0[ab * 512 + ach * 64 + t]) : 0.f;

    if (blk < 32 && t < 256) {
        unsigned pk = (unsigned)g.h0[blk * 512 + 2 * t] |
                      ((unsigned)g.h0[blk * 512 + 2 * t + 1] << 16);
        stcu((unsigned*)(g.h0b + blk * 512 + 2 * t), pk);
    }

    int anrows = (ach == 7) ? 21 : 25;
    int arow0 = ab * 196 + ach * 25;
    int c2l = (t & 127) * 2, rq = (t >> 7) * 7;  // column-pair / row-quarter split

    // step-invariant register caches: pre1 (7 rows x 2 adjacent cols packed)
    // and areg2: a[row, dims 2tt..2tt+1] for this block's 25 rows (t<256 only).
    unsigned p1p[7];
#pragma unroll
    for (int i = 0; i < 7; ++i) {
        int r = min(arow0 + rq + i, 6271);
        unsigned lo = g.pre1[(size_t)r * 256 + c2l];
        unsigned hi = g.pre1[(size_t)r * 256 + c2l + 1];
        p1p[i] = lo | (hi << 16);
    }
    unsigned areg2[25];
    if (t < 256) {
#pragma unroll
        for (int r = 0; r < 25; ++r) {
            int rr = min(arow0 + r, 6271);  // clamped rows have esh==0 (no effect)
            areg2[r] = *(const unsigned*)(g.a + (size_t)rr * 512 + 2 * t);
        }
    }
    gridbar(g.bars, blk, t, 1);  // h0b visible; groups now run loosely coupled

    const uint4* wb = (const uint4*)g.wT;  // wTk4
    float* zpb = g.zp + (size_t)(ab * 8 + ach) * 528;
    float acc4[4] = {0.f, 0.f, 0.f, 0.f};

    // prologue: e-GEMV for step 0 (e is static); K-half split.
    if (t < 128) einp[t] = *(const unsigned*)(g.hze + (size_t)ab * T_ * 1280 + 1024 + 2 * t);
    __syncthreads();
#pragma unroll 4
    for (int k8 = 0; k8 < 16; ++k8) {
        int ke = half * 16 + k8;
        uint4 wv = wb[(size_t)(64 + ke) * 2048 + col];
        uint4 iv = *(const uint4*)&einp[ke * 4];
        dot2bf(acc4[0], iv.x, wv.x);
        dot2bf(acc4[1], iv.y, wv.y);
        dot2bf(acc4[2], iv.z, wv.z);
        dot2bf(acc4[3], iv.w, wv.w);
    }

    for (int step = 0; step < T_; ++step) {
        int ep = step + 1;
        size_t row = (size_t)ab * T_ + step;
        const u16* hz = g.hze + row * 1280;
        // ================= stage A: staging + hterm + attention scores =========
        const u16* hsrcA = step ? (g.hze + (row - 1) * 1280) : (g.h0b + ab * 512);
        if (t < 256) hsp[t] = ldc32(hsrcA + 2 * t);
        __syncthreads();
        // hterm: column tt, K-half 'half' (256 of 512 K) -> partial in htp[t].
        {
            float ha0 = 0.f, ha1 = 0.f, ha2 = 0.f, ha3 = 0.f;
            const u16* wp = g.w1hT + (size_t)tt * 512 + half * 256;
            const unsigned* hb = &hsp[half * 128];
#pragma unroll 4
            for (int k = 0; k < 256; k += 8) {
                uint4 wv = *(const uint4*)(wp + k);
                uint4 hv = *(const uint4*)&hb[k >> 1];
                dot2bf(ha0, hv.x, wv.x);
                dot2bf(ha1, hv.y, wv.y);
                dot2bf(ha2, hv.z, wv.z);
                dot2bf(ha3, hv.w, wv.w);
            }
            htp[t] = (ha0 + ha1) + (ha2 + ha3);
        }
        __syncthreads();
        {
            float hv0 = htp[c2l] + htp[c2l + 256];
            float hv1 = htp[c2l + 1] + htp[c2l + 257];
#pragma unroll
            for (int i = 0; i < 7; ++i) {
                float2 pv = bfp(p1p[i]);
                int r = rq + i;
                unsigned pk = 0u;
                if (r < anrows)
                    pk = (unsigned)f2bf(tanh_fast(pv.x + hv0)) |
                         ((unsigned)f2bf(tanh_fast(pv.y + hv1)) << 16);
                su.x1p[r][t & 127] = pk;
            }
        }
        __syncthreads();
        // x2 GEMM: 448 threads, 2 rows x 4 cols tiles over k=256.
        if (t < 448) {
            int r0 = (t >> 5) * 2, c0v = (t & 31) * 4;
            int lswz = t & 31;
            float acc[2][4];
#pragma unroll
            for (int i = 0; i < 2; ++i)
#pragma unroll
                for (int j = 0; j < 4; ++j) acc[i][j] = 0.f;
            for (int k8 = 0; k8 < 256; k8 += 8) {
                int ru = (((k8 >> 3) ^ lswz) & 31) * 8;
                uint4 wv[4];
#pragma unroll
                for (int j = 0; j < 4; ++j)
                    wv[j] = *(const uint4*)&w2s[(size_t)(c0v + j) * 256 + ru];
                uint4 xv[2];
#pragma unroll
                for (int i = 0; i < 2; ++i)
                    xv[i] = *(const uint4*)&su.x1p[r0 + i][k8 >> 1];
#pragma unroll
                for (int j = 0; j < 4; ++j) {
#pragma unroll
                    for (int i = 0; i < 2; ++i) {
                        dot2bf(acc[i][j], xv[i].x, wv[j].x);
                        dot2bf(acc[i][j], xv[i].y, wv[j].y);
                        dot2bf(acc[i][j], xv[i].z, wv[j].z);
                        dot2bf(acc[i][j], xv[i].w, wv[j].w);
                    }
                }
            }
#pragma unroll
            for (int i = 0; i < 2; ++i) {
                float p = 0.f;
#pragma unroll
                for (int j = 0; j < 4; ++j)
                    p += tanh_fast(acc[i][j] + b2s[c0v + j]) * w3s[c0v + j];
                su.part[r0 + i][t & 31] = p;
            }
        }
        __syncthreads();
        // scores -> exp (no max: |s| bounded ~2; softmax shift-invariant)
        if (t < 25) {
            float s = 0.f;
            if (t < anrows) {
#pragma unroll
                for (int cg = 0; cg < 32; ++cg) s += su.part[t][cg];
                esh[t] = __expf(s);
            } else {
                esh[t] = 0.f;
            }
        }
        __syncthreads();
        // partial z numerator (dims 2t, 2t+1) + denominator (t<256)
        if (t < 256) {
            float zpx = 0.f, zpy = 0.f, dp = 0.f;
#pragma unroll
            for (int r = 0; r < 25; ++r) {
                float er = esh[r];
                float2 av = bfp(areg2[r]);
                zpx += er * av.x;
                zpy += er * av.y;
                dp += er;
            }
            union { double d; float2 f; } u;
            u.f = make_float2(zpx, zpy);
            stcd((double*)(zpb + 2 * t), u.d);
            if (t == 0) stcf(zpb + 512, dp);
        }
        // --- ZP-bar post (group) ---
        __syncthreads();
        if (t == 0) {
            int old = __hip_atomic_fetch_add(&g.bars[ZP_ARR + abL], 1, __ATOMIC_RELAXED,
                                             __HIP_MEMORY_SCOPE_AGENT);
            if (old == ep * 8 - 1) stci(&g.bars[ZP_REL + abL], ep);
        }
        // --- hidden work: gate-GEMV h segment, K-half split ---
#pragma unroll 4
        for (int k8 = 0; k8 < 32; ++k8) {
            int kh = half * 32 + k8;
            uint4 wv = wb[(size_t)(96 + kh) * 2048 + col];
            uint4 iv = *(const uint4*)&hsp[kh * 4];
            dot2bf(acc4[0], iv.x, wv.x);
            dot2bf(acc4[1], iv.y, wv.y);
            dot2bf(acc4[2], iv.z, wv.z);
            dot2bf(acc4[3], iv.w, wv.w);
        }
        // --- ZP-bar wait ---
        if (t == 0) {
            while (ldci(&g.bars[ZP_REL + abL]) < ep) __builtin_amdgcn_s_sleep(2);
        }
        __syncthreads();
        // ================= stage B: combine partials -> z =====================
        if (t < 8) dsh[t] = ldcf(g.zp + (size_t)(ab * 8 + t) * 528 + 512);
        float zx = 0.f, zy = 0.f;
        if (t < 256) {
#pragma unroll
            for (int i = 0; i < 8; ++i) {
                union { double d; float2 f; } u;
                u.d = ldc64(g.zp + (size_t)(ab * 8 + i) * 528 + 2 * t);
                zx += u.f.x;
                zy += u.f.y;
            }
        }
        __syncthreads();
        if (t < 256) {
            float inv = 1.f / (((dsh[0] + dsh[1]) + (dsh[2] + dsh[3])) +
                               ((dsh[4] + dsh[5]) + (dsh[6] + dsh[7])));
            unsigned pk = (unsigned)f2bf(zx * inv) | ((unsigned)f2bf(zy * inv) << 16);
            zinp[t] = pk;
            if ((t >> 5) == ach) stcu((unsigned*)(hz + 512 + 2 * t), pk);
        }
        __syncthreads();
        // ================= stage C: z-segment GEMV + LSTM update ==============
#pragma unroll 4
        for (int k8 = 0; k8 < 32; ++k8) {
            int kz = half * 32 + k8;
            uint4 wv = wb[(size_t)kz * 2048 + col];
            uint4 iv = *(const uint4*)&zinp[kz * 4];
            dot2bf(acc4[0], iv.x, wv.x);
            dot2bf(acc4[1], iv.y, wv.y);
            dot2bf(acc4[2], iv.z, wv.z);
            dot2bf(acc4[3], iv.w, wv.w);
        }
        gacc2[half][tt >> 6][tt & 63] = (acc4[0] + acc4[1]) + (acc4[2] + acc4[3]);
        __syncthreads();
        if (t < 64) {
            float gg[4];
#pragma unroll
            for (int q = 0; q < 4; ++q)
                gg[q] = gacc2[0][q][t] + gacc2[1][q][t] + bsh[q * 64 + t];
            float gi = sigm(gg[0]), gf = sigm(gg[1]);
            float gn = tanh_fast(gg[2]), go = sigm(gg[3]);
            float cn = gf * creg + gi * gn;
            creg = cn;  // c-state lives in a register (block-private)
            hsh[t] = go * tanh_fast(cn);
        }
        __syncthreads();
        if (t < 32) {
            unsigned pk = (unsigned)f2bf(hsh[2 * t]) | ((unsigned)f2bf(hsh[2 * t + 1]) << 16);
            stcu((unsigned*)(hz + ach * 64 + 2 * t), pk);
        }
        // --- h-bar (group); next step's e-GEMV hidden in the window; skip last ---
        if (step + 1 < T_) {
            __syncthreads();  // drain h stores before arrival
            if (t == 0) {
                int old = __hip_atomic_fetch_add(&g.bars[H_ARR + abL], 1, __ATOMIC_RELAXED,
                                                 __HIP_MEMORY_SCOPE_AGENT);
                if (old == ep * 8 - 1) stci(&g.bars[H_REL + abL], ep);
            }
#pragma unroll
            for (int i = 0; i < 4; ++i) acc4[i] = 0.f;
            if (t < 128) einp[t] = *(const unsigned*)(hz + 1280 + 1024 + 2 * t);
            __syncthreads();
#pragma unroll 4
            for (int k8 = 0; k8 < 16; ++k8) {
                int ke = half * 16 + k8;
                uint4 wv = wb[(size_t)(64 + ke) * 2048 + col];
                uint4 iv = *(const uint4*)&einp[ke * 4];
                dot2bf(acc4[0], iv.x, wv.x);
                dot2bf(acc4[1], iv.y, wv.y);
                dot2bf(acc4[2], iv.z, wv.z);
                dot2bf(acc4[3], iv.w, wv.w);
            }
            if (t == 0) {
                while (ldci(&g.bars[H_REL + abL]) < ep) __builtin_amdgcn_s_sleep(2);
            }
            __syncthreads();
        }
    }
}

extern "C" void kernel_launch(void* const* d_in, const int* in_sizes, int n_in,
                              void* d_out, int out_size, void* d_ws, size_t ws_size,
                              hipStream_t stream) {
    (void)in_sizes; (void)n_in; (void)out_size; (void)ws_size;
    const int* y = (const int*)d_in[3];

    char* base = (char*)d_ws;
    size_t off = 0;
    auto alloc = [&](size_t bytes) {
        void* p = base + off;
        off = (off + bytes + 63) & ~(size_t)63;
        return p;
    };
    // Total footprint ~34.0 MB — must stay <= 34.34 MB (round-2 proven bound).
    int* flg   = (int*)alloc(64);
    int* bars  = (int*)alloc(NBARS * 4);
    u16* conv  = (u16*)alloc((size_t)7067000 * 2);
    u16* pre1  = (u16*)alloc((size_t)6272 * 256 * 2);   // t2 aliases after decoder
    u16* hze   = (u16*)alloc((size_t)4096 * 1280 * 2);
    u16* wTk4  = (u16*)alloc((size_t)2048 * 1280 * 2);  // t1 aliases after decoder
    u16* w1hT  = (u16*)alloc((size_t)256 * 512 * 2);
    u16* w2T   = (u16*)alloc((size_t)128 * 256 * 2);
    u16* h0b   = (u16*)alloc((size_t)32 * 512 * 2);
    float* zp  = (float*)alloc((size_t)32 * 8 * 528 * 4);  // partial-z exchange
    u16* t1 = wTk4;  // wTk4 dead after decoder; 5.24MB >= 2.93MB
    u16* t2 = pre1;  // pre1 dead after decoder; 3.21MB >= 2.93MB

    u16* c_a     = conv + 0;
    u16* c_h0    = conv + 3211264;
    u16* c_c0    = conv + 3227648;
    u16* c_attw1 = conv + 3244032;
    u16* c_attb1 = conv + 3506176;
    u16* c_attw2 = conv + 3506432;
    u16* c_attb2 = conv + 3539200;
    u16* c_attw3 = conv + 3539328;
    u16* c_wih   = conv + 3539456;
    u16* c_whh   = conv + 5112320;
    u16* c_bih   = conv + 6160896;
    u16* c_bhh   = conv + 6162944;
    u16* c_emb   = conv + 6164992;
    u16* c_ow1   = conv + 6296064;
    u16* c_ob1   = conv + 6754304;
    u16* c_ow2   = conv + 6754664;
    u16* c_ob2   = conv + 6882832;
    u16* c_ow3   = conv + 6883192;
    u16* c_ob3   = conv + 7066488;

    ConvPtrs cp;
    {
        const int idx[19] = {0, 1, 2, 4, 5, 6, 7, 8, 10, 11, 12, 13, 14, 15, 16, 17, 18, 19, 20};
        for (int i = 0; i < 19; ++i) cp.p[i] = d_in[idx[i]];
    }

    detect_kernel<<<1, 64, 0, stream>>>((const u16*)d_in[4], flg, bars);
    conv_kernel<<<6902, 256, 0, stream>>>(cp, flg, conv);
    prep_kernel<<<2432, 256, 0, stream>>>(c_wih, c_whh, c_attw1, c_attw2, wTk4, w1hT, w2T);
    embed_kernel<<<1024, 256, 0, stream>>>(y, c_emb, hze);
    gemm_kernel<false, 1><<<dim3(4, 49), 256, 0, stream>>>(
        c_a, 512, c_attw1, 256, c_attb1, pre1, 256, 6272, 256, 512, flg);

    DecArgs g;
    g.h0 = c_h0; g.c0 = c_c0; g.pre1 = pre1; g.w2T = w2T; g.att_b2 = c_attb2;
    g.att_w3 = c_attw3; g.w1hT = w1hT; g.wT = wTk4; g.bih = c_bih; g.bhh = c_bhh;
    g.a = c_a; g.hze = hze; g.h0b = h0b; g.zp = zp; g.bars = bars;
    decoder_kernel<<<GRID_, 512, 0, stream>>>(g);

    gemm_kernel<true, 1><<<dim3(6, 32), 256, 0, stream>>>(
        hze, 1280, c_ow1, 358, c_ob1, t1, 358, 4096, 358, 1280, flg);
    gemm_kernel<true, 1><<<dim3(6, 32), 256, 0, stream>>>(
        t1, 358, c_ow2, 358, c_ob2, t2, 358, 4096, 358, 358, flg);
    gemm_kernel<false, 2><<<dim3(8, 32), 256, 0, stream>>>(
        t2, 358, c_ow3, 512, c_ob3, d_out, 512, 4096, 512, 358, flg);
}

// Round 9
// 3470.411 us; speedup vs baseline: 1.4435x; 1.0122x over previous
//
#include <hip/hip_runtime.h>
#include <hip/hip_bf16.h>
#include <cstdint>

#define B_ 32
#define L_ 196
#define D_ 512
#define H_ 512
#define E_ 256
#define T_ 128
#define V_ 512
#define GRID_ 256
#define NBARS 8192
// bars layout (ints): slot(blk)=blk*16 [0..4095] (init grid barrier only);
// per-group lines (gb<32, stride 16): ZP_ARR 4096, ZP_REL 4608,
// H_ARR 6144, H_REL 6656.
#define ZP_ARR 4096
#define ZP_REL 4608
#define H_ARR 6144
#define H_REL 6656

using u16 = unsigned short;

__device__ __forceinline__ float bf2f(u16 u) { return __uint_as_float(((unsigned)u) << 16); }
__device__ __forceinline__ u16 f2bf(float f) {
    unsigned u = __float_as_uint(f);
    return (u16)((u + 0x7FFFu + ((u >> 16) & 1u)) >> 16);
}
__device__ __forceinline__ float2 bfp(unsigned u) {
    return make_float2(__uint_as_float(u << 16), __uint_as_float(u & 0xffff0000u));
}
__device__ __forceinline__ float sigm(float x) { return 1.f / (1.f + __expf(-x)); }
__device__ __forceinline__ float tanh_fast(float x) { return 1.f - 2.f / (__expf(2.f * x) + 1.f); }

// v_dot2_f32_bf16: acc += a.lo*b.lo + a.hi*b.hi (bf16 pairs, f32 accumulate).
__device__ __forceinline__ void dot2bf(float& acc, unsigned a, unsigned b) {
    asm("v_dot2_f32_bf16 %0, %1, %2, %0" : "+v"(acc) : "v"(a), "v"(b));
}

// --- coherent (cache-bypass) payload access: relaxed agent-scope atomics.
__device__ __forceinline__ float ldcf(const float* p) {
    return __hip_atomic_load((float*)p, __ATOMIC_RELAXED, __HIP_MEMORY_SCOPE_AGENT);
}
__device__ __forceinline__ int ldci(const int* p) {
    return __hip_atomic_load((int*)p, __ATOMIC_RELAXED, __HIP_MEMORY_SCOPE_AGENT);
}
__device__ __forceinline__ unsigned ldc32(const void* p) {
    return __hip_atomic_load((unsigned*)p, __ATOMIC_RELAXED, __HIP_MEMORY_SCOPE_AGENT);
}
__device__ __forceinline__ double ldc64(const void* p) {
    return __hip_atomic_load((double*)p, __ATOMIC_RELAXED, __HIP_MEMORY_SCOPE_AGENT);
}
__device__ __forceinline__ void stcf(float* p, float v) {
    __hip_atomic_store(p, v, __ATOMIC_RELAXED, __HIP_MEMORY_SCOPE_AGENT);
}
__device__ __forceinline__ void stci(int* p, int v) {
    __hip_atomic_store(p, v, __ATOMIC_RELAXED, __HIP_MEMORY_SCOPE_AGENT);
}
__device__ __forceinline__ void stcu(unsigned* p, unsigned v) {
    __hip_atomic_store(p, v, __ATOMIC_RELAXED, __HIP_MEMORY_SCOPE_AGENT);
}
__device__ __forceinline__ void atadd(float* p, float v) {
    __hip_atomic_fetch_add(p, v, __ATOMIC_RELAXED, __HIP_MEMORY_SCOPE_AGENT);
}

// ---------------- dtype detect + barrier reset ----------------
__global__ void detect_kernel(const u16* __restrict__ w, int* __restrict__ flg,
                              int* __restrict__ bars) {
    for (int i = threadIdx.x; i < NBARS; i += 64) bars[i] = 0;
    if (threadIdx.x == 0) {
        int cnt = 0;
        for (int i = 0; i < 64; ++i) {
            int e = (w[i] >> 7) & 0xFF;
            cnt += (e >= 100 && e <= 130);
        }
        flg[0] = (cnt >= 56) ? 1 : 0;
    }
}

// ---------------- convert all float tensors to internal bf16 ----------------
struct ConvPtrs { const void* p[19]; };

__global__ __launch_bounds__(256) void conv_kernel(ConvPtrs cp, const int* __restrict__ flg,
                                                   u16* __restrict__ dst) {
    constexpr int NT = 19;
    constexpr unsigned off[NT + 1] = {
        0u, 3211264u, 3227648u, 3244032u, 3506176u, 3506432u, 3539200u, 3539328u,
        3539456u, 5112320u, 6160896u, 6162944u, 6164992u, 6296064u, 6754304u,
        6754664u, 6882832u, 6883192u, 7066488u, 7067000u};
    constexpr unsigned realN[NT] = {
        3211264u, 16384u, 16384u, 262144u, 256u, 32768u, 128u, 128u,
        1572864u, 1048576u, 2048u, 2048u, 131072u, 458240u, 358u,
        128164u, 358u, 183296u, 512u};
    unsigned pos = (blockIdx.x * 256u + threadIdx.x) * 4u;
    if (pos >= off[NT]) return;
    int t = 0;
#pragma unroll
    for (int i = 1; i < NT; ++i) t += (pos >= off[i]);
    unsigned local = pos - off[t];
    int bf = flg[0];
    const void* src = cp.p[t];
    u16* d = dst + off[t];
#pragma unroll
    for (int j = 0; j < 4; ++j) {
        unsigned l = local + j;
        u16 v = 0;
        if (l < realN[t]) v = bf ? ((const u16*)src)[l] : f2bf(((const float*)src)[l]);
        d[l] = v;
    }
}

// ---------------- weight prep: wTk4 (K-pair-major gate weights), w1hT, w2T ----
// wTk4 u32 layout: word ((k8*2048 + col)*4 + w) holds bf16 pair (K=k8*8+2w, +1)
// of gate column col. K order: 0..511 z, 512..767 e, 768..1279 h.
__global__ __launch_bounds__(256) void prep_kernel(const u16* __restrict__ w_ih,
                                                   const u16* __restrict__ w_hh,
                                                   const u16* __restrict__ att_w1,
                                                   const u16* __restrict__ att_w2,
                                                   u16* __restrict__ wTk4,
                                                   u16* __restrict__ w1hT,
                                                   u16* __restrict__ w2T) {
    int c = blockIdx.x, t = threadIdx.x;
    if (c < 2048) {
        if (t < 160) {
            unsigned* dst = (unsigned*)wTk4;
#pragma unroll
            for (int w = 0; w < 4; ++w) {
                int k0 = t * 8 + 2 * w;
                unsigned a = (k0 < 768) ? w_ih[(size_t)k0 * 2048 + c]
                                        : w_hh[(size_t)(k0 - 768) * 2048 + c];
                unsigned b = (k0 + 1 < 768) ? w_ih[(size_t)(k0 + 1) * 2048 + c]
                                            : w_hh[(size_t)(k0 + 1 - 768) * 2048 + c];
                dst[((size_t)t * 2048 + c) * 4 + w] = a | (b << 16);
            }
        }
    } else if (c < 2304) {
        int c2 = c - 2048;
#pragma unroll
        for (int i = 0; i < 2; ++i) {
            int k = i * 256 + t;
            w1hT[(size_t)c2 * 512 + k] = att_w1[(size_t)(512 + k) * 256 + c2];
        }
    } else {
        int c3 = c - 2304;
        w2T[c3 * 256 + t] = att_w2[(size_t)t * 128 + c3];
    }
}

// ---------------- embedding (shifted y) -> hze e-part ----------------
__global__ __launch_bounds__(256) void embed_kernel(const int* __restrict__ y,
                                                    const u16* __restrict__ emb,
                                                    u16* __restrict__ hze) {
    int t = threadIdx.x;
    int row0 = blockIdx.x * 4;
    for (int i = 0; i < 4; ++i) {
        int row = row0 + i;
        int b = row >> 7, tt = row & 127;
        int yin = tt ? y[b * T_ + tt - 1] : 0;
        hze[(size_t)row * 1280 + 1024 + t] = emb[yin * E_ + t];
    }
}

// ---------------- generic tiled GEMM: C = act(A @ Bw + bias) ----------------
template <bool TANH, int OMODE>
__global__ __launch_bounds__(256) void gemm_kernel(const u16* __restrict__ A, int lda,
                                                   const u16* __restrict__ Bw, int ldb,
                                                   const u16* __restrict__ bias,
                                                   void* __restrict__ Cv, int ldc,
                                                   int M, int N, int K,
                                                   const int* __restrict__ flg) {
    __shared__ float As[16][132];
    __shared__ float Bs[16][68];
    int t = threadIdx.x;
    int n0 = blockIdx.x * 64;
    int m0 = blockIdx.y * 128;
    int tx = t & 15, ty = t >> 4;
    float acc[8][4];
#pragma unroll
    for (int i = 0; i < 8; ++i)
#pragma unroll
        for (int j = 0; j < 4; ++j) acc[i][j] = 0.f;

    int ar = t >> 1, akb = (t & 1) * 8;
    int bn = t & 63, bkg = t >> 6;

    for (int k0 = 0; k0 < K; k0 += 16) {
        const u16* Ap = A + (size_t)(m0 + ar) * lda + k0 + akb;
        if (k0 + 16 <= K) {
#pragma unroll
            for (int i = 0; i < 8; ++i) As[akb + i][ar] = bf2f(Ap[i]);
        } else {
#pragma unroll
            for (int i = 0; i < 8; ++i) As[akb + i][ar] = (k0 + akb + i < K) ? bf2f(Ap[i]) : 0.f;
        }
#pragma unroll
        for (int i = 0; i < 4; ++i) {
            int kk = bkg * 4 + i;
            int kg = k0 + kk, ng = n0 + bn;
            Bs[kk][bn] = (kg < K && ng < N) ? bf2f(Bw[(size_t)kg * ldb + ng]) : 0.f;
        }
        __syncthreads();
#pragma unroll
        for (int kk = 0; kk < 16; ++kk) {
            float4 aA = *(const float4*)&As[kk][ty * 8];
            float4 aB = *(const float4*)&As[kk][ty * 8 + 4];
            float4 bv = *(const float4*)&Bs[kk][tx * 4];
            float av[8] = {aA.x, aA.y, aA.z, aA.w, aB.x, aB.y, aB.z, aB.w};
            float bb[4] = {bv.x, bv.y, bv.z, bv.w};
#pragma unroll
            for (int i = 0; i < 8; ++i)
#pragma unroll
                for (int j = 0; j < 4; ++j) acc[i][j] += av[i] * bb[j];
        }
        __syncthreads();
    }
    int obf = (OMODE == 2) ? flg[0] : 1;
    float bb[4];
#pragma unroll
    for (int j = 0; j < 4; ++j) {
        int n = n0 + tx * 4 + j;
        bb[j] = (n < N) ? bf2f(bias[n]) : 0.f;
    }
#pragma unroll
    for (int i = 0; i < 8; ++i) {
        int m = m0 + ty * 8 + i;
#pragma unroll
        for (int j = 0; j < 4; ++j) {
            int n = n0 + tx * 4 + j;
            if (n < N) {
                float v = acc[i][j] + bb[j];
                if (TANH) v = tanhf(v);
                if (OMODE == 1 || obf)
                    ((u16*)Cv)[(size_t)m * ldc + n] = f2bf(v);
                else
                    ((float*)Cv)[(size_t)m * ldc + n] = v;
            }
        }
    }
}

// ---------------- persistent decoder ----------------
struct DecArgs {
    const u16 *h0, *c0, *pre1, *w2T, *att_b2, *att_w3, *w1hT, *wT, *bih, *bhh, *a;
    u16 *hze, *h0b;
    float *zacc;  // [2 parities][32 groups][528]: 512 z-numerator + den (atomicAdd)
    int* bars;
};

// x1p: packed bf16 pairs along K (256 -> 128 u32/row). Stride 136 words: rows
// 16B-aligned; row-groups 4 apart differ by 544 words = 0 mod 32 banks.
struct SA { unsigned x1p[28][136]; float part[28][36]; };

// Init-only grid barrier: all-poll (512 threads poll 256 slots, duplicated).
__device__ __forceinline__ void gridbar(int* bars, int blk, int t, int epoch) {
    __syncthreads();
    if (t == 0) stci(&bars[blk << 4], epoch);
    for (;;) {
        int v = ldci(&bars[(t & 255) << 4]);
        if (__syncthreads_count(v < epoch) == 0) break;
        __builtin_amdgcn_s_sleep(2);
    }
}

// 512-thread blocks, 2 waves/SIMD. Per-step sync: 2 group barriers (8 blocks,
// one per XCD). ZACC EXCHANGE: partial-z is accumulated via f32 atomicAdd into
// one zacc[513] per group (LLC-resident RMW) instead of 8 separate partial
// buffers -> post-barrier read is ONE ldc64 per thread (was 8), footprint
// 135KB (was 541KB; r8's 16KB/block/step reads streamed to HBM: FETCH 312MB).
// Double-buffered by step parity; block re-zeroes its 64-dim slice at step
// start (ordering: all reads of that parity completed before prior h-bar).

__global__ __launch_bounds__(512) void decoder_kernel(DecArgs g) {
    int blk = blockIdx.x, t = threadIdx.x;
    int tt = t & 255, half = t >> 8;
    __shared__ SA su;
    __shared__ float w3s[128], b2s[128], bsh[256];
    __shared__ unsigned hsp[256];   // h(t-1) packed bf16 pairs
    __shared__ unsigned einp[128];  // e_t packed pairs
    __shared__ unsigned zinp[256];  // z_t packed pairs
    __shared__ float htp[512];      // hterm partials [half*256 + col]
    __shared__ float gacc2[2][4][66];  // gate partials per K-half
    __shared__ float hsh[64];
    __shared__ float esh[28];       // exp(score) for this block's rows
    __shared__ float dsh[8];        // denominator broadcast
    __shared__ u16 w2s[128 * 256];  // w2T staged; k-unit (16B) XOR-swizzled by row>>2

    int ab = blk >> 3;   // batch (group of 8 consecutive blocks, one per XCD)
    int ach = blk & 7;   // hidden-dim slice == XCD id (weight L2 locality)
    int abL = ab << 4;

    if (t < 128) {
        w3s[t] = bf2f(g.att_w3[t]);
        b2s[t] = bf2f(g.att_b2[t]);
    }
    // stage w2T (64KB): 512 threads, 8 units (16B) each; unit u of row r at u^(r>>2).
    {
        int r = t >> 2, q8 = (t & 3) * 8;
#pragma unroll
        for (int u = q8; u < q8 + 8; ++u) {
            *(uint4*)&w2s[(size_t)r * 256 + ((u ^ (r >> 2)) & 31) * 8] =
                *(const uint4*)(g.w2T + (size_t)r * 256 + u * 8);
        }
    }
    // gate column for this thread's half: col, K-half = half.
    int col = (tt >> 6) * 512 + ach * 64 + (tt & 63);
    if (half == 0) bsh[tt] = bf2f(g.bih[col]) + bf2f(g.bhh[col]);
    float creg = (t < 64) ? bf2f(g.c0[ab * 512 + ach * 64 + t]) : 0.f;

    if (blk < 32 && t < 256) {
        unsigned pk = (unsigned)g.h0[blk * 512 + 2 * t] |
                      ((unsigned)g.h0[blk * 512 + 2 * t + 1] << 16);
        stcu((unsigned*)(g.h0b + blk * 512 + 2 * t), pk);
    }
    // zero both zacc parities for this block's dim slice (+ den by ach 0)
    {
        float* z0 = g.zacc + (size_t)ab * 528;
        float* z1 = g.zacc + (size_t)(32 + ab) * 528;
        if (t < 64) {
            stcf(z0 + ach * 64 + t, 0.f);
            stcf(z1 + ach * 64 + t, 0.f);
        }
        if (t == 64 && ach == 0) {
            stcf(z0 + 512, 0.f);
            stcf(z1 + 512, 0.f);
        }
    }

    int anrows = (ach == 7) ? 21 : 25;
    int arow0 = ab * 196 + ach * 25;
    int c2l = (t & 127) * 2, rq = (t >> 7) * 7;  // column-pair / row-quarter split

    // step-invariant register caches: pre1 (7 rows x 2 adjacent cols packed)
    // and areg2: a[row, dims 2tt..2tt+1] for this block's 25 rows (t<256 only).
    unsigned p1p[7];
#pragma unroll
    for (int i = 0; i < 7; ++i) {
        int r = min(arow0 + rq + i, 6271);
        unsigned lo = g.pre1[(size_t)r * 256 + c2l];
        unsigned hi = g.pre1[(size_t)r * 256 + c2l + 1];
        p1p[i] = lo | (hi << 16);
    }
    unsigned areg2[25];
    if (t < 256) {
#pragma unroll
        for (int r = 0; r < 25; ++r) {
            int rr = min(arow0 + r, 6271);  // clamped rows have esh==0 (no effect)
            areg2[r] = *(const unsigned*)(g.a + (size_t)rr * 512 + 2 * t);
        }
    }
    gridbar(g.bars, blk, t, 1);  // h0b + zacc zeros visible

    const uint4* wb = (const uint4*)g.wT;  // wTk4
    float acc4[4] = {0.f, 0.f, 0.f, 0.f};

    // prologue: e-GEMV for step 0 (e is static); K-half split.
    if (t < 128) einp[t] = *(const unsigned*)(g.hze + (size_t)ab * T_ * 1280 + 1024 + 2 * t);
    __syncthreads();
#pragma unroll 4
    for (int k8 = 0; k8 < 16; ++k8) {
        int ke = half * 16 + k8;
        uint4 wv = wb[(size_t)(64 + ke) * 2048 + col];
        uint4 iv = *(const uint4*)&einp[ke * 4];
        dot2bf(acc4[0], iv.x, wv.x);
        dot2bf(acc4[1], iv.y, wv.y);
        dot2bf(acc4[2], iv.z, wv.z);
        dot2bf(acc4[3], iv.w, wv.w);
    }

    for (int step = 0; step < T_; ++step) {
        int ep = step + 1;
        size_t row = (size_t)ab * T_ + step;
        const u16* hz = g.hze + row * 1280;
        // zero the other parity for step+2 (safe: all reads of it finished
        // before the h-bar we just passed; next atomics to it follow our
        // h-bar arrival this step).
        if (step) {
            float* zn = g.zacc + (size_t)(((step + 1) & 1) * 32 + ab) * 528;
            if (t < 64) stcf(zn + ach * 64 + t, 0.f);
            if (t == 64 && ach == 0) stcf(zn + 512, 0.f);
        }
        // ================= stage A: staging + hterm + attention scores =========
        const u16* hsrcA = step ? (g.hze + (row - 1) * 1280) : (g.h0b + ab * 512);
        if (t < 256) hsp[t] = ldc32(hsrcA + 2 * t);
        __syncthreads();
        // hterm: column tt, K-half 'half' (256 of 512 K) -> partial in htp[t].
        {
            float ha0 = 0.f, ha1 = 0.f, ha2 = 0.f, ha3 = 0.f;
            const u16* wp = g.w1hT + (size_t)tt * 512 + half * 256;
            const unsigned* hb = &hsp[half * 128];
#pragma unroll 4
            for (int k = 0; k < 256; k += 8) {
                uint4 wv = *(const uint4*)(wp + k);
                uint4 hv = *(const uint4*)&hb[k >> 1];
                dot2bf(ha0, hv.x, wv.x);
                dot2bf(ha1, hv.y, wv.y);
                dot2bf(ha2, hv.z, wv.z);
                dot2bf(ha3, hv.w, wv.w);
            }
            htp[t] = (ha0 + ha1) + (ha2 + ha3);
        }
        __syncthreads();
        {
            float hv0 = htp[c2l] + htp[c2l + 256];
            float hv1 = htp[c2l + 1] + htp[c2l + 257];
#pragma unroll
            for (int i = 0; i < 7; ++i) {
                float2 pv = bfp(p1p[i]);
                int r = rq + i;
                unsigned pk = 0u;
                if (r < anrows)
                    pk = (unsigned)f2bf(tanh_fast(pv.x + hv0)) |
                         ((unsigned)f2bf(tanh_fast(pv.y + hv1)) << 16);
                su.x1p[r][t & 127] = pk;
            }
        }
        __syncthreads();
        // x2 GEMM: 448 threads, 2 rows x 4 cols tiles over k=256.
        if (t < 448) {
            int r0 = (t >> 5) * 2, c0v = (t & 31) * 4;
            int lswz = t & 31;
            float acc[2][4];
#pragma unroll
            for (int i = 0; i < 2; ++i)
#pragma unroll
                for (int j = 0; j < 4; ++j) acc[i][j] = 0.f;
            for (int k8 = 0; k8 < 256; k8 += 8) {
                int ru = (((k8 >> 3) ^ lswz) & 31) * 8;
                uint4 wv[4];
#pragma unroll
                for (int j = 0; j < 4; ++j)
                    wv[j] = *(const uint4*)&w2s[(size_t)(c0v + j) * 256 + ru];
                uint4 xv[2];
#pragma unroll
                for (int i = 0; i < 2; ++i)
                    xv[i] = *(const uint4*)&su.x1p[r0 + i][k8 >> 1];
#pragma unroll
                for (int j = 0; j < 4; ++j) {
#pragma unroll
                    for (int i = 0; i < 2; ++i) {
                        dot2bf(acc[i][j], xv[i].x, wv[j].x);
                        dot2bf(acc[i][j], xv[i].y, wv[j].y);
                        dot2bf(acc[i][j], xv[i].z, wv[j].z);
                        dot2bf(acc[i][j], xv[i].w, wv[j].w);
                    }
                }
            }
#pragma unroll
            for (int i = 0; i < 2; ++i) {
                float p = 0.f;
#pragma unroll
                for (int j = 0; j < 4; ++j)
                    p += tanh_fast(acc[i][j] + b2s[c0v + j]) * w3s[c0v + j];
                su.part[r0 + i][t & 31] = p;
            }
        }
        __syncthreads();
        // scores -> exp (no max: |s| bounded ~2; softmax shift-invariant)
        if (t < 25) {
            float s = 0.f;
            if (t < anrows) {
#pragma unroll
                for (int cg = 0; cg < 32; ++cg) s += su.part[t][cg];
                esh[t] = __expf(s);
            } else {
                esh[t] = 0.f;
            }
        }
        __syncthreads();
        // partial z numerator (dims 2t, 2t+1) + denominator -> zacc atomicAdd
        if (t < 256) {
            float zpx = 0.f, zpy = 0.f, dp = 0.f;
#pragma unroll
            for (int r = 0; r < 25; ++r) {
                float er = esh[r];
                float2 av = bfp(areg2[r]);
                zpx += er * av.x;
                zpy += er * av.y;
                dp += er;
            }
            float* za = g.zacc + (size_t)((step & 1) * 32 + ab) * 528;
            atadd(za + 2 * t, zpx);
            atadd(za + 2 * t + 1, zpy);
            if (t == 0) atadd(za + 512, dp);
        }
        // --- ZP-bar post (group) ---
        __syncthreads();
        if (t == 0) {
            int old = __hip_atomic_fetch_add(&g.bars[ZP_ARR + abL], 1, __ATOMIC_RELAXED,
                                             __HIP_MEMORY_SCOPE_AGENT);
            if (old == ep * 8 - 1) stci(&g.bars[ZP_REL + abL], ep);
        }
        // --- hidden work: gate-GEMV h segment, K-half split ---
#pragma unroll 4
        for (int k8 = 0; k8 < 32; ++k8) {
            int kh = half * 32 + k8;
            uint4 wv = wb[(size_t)(96 + kh) * 2048 + col];
            uint4 iv = *(const uint4*)&hsp[kh * 4];
            dot2bf(acc4[0], iv.x, wv.x);
            dot2bf(acc4[1], iv.y, wv.y);
            dot2bf(acc4[2], iv.z, wv.z);
            dot2bf(acc4[3], iv.w, wv.w);
        }
        // prefetch first 8 z-GEMV weight vectors (hides L2 latency behind wait)
        uint4 wz[8];
#pragma unroll
        for (int k8 = 0; k8 < 8; ++k8)
            wz[k8] = wb[(size_t)(half * 32 + k8) * 2048 + col];
        // --- ZP-bar wait ---
        if (t == 0) {
            while (ldci(&g.bars[ZP_REL + abL]) < ep) __builtin_amdgcn_s_sleep(2);
        }
        __syncthreads();
        // ================= stage B: read combined zacc -> z ===================
        {
            const float* za = g.zacc + (size_t)((step & 1) * 32 + ab) * 528;
            if (t == 0) dsh[0] = ldcf(za + 512);
            float zx = 0.f, zy = 0.f;
            if (t < 256) {
                union { double d; float2 f; } u;
                u.d = ldc64(za + 2 * t);
                zx = u.f.x;
                zy = u.f.y;
            }
            __syncthreads();
            if (t < 256) {
                float inv = 1.f / dsh[0];
                unsigned pk = (unsigned)f2bf(zx * inv) | ((unsigned)f2bf(zy * inv) << 16);
                zinp[t] = pk;
                if ((t >> 5) == ach) stcu((unsigned*)(hz + 512 + 2 * t), pk);
            }
        }
        __syncthreads();
        // ================= stage C: z-segment GEMV + LSTM update ==============
#pragma unroll
        for (int k8 = 0; k8 < 8; ++k8) {
            uint4 wv = wz[k8];
            uint4 iv = *(const uint4*)&zinp[(half * 32 + k8) * 4];
            dot2bf(acc4[0], iv.x, wv.x);
            dot2bf(acc4[1], iv.y, wv.y);
            dot2bf(acc4[2], iv.z, wv.z);
            dot2bf(acc4[3], iv.w, wv.w);
        }
#pragma unroll 4
        for (int k8 = 8; k8 < 32; ++k8) {
            int kz = half * 32 + k8;
            uint4 wv = wb[(size_t)kz * 2048 + col];
            uint4 iv = *(const uint4*)&zinp[kz * 4];
            dot2bf(acc4[0], iv.x, wv.x);
            dot2bf(acc4[1], iv.y, wv.y);
            dot2bf(acc4[2], iv.z, wv.z);
            dot2bf(acc4[3], iv.w, wv.w);
        }
        gacc2[half][tt >> 6][tt & 63] = (acc4[0] + acc4[1]) + (acc4[2] + acc4[3]);
        __syncthreads();
        if (t < 64) {
            float gg[4];
#pragma unroll
            for (int q = 0; q < 4; ++q)
                gg[q] = gacc2[0][q][t] + gacc2[1][q][t] + bsh[q * 64 + t];
            float gi = sigm(gg[0]), gf = sigm(gg[1]);
            float gn = tanh_fast(gg[2]), go = sigm(gg[3]);
            float cn = gf * creg + gi * gn;
            creg = cn;  // c-state lives in a register (block-private)
            hsh[t] = go * tanh_fast(cn);
        }
        __syncthreads();
        if (t < 32) {
            unsigned pk = (unsigned)f2bf(hsh[2 * t]) | ((unsigned)f2bf(hsh[2 * t + 1]) << 16);
            stcu((unsigned*)(hz + ach * 64 + 2 * t), pk);
        }
        // --- h-bar (group); next step's e-GEMV hidden in the window; skip last ---
        if (step + 1 < T_) {
            __syncthreads();  // drain h stores before arrival
            if (t == 0) {
                int old = __hip_atomic_fetch_add(&g.bars[H_ARR + abL], 1, __ATOMIC_RELAXED,
                                                 __HIP_MEMORY_SCOPE_AGENT);
                if (old == ep * 8 - 1) stci(&g.bars[H_REL + abL], ep);
            }
#pragma unroll
            for (int i = 0; i < 4; ++i) acc4[i] = 0.f;
            if (t < 128) einp[t] = *(const unsigned*)(hz + 1280 + 1024 + 2 * t);
            __syncthreads();
#pragma unroll 4
            for (int k8 = 0; k8 < 16; ++k8) {
                int ke = half * 16 + k8;
                uint4 wv = wb[(size_t)(64 + ke) * 2048 + col];
                uint4 iv = *(const uint4*)&einp[ke * 4];
                dot2bf(acc4[0], iv.x, wv.x);
                dot2bf(acc4[1], iv.y, wv.y);
                dot2bf(acc4[2], iv.z, wv.z);
                dot2bf(acc4[3], iv.w, wv.w);
            }
            if (t == 0) {
                while (ldci(&g.bars[H_REL + abL]) < ep) __builtin_amdgcn_s_sleep(2);
            }
            __syncthreads();
        }
    }
}

extern "C" void kernel_launch(void* const* d_in, const int* in_sizes, int n_in,
                              void* d_out, int out_size, void* d_ws, size_t ws_size,
                              hipStream_t stream) {
    (void)in_sizes; (void)n_in; (void)out_size; (void)ws_size;
    const int* y = (const int*)d_in[3];

    char* base = (char*)d_ws;
    size_t off = 0;
    auto alloc = [&](size_t bytes) {
        void* p = base + off;
        off = (off + bytes + 63) & ~(size_t)63;
        return p;
    };
    // Total footprint ~33.6 MB — must stay <= 34.34 MB (round-2 proven bound).
    int* flg   = (int*)alloc(64);
    int* bars  = (int*)alloc(NBARS * 4);
    u16* conv  = (u16*)alloc((size_t)7067000 * 2);
    u16* pre1  = (u16*)alloc((size_t)6272 * 256 * 2);   // t2 aliases after decoder
    u16* hze   = (u16*)alloc((size_t)4096 * 1280 * 2);
    u16* wTk4  = (u16*)alloc((size_t)2048 * 1280 * 2);  // t1 aliases after decoder
    u16* w1hT  = (u16*)alloc((size_t)256 * 512 * 2);
    u16* w2T   = (u16*)alloc((size_t)128 * 256 * 2);
    u16* h0b   = (u16*)alloc((size_t)32 * 512 * 2);
    float* zacc = (float*)alloc((size_t)2 * 32 * 528 * 4);  // atomic z exchange
    u16* t1 = wTk4;  // wTk4 dead after decoder; 5.24MB >= 2.93MB
    u16* t2 = pre1;  // pre1 dead after decoder; 3.21MB >= 2.93MB

    u16* c_a     = conv + 0;
    u16* c_h0    = conv + 3211264;
    u16* c_c0    = conv + 3227648;
    u16* c_attw1 = conv + 3244032;
    u16* c_attb1 = conv + 3506176;
    u16* c_attw2 = conv + 3506432;
    u16* c_attb2 = conv + 3539200;
    u16* c_attw3 = conv + 3539328;
    u16* c_wih   = conv + 3539456;
    u16* c_whh   = conv + 5112320;
    u16* c_bih   = conv + 6160896;
    u16* c_bhh   = conv + 6162944;
    u16* c_emb   = conv + 6164992;
    u16* c_ow1   = conv + 6296064;
    u16* c_ob1   = conv + 6754304;
    u16* c_ow2   = conv + 6754664;
    u16* c_ob2   = conv + 6882832;
    u16* c_ow3   = conv + 6883192;
    u16* c_ob3   = conv + 7066488;

    ConvPtrs cp;
    {
        const int idx[19] = {0, 1, 2, 4, 5, 6, 7, 8, 10, 11, 12, 13, 14, 15, 16, 17, 18, 19, 20};
        for (int i = 0; i < 19; ++i) cp.p[i] = d_in[idx[i]];
    }

    detect_kernel<<<1, 64, 0, stream>>>((const u16*)d_in[4], flg, bars);
    conv_kernel<<<6902, 256, 0, stream>>>(cp, flg, conv);
    prep_kernel<<<2432, 256, 0, stream>>>(c_wih, c_whh, c_attw1, c_attw2, wTk4, w1hT, w2T);
    embed_kernel<<<1024, 256, 0, stream>>>(y, c_emb, hze);
    gemm_kernel<false, 1><<<dim3(4, 49), 256, 0, stream>>>(
        c_a, 512, c_attw1, 256, c_attb1, pre1, 256, 6272, 256, 512, flg);

    DecArgs g;
    g.h0 = c_h0; g.c0 = c_c0; g.pre1 = pre1; g.w2T = w2T; g.att_b2 = c_attb2;
    g.att_w3 = c_attw3; g.w1hT = w1hT; g.wT = wTk4; g.bih = c_bih; g.bhh = c_bhh;
    g.a = c_a; g.hze = hze; g.h0b = h0b; g.zacc = zacc; g.bars = bars;
    decoder_kernel<<<GRID_, 512, 0, stream>>>(g);

    gemm_kernel<true, 1><<<dim3(6, 32), 256, 0, stream>>>(
        hze, 1280, c_ow1, 358, c_ob1, t1, 358, 4096, 358, 1280, flg);
    gemm_kernel<true, 1><<<dim3(6, 32), 256, 0, stream>>>(
        t1, 358, c_ow2, 358, c_ob2, t2, 358, 4096, 358, 358, flg);
    gemm_kernel<false, 2><<<dim3(8, 32), 256, 0, stream>>>(
        t2, 358, c_ow3, 512, c_ob3, d_out, 512, 4096, 512, 358, flg);
}

// Round 10
// 2852.114 us; speedup vs baseline: 1.7564x; 1.2168x over previous
//
#include <hip/hip_runtime.h>
#include <hip/hip_bf16.h>
#include <cstdint>

#define B_ 32
#define L_ 196
#define D_ 512
#define H_ 512
#define E_ 256
#define T_ 128
#define V_ 512
#define GRID_ 256
#define NBARS 8192
// bars layout (ints): slot(blk)=blk*16 [0..4095] (init grid barrier only);
// per-group lines (gb<32, stride 16): ZP_ARR 4096, ZP_REL 4608,
// H_ARR 6144, H_REL 6656.
#define ZP_ARR 4096
#define ZP_REL 4608
#define H_ARR 6144
#define H_REL 6656

using u16 = unsigned short;
typedef __attribute__((ext_vector_type(8))) short bfrag8;   // 8 bf16 (4 VGPRs)
typedef __attribute__((ext_vector_type(4))) float f32x4;    // MFMA accumulator

__device__ __forceinline__ float bf2f(u16 u) { return __uint_as_float(((unsigned)u) << 16); }
__device__ __forceinline__ u16 f2bf(float f) {
    unsigned u = __float_as_uint(f);
    return (u16)((u + 0x7FFFu + ((u >> 16) & 1u)) >> 16);
}
__device__ __forceinline__ float2 bfp(unsigned u) {
    return make_float2(__uint_as_float(u << 16), __uint_as_float(u & 0xffff0000u));
}
__device__ __forceinline__ float sigm(float x) { return 1.f / (1.f + __expf(-x)); }
__device__ __forceinline__ float tanh_fast(float x) { return 1.f - 2.f / (__expf(2.f * x) + 1.f); }

// v_dot2_f32_bf16: acc += a.lo*b.lo + a.hi*b.hi (bf16 pairs, f32 accumulate).
__device__ __forceinline__ void dot2bf(float& acc, unsigned a, unsigned b) {
    asm("v_dot2_f32_bf16 %0, %1, %2, %0" : "+v"(acc) : "v"(a), "v"(b));
}

// --- coherent (cache-bypass) payload access: relaxed agent-scope atomics.
__device__ __forceinline__ float ldcf(const float* p) {
    return __hip_atomic_load((float*)p, __ATOMIC_RELAXED, __HIP_MEMORY_SCOPE_AGENT);
}
__device__ __forceinline__ int ldci(const int* p) {
    return __hip_atomic_load((int*)p, __ATOMIC_RELAXED, __HIP_MEMORY_SCOPE_AGENT);
}
__device__ __forceinline__ unsigned ldc32(const void* p) {
    return __hip_atomic_load((unsigned*)p, __ATOMIC_RELAXED, __HIP_MEMORY_SCOPE_AGENT);
}
__device__ __forceinline__ double ldc64(const void* p) {
    return __hip_atomic_load((double*)p, __ATOMIC_RELAXED, __HIP_MEMORY_SCOPE_AGENT);
}
__device__ __forceinline__ void stcf(float* p, float v) {
    __hip_atomic_store(p, v, __ATOMIC_RELAXED, __HIP_MEMORY_SCOPE_AGENT);
}
__device__ __forceinline__ void stci(int* p, int v) {
    __hip_atomic_store(p, v, __ATOMIC_RELAXED, __HIP_MEMORY_SCOPE_AGENT);
}
__device__ __forceinline__ void stcu(unsigned* p, unsigned v) {
    __hip_atomic_store(p, v, __ATOMIC_RELAXED, __HIP_MEMORY_SCOPE_AGENT);
}
__device__ __forceinline__ void atadd(float* p, float v) {
    __hip_atomic_fetch_add(p, v, __ATOMIC_RELAXED, __HIP_MEMORY_SCOPE_AGENT);
}

// ---------------- dtype detect + barrier reset ----------------
__global__ void detect_kernel(const u16* __restrict__ w, int* __restrict__ flg,
                              int* __restrict__ bars) {
    for (int i = threadIdx.x; i < NBARS; i += 64) bars[i] = 0;
    if (threadIdx.x == 0) {
        int cnt = 0;
        for (int i = 0; i < 64; ++i) {
            int e = (w[i] >> 7) & 0xFF;
            cnt += (e >= 100 && e <= 130);
        }
        flg[0] = (cnt >= 56) ? 1 : 0;
    }
}

// ---------------- convert all float tensors to internal bf16 ----------------
struct ConvPtrs { const void* p[19]; };

__global__ __launch_bounds__(256) void conv_kernel(ConvPtrs cp, const int* __restrict__ flg,
                                                   u16* __restrict__ dst) {
    constexpr int NT = 19;
    constexpr unsigned off[NT + 1] = {
        0u, 3211264u, 3227648u, 3244032u, 3506176u, 3506432u, 3539200u, 3539328u,
        3539456u, 5112320u, 6160896u, 6162944u, 6164992u, 6296064u, 6754304u,
        6754664u, 6882832u, 6883192u, 7066488u, 7067000u};
    constexpr unsigned realN[NT] = {
        3211264u, 16384u, 16384u, 262144u, 256u, 32768u, 128u, 128u,
        1572864u, 1048576u, 2048u, 2048u, 131072u, 458240u, 358u,
        128164u, 358u, 183296u, 512u};
    unsigned pos = (blockIdx.x * 256u + threadIdx.x) * 4u;
    if (pos >= off[NT]) return;
    int t = 0;
#pragma unroll
    for (int i = 1; i < NT; ++i) t += (pos >= off[i]);
    unsigned local = pos - off[t];
    int bf = flg[0];
    const void* src = cp.p[t];
    u16* d = dst + off[t];
#pragma unroll
    for (int j = 0; j < 4; ++j) {
        unsigned l = local + j;
        u16 v = 0;
        if (l < realN[t]) v = bf ? ((const u16*)src)[l] : f2bf(((const float*)src)[l]);
        d[l] = v;
    }
}

// ---------------- weight prep: wTk4, w1hT, bfragG (MFMA-ordered att_w2) ------
// wTk4 u32 layout: word ((k8*2048 + col)*4 + w) holds bf16 pair (K=k8*8+2w, +1)
// of gate column col. K order: 0..511 z, 512..767 e, 768..1279 h.
// bfragG: mfma_f32_16x16x32_bf16 B-fragment order for att_w2[K=256][N=128]:
// value att_w2[k][n] at ((n>>4)*8 + (k>>5))*64*8 + ((n&15)|(((k&31)>>3)<<4))*8 + (k&7).
__global__ __launch_bounds__(256) void prep_kernel(const u16* __restrict__ w_ih,
                                                   const u16* __restrict__ w_hh,
                                                   const u16* __restrict__ att_w1,
                                                   const u16* __restrict__ att_w2,
                                                   u16* __restrict__ wTk4,
                                                   u16* __restrict__ w1hT,
                                                   u16* __restrict__ bfG) {
    int c = blockIdx.x, t = threadIdx.x;
    if (c < 2048) {
        if (t < 160) {
            unsigned* dst = (unsigned*)wTk4;
#pragma unroll
            for (int w = 0; w < 4; ++w) {
                int k0 = t * 8 + 2 * w;
                unsigned a = (k0 < 768) ? w_ih[(size_t)k0 * 2048 + c]
                                        : w_hh[(size_t)(k0 - 768) * 2048 + c];
                unsigned b = (k0 + 1 < 768) ? w_ih[(size_t)(k0 + 1) * 2048 + c]
                                            : w_hh[(size_t)(k0 + 1 - 768) * 2048 + c];
                dst[((size_t)t * 2048 + c) * 4 + w] = a | (b << 16);
            }
        }
    } else if (c < 2304) {
        int c2 = c - 2048;
#pragma unroll
        for (int i = 0; i < 2; ++i) {
            int k = i * 256 + t;
            w1hT[(size_t)c2 * 512 + k] = att_w1[(size_t)(512 + k) * 256 + c2];
        }
    } else {
        int n = c - 2304;  // att-hidden col 0..127
        int k = t;         // K 0..255
        int idx = ((((n >> 4) * 8 + (k >> 5)) * 64 +
                    ((n & 15) | (((k & 31) >> 3) << 4))) * 8) + (k & 7);
        bfG[idx] = att_w2[(size_t)k * 128 + n];
    }
}

// ---------------- embedding (shifted y) -> hze e-part ----------------
__global__ __launch_bounds__(256) void embed_kernel(const int* __restrict__ y,
                                                    const u16* __restrict__ emb,
                                                    u16* __restrict__ hze) {
    int t = threadIdx.x;
    int row0 = blockIdx.x * 4;
    for (int i = 0; i < 4; ++i) {
        int row = row0 + i;
        int b = row >> 7, tt = row & 127;
        int yin = tt ? y[b * T_ + tt - 1] : 0;
        hze[(size_t)row * 1280 + 1024 + t] = emb[yin * E_ + t];
    }
}

// ---------------- generic tiled GEMM: C = act(A @ Bw + bias) ----------------
template <bool TANH, int OMODE>
__global__ __launch_bounds__(256) void gemm_kernel(const u16* __restrict__ A, int lda,
                                                   const u16* __restrict__ Bw, int ldb,
                                                   const u16* __restrict__ bias,
                                                   void* __restrict__ Cv, int ldc,
                                                   int M, int N, int K,
                                                   const int* __restrict__ flg) {
    __shared__ float As[16][132];
    __shared__ float Bs[16][68];
    int t = threadIdx.x;
    int n0 = blockIdx.x * 64;
    int m0 = blockIdx.y * 128;
    int tx = t & 15, ty = t >> 4;
    float acc[8][4];
#pragma unroll
    for (int i = 0; i < 8; ++i)
#pragma unroll
        for (int j = 0; j < 4; ++j) acc[i][j] = 0.f;

    int ar = t >> 1, akb = (t & 1) * 8;
    int bn = t & 63, bkg = t >> 6;

    for (int k0 = 0; k0 < K; k0 += 16) {
        const u16* Ap = A + (size_t)(m0 + ar) * lda + k0 + akb;
        if (k0 + 16 <= K) {
#pragma unroll
            for (int i = 0; i < 8; ++i) As[akb + i][ar] = bf2f(Ap[i]);
        } else {
#pragma unroll
            for (int i = 0; i < 8; ++i) As[akb + i][ar] = (k0 + akb + i < K) ? bf2f(Ap[i]) : 0.f;
        }
#pragma unroll
        for (int i = 0; i < 4; ++i) {
            int kk = bkg * 4 + i;
            int kg = k0 + kk, ng = n0 + bn;
            Bs[kk][bn] = (kg < K && ng < N) ? bf2f(Bw[(size_t)kg * ldb + ng]) : 0.f;
        }
        __syncthreads();
#pragma unroll
        for (int kk = 0; kk < 16; ++kk) {
            float4 aA = *(const float4*)&As[kk][ty * 8];
            float4 aB = *(const float4*)&As[kk][ty * 8 + 4];
            float4 bv = *(const float4*)&Bs[kk][tx * 4];
            float av[8] = {aA.x, aA.y, aA.z, aA.w, aB.x, aB.y, aB.z, aB.w};
            float bb[4] = {bv.x, bv.y, bv.z, bv.w};
#pragma unroll
            for (int i = 0; i < 8; ++i)
#pragma unroll
                for (int j = 0; j < 4; ++j) acc[i][j] += av[i] * bb[j];
        }
        __syncthreads();
    }
    int obf = (OMODE == 2) ? flg[0] : 1;
    float bb[4];
#pragma unroll
    for (int j = 0; j < 4; ++j) {
        int n = n0 + tx * 4 + j;
        bb[j] = (n < N) ? bf2f(bias[n]) : 0.f;
    }
#pragma unroll
    for (int i = 0; i < 8; ++i) {
        int m = m0 + ty * 8 + i;
#pragma unroll
        for (int j = 0; j < 4; ++j) {
            int n = n0 + tx * 4 + j;
            if (n < N) {
                float v = acc[i][j] + bb[j];
                if (TANH) v = tanhf(v);
                if (OMODE == 1 || obf)
                    ((u16*)Cv)[(size_t)m * ldc + n] = f2bf(v);
                else
                    ((float*)Cv)[(size_t)m * ldc + n] = v;
            }
        }
    }
}

// ---------------- persistent decoder ----------------
struct DecArgs {
    const u16 *h0, *c0, *pre1, *bfG, *att_b2, *att_w3, *w1hT, *wT, *bih, *bhh, *a;
    u16 *hze, *h0b;
    float *zacc;  // [2 parities][32 groups][528]: 512 z-numerator + den (atomicAdd)
    int* bars;
};

// Init-only grid barrier: all-poll (512 threads poll 256 slots, duplicated).
__device__ __forceinline__ void gridbar(int* bars, int blk, int t, int epoch) {
    __syncthreads();
    if (t == 0) stci(&bars[blk << 4], epoch);
    for (;;) {
        int v = ldci(&bars[(t & 255) << 4]);
        if (__syncthreads_count(v < epoch) == 0) break;
        __builtin_amdgcn_s_sleep(2);
    }
}

// 512-thread blocks, 2 waves/SIMD. Per-step sync: 2 group barriers (8 blocks,
// one per XCD). x2 attention GEMM is MFMA (16x16x32 bf16): B (att_w2) staged
// fragment-ordered in LDS once; A (x1) written fragment-ordered by producers
// each step. Replaces the w2s dot2 stream (~1MB LDS/step) with ~0.2MB.

__global__ __launch_bounds__(512) void decoder_kernel(DecArgs g) {
    int blk = blockIdx.x, t = threadIdx.x;
    int tt = t & 255, half = t >> 8;
    __shared__ u16 bfl[8 * 8 * 64 * 8];  // 64KB B-fragments (8 N-tiles x 8 K-tiles)
    __shared__ u16 afl[2 * 8 * 64 * 8];  // 16KB A-fragments (2 M-tiles x 8 K-tiles)
    __shared__ float part2[32][9];       // per-wave score partials
    __shared__ float bsh[256];
    __shared__ unsigned hsp[256];   // h(t-1) packed bf16 pairs
    __shared__ unsigned einp[128];  // e_t packed pairs
    __shared__ unsigned zinp[256];  // z_t packed pairs
    __shared__ float htp[512];      // hterm partials [half*256 + col]
    __shared__ float gacc2[2][4][66];  // gate partials per K-half
    __shared__ float hsh[64];
    __shared__ float esh[28];       // exp(score) for this block's rows
    __shared__ float dsh[8];        // denominator broadcast

    int ab = blk >> 3;   // batch (group of 8 consecutive blocks, one per XCD)
    int ach = blk & 7;   // hidden-dim slice == XCD id (weight L2 locality)
    int abL = ab << 4;

    // stage B-fragments (linear 64KB copy) + zero A-fragments
    {
        uint4* bd = (uint4*)bfl;
        const uint4* bs = (const uint4*)g.bfG;
#pragma unroll
        for (int i = 0; i < 16; ++i) bd[t + 512 * i] = bs[t + 512 * i];
        uint4 z4 = {0u, 0u, 0u, 0u};
        ((uint4*)afl)[t] = z4;
        ((uint4*)afl)[t + 512] = z4;
    }
    // per-lane attention epilogue constants: col = wave*16 + (lane&15)
    int lane = t & 63, wv8 = t >> 6;
    int colA = wv8 * 16 + (lane & 15);
    float b2r = bf2f(g.att_b2[colA]);
    float w3r = bf2f(g.att_w3[colA]);

    // gate column for this thread's half: col, K-half = half.
    int col = (tt >> 6) * 512 + ach * 64 + (tt & 63);
    if (half == 0) bsh[tt] = bf2f(g.bih[col]) + bf2f(g.bhh[col]);
    float creg = (t < 64) ? bf2f(g.c0[ab * 512 + ach * 64 + t]) : 0.f;

    if (blk < 32 && t < 256) {
        unsigned pk = (unsigned)g.h0[blk * 512 + 2 * t] |
                      ((unsigned)g.h0[blk * 512 + 2 * t + 1] << 16);
        stcu((unsigned*)(g.h0b + blk * 512 + 2 * t), pk);
    }
    // zero both zacc parities for this block's dim slice (+ den by ach 0)
    {
        float* z0 = g.zacc + (size_t)ab * 528;
        float* z1 = g.zacc + (size_t)(32 + ab) * 528;
        if (t < 64) {
            stcf(z0 + ach * 64 + t, 0.f);
            stcf(z1 + ach * 64 + t, 0.f);
        }
        if (t == 64 && ach == 0) {
            stcf(z0 + 512, 0.f);
            stcf(z1 + 512, 0.f);
        }
    }

    int anrows = (ach == 7) ? 21 : 25;
    int arow0 = ab * 196 + ach * 25;
    int c2l = (t & 127) * 2, rq = (t >> 7) * 7;  // column-pair / row-quarter split

    // step-invariant register caches: pre1 (7 rows x 2 adjacent cols packed)
    // and areg2: a[row, dims 2tt..2tt+1] for this block's 25 rows (t<256 only).
    unsigned p1p[7];
#pragma unroll
    for (int i = 0; i < 7; ++i) {
        int r = min(arow0 + rq + i, 6271);
        unsigned lo = g.pre1[(size_t)r * 256 + c2l];
        unsigned hi = g.pre1[(size_t)r * 256 + c2l + 1];
        p1p[i] = lo | (hi << 16);
    }
    unsigned areg2[25];
    if (t < 256) {
#pragma unroll
        for (int r = 0; r < 25; ++r) {
            int rr = min(arow0 + r, 6271);  // clamped rows have esh==0 (no effect)
            areg2[r] = *(const unsigned*)(g.a + (size_t)rr * 512 + 2 * t);
        }
    }
    gridbar(g.bars, blk, t, 1);  // h0b + zacc zeros visible

    const uint4* wb = (const uint4*)g.wT;  // wTk4
    float acc4[4] = {0.f, 0.f, 0.f, 0.f};

    // afrag producer constants (k-pair c2l): lane-high and j within fragment
    int af_kt = c2l >> 5, af_lhi = ((c2l & 31) >> 3) << 4, af_jp = (c2l & 7) >> 1;

    // prologue: e-GEMV for step 0 (e is static); K-half split.
    if (t < 128) einp[t] = *(const unsigned*)(g.hze + (size_t)ab * T_ * 1280 + 1024 + 2 * t);
    __syncthreads();
#pragma unroll 4
    for (int k8 = 0; k8 < 16; ++k8) {
        int ke = half * 16 + k8;
        uint4 wv = wb[(size_t)(64 + ke) * 2048 + col];
        uint4 iv = *(const uint4*)&einp[ke * 4];
        dot2bf(acc4[0], iv.x, wv.x);
        dot2bf(acc4[1], iv.y, wv.y);
        dot2bf(acc4[2], iv.z, wv.z);
        dot2bf(acc4[3], iv.w, wv.w);
    }

    for (int step = 0; step < T_; ++step) {
        int ep = step + 1;
        size_t row = (size_t)ab * T_ + step;
        const u16* hz = g.hze + row * 1280;
        // zero the other parity for step+2 (safe: all reads of it finished
        // before the h-bar we just passed).
        if (step) {
            float* zn = g.zacc + (size_t)(((step + 1) & 1) * 32 + ab) * 528;
            if (t < 64) stcf(zn + ach * 64 + t, 0.f);
            if (t == 64 && ach == 0) stcf(zn + 512, 0.f);
        }
        // ================= stage A: staging + hterm + attention scores =========
        const u16* hsrcA = step ? (g.hze + (row - 1) * 1280) : (g.h0b + ab * 512);
        if (t < 256) hsp[t] = ldc32(hsrcA + 2 * t);
        __syncthreads();
        // hterm: column tt, K-half 'half' (256 of 512 K) -> partial in htp[t].
        {
            float ha0 = 0.f, ha1 = 0.f, ha2 = 0.f, ha3 = 0.f;
            const u16* wp = g.w1hT + (size_t)tt * 512 + half * 256;
            const unsigned* hb = &hsp[half * 128];
#pragma unroll 4
            for (int k = 0; k < 256; k += 8) {
                uint4 wv = *(const uint4*)(wp + k);
                uint4 hv = *(const uint4*)&hb[k >> 1];
                dot2bf(ha0, hv.x, wv.x);
                dot2bf(ha1, hv.y, wv.y);
                dot2bf(ha2, hv.z, wv.z);
                dot2bf(ha3, hv.w, wv.w);
            }
            htp[t] = (ha0 + ha1) + (ha2 + ha3);
        }
        __syncthreads();
        // producers: x1 = tanh(pre1 + hterm) -> A-fragments (bf16 pairs)
        {
            float hv0 = htp[c2l] + htp[c2l + 256];
            float hv1 = htp[c2l + 1] + htp[c2l + 257];
            unsigned* af32 = (unsigned*)afl;
#pragma unroll
            for (int i = 0; i < 7; ++i) {
                int r = rq + i;
                if (r < anrows) {
                    float2 pv = bfp(p1p[i]);
                    unsigned pk = (unsigned)f2bf(tanh_fast(pv.x + hv0)) |
                                  ((unsigned)f2bf(tanh_fast(pv.y + hv1)) << 16);
                    int mt = r >> 4;
                    af32[((mt * 8 + af_kt) * 64 + ((r & 15) | af_lhi)) * 4 + af_jp] = pk;
                }
            }
        }
        __syncthreads();
        // x2 GEMM via MFMA: wave wv8 owns N-tile wv8 (16 cols), both M-tiles.
        {
            f32x4 acc0 = {0.f, 0.f, 0.f, 0.f};
            f32x4 acc1 = {0.f, 0.f, 0.f, 0.f};
            const bfrag8* bp = (const bfrag8*)bfl;
            const bfrag8* ap = (const bfrag8*)afl;
#pragma unroll
            for (int kt = 0; kt < 8; ++kt) {
                bfrag8 bv = bp[(wv8 * 8 + kt) * 64 + lane];
                bfrag8 a0 = ap[kt * 64 + lane];
                bfrag8 a1 = ap[(8 + kt) * 64 + lane];
                acc0 = __builtin_amdgcn_mfma_f32_16x16x32_bf16(a0, bv, acc0, 0, 0, 0);
                acc1 = __builtin_amdgcn_mfma_f32_16x16x32_bf16(a1, bv, acc1, 0, 0, 0);
            }
#pragma unroll
            for (int q = 0; q < 4; ++q) {
                float p0 = tanh_fast(acc0[q] + b2r) * w3r;
                float p1 = tanh_fast(acc1[q] + b2r) * w3r;
#pragma unroll
                for (int off = 1; off < 16; off <<= 1) {
                    p0 += __shfl_xor(p0, off);
                    p1 += __shfl_xor(p1, off);
                }
                if ((lane & 15) == 0) {
                    int r0 = (lane >> 4) * 4 + q;
                    part2[r0][wv8] = p0;
                    part2[16 + r0][wv8] = p1;
                }
            }
        }
        __syncthreads();
        // scores -> exp (no max: |s| bounded ~2; softmax shift-invariant)
        if (t < 25) {
            if (t < anrows) {
                const float* pr = part2[t];
                float s = ((pr[0] + pr[1]) + (pr[2] + pr[3])) +
                          ((pr[4] + pr[5]) + (pr[6] + pr[7]));
                esh[t] = __expf(s);
            } else {
                esh[t] = 0.f;
            }
        }
        __syncthreads();
        // partial z numerator (dims 2t, 2t+1) + denominator -> zacc atomicAdd
        if (t < 256) {
            float zpx = 0.f, zpy = 0.f, dp = 0.f;
#pragma unroll
            for (int r = 0; r < 25; ++r) {
                float er = esh[r];
                float2 av = bfp(areg2[r]);
                zpx += er * av.x;
                zpy += er * av.y;
                dp += er;
            }
            float* za = g.zacc + (size_t)((step & 1) * 32 + ab) * 528;
            atadd(za + 2 * t, zpx);
            atadd(za + 2 * t + 1, zpy);
            if (t == 0) atadd(za + 512, dp);
        }
        // --- ZP-bar post (group) ---
        __syncthreads();
        if (t == 0) {
            int old = __hip_atomic_fetch_add(&g.bars[ZP_ARR + abL], 1, __ATOMIC_RELAXED,
                                             __HIP_MEMORY_SCOPE_AGENT);
            if (old == ep * 8 - 1) stci(&g.bars[ZP_REL + abL], ep);
        }
        // --- hidden work: gate-GEMV h segment, K-half split ---
#pragma unroll 4
        for (int k8 = 0; k8 < 32; ++k8) {
            int kh = half * 32 + k8;
            uint4 wv = wb[(size_t)(96 + kh) * 2048 + col];
            uint4 iv = *(const uint4*)&hsp[kh * 4];
            dot2bf(acc4[0], iv.x, wv.x);
            dot2bf(acc4[1], iv.y, wv.y);
            dot2bf(acc4[2], iv.z, wv.z);
            dot2bf(acc4[3], iv.w, wv.w);
        }
        // prefetch first 8 z-GEMV weight vectors (hides L2 latency behind wait)
        uint4 wz[8];
#pragma unroll
        for (int k8 = 0; k8 < 8; ++k8)
            wz[k8] = wb[(size_t)(half * 32 + k8) * 2048 + col];
        // --- ZP-bar wait ---
        if (t == 0) {
            while (ldci(&g.bars[ZP_REL + abL]) < ep) __builtin_amdgcn_s_sleep(2);
        }
        __syncthreads();
        // ================= stage B: read combined zacc -> z ===================
        {
            const float* za = g.zacc + (size_t)((step & 1) * 32 + ab) * 528;
            if (t == 0) dsh[0] = ldcf(za + 512);
            float zx = 0.f, zy = 0.f;
            if (t < 256) {
                union { double d; float2 f; } u;
                u.d = ldc64(za + 2 * t);
                zx = u.f.x;
                zy = u.f.y;
            }
            __syncthreads();
            if (t < 256) {
                float inv = 1.f / dsh[0];
                unsigned pk = (unsigned)f2bf(zx * inv) | ((unsigned)f2bf(zy * inv) << 16);
                zinp[t] = pk;
                if ((t >> 5) == ach) stcu((unsigned*)(hz + 512 + 2 * t), pk);
            }
        }
        __syncthreads();
        // ================= stage C: z-segment GEMV + LSTM update ==============
#pragma unroll
        for (int k8 = 0; k8 < 8; ++k8) {
            uint4 wv = wz[k8];
            uint4 iv = *(const uint4*)&zinp[(half * 32 + k8) * 4];
            dot2bf(acc4[0], iv.x, wv.x);
            dot2bf(acc4[1], iv.y, wv.y);
            dot2bf(acc4[2], iv.z, wv.z);
            dot2bf(acc4[3], iv.w, wv.w);
        }
#pragma unroll 4
        for (int k8 = 8; k8 < 32; ++k8) {
            int kz = half * 32 + k8;
            uint4 wv = wb[(size_t)kz * 2048 + col];
            uint4 iv = *(const uint4*)&zinp[kz * 4];
            dot2bf(acc4[0], iv.x, wv.x);
            dot2bf(acc4[1], iv.y, wv.y);
            dot2bf(acc4[2], iv.z, wv.z);
            dot2bf(acc4[3], iv.w, wv.w);
        }
        gacc2[half][tt >> 6][tt & 63] = (acc4[0] + acc4[1]) + (acc4[2] + acc4[3]);
        __syncthreads();
        if (t < 64) {
            float gg[4];
#pragma unroll
            for (int q = 0; q < 4; ++q)
                gg[q] = gacc2[0][q][t] + gacc2[1][q][t] + bsh[q * 64 + t];
            float gi = sigm(gg[0]), gf = sigm(gg[1]);
            float gn = tanh_fast(gg[2]), go = sigm(gg[3]);
            float cn = gf * creg + gi * gn;
            creg = cn;  // c-state lives in a register (block-private)
            hsh[t] = go * tanh_fast(cn);
        }
        __syncthreads();
        if (t < 32) {
            unsigned pk = (unsigned)f2bf(hsh[2 * t]) | ((unsigned)f2bf(hsh[2 * t + 1]) << 16);
            stcu((unsigned*)(hz + ach * 64 + 2 * t), pk);
        }
        // --- h-bar (group); next step's e-GEMV hidden in the window; skip last ---
        if (step + 1 < T_) {
            __syncthreads();  // drain h stores before arrival
            if (t == 0) {
                int old = __hip_atomic_fetch_add(&g.bars[H_ARR + abL], 1, __ATOMIC_RELAXED,
                                                 __HIP_MEMORY_SCOPE_AGENT);
                if (old == ep * 8 - 1) stci(&g.bars[H_REL + abL], ep);
            }
#pragma unroll
            for (int i = 0; i < 4; ++i) acc4[i] = 0.f;
            if (t < 128) einp[t] = *(const unsigned*)(hz + 1280 + 1024 + 2 * t);
            __syncthreads();
#pragma unroll 4
            for (int k8 = 0; k8 < 16; ++k8) {
                int ke = half * 16 + k8;
                uint4 wv = wb[(size_t)(64 + ke) * 2048 + col];
                uint4 iv = *(const uint4*)&einp[ke * 4];
                dot2bf(acc4[0], iv.x, wv.x);
                dot2bf(acc4[1], iv.y, wv.y);
                dot2bf(acc4[2], iv.z, wv.z);
                dot2bf(acc4[3], iv.w, wv.w);
            }
            if (t == 0) {
                while (ldci(&g.bars[H_REL + abL]) < ep) __builtin_amdgcn_s_sleep(2);
            }
            __syncthreads();
        }
    }
}

extern "C" void kernel_launch(void* const* d_in, const int* in_sizes, int n_in,
                              void* d_out, int out_size, void* d_ws, size_t ws_size,
                              hipStream_t stream) {
    (void)in_sizes; (void)n_in; (void)out_size; (void)ws_size;
    const int* y = (const int*)d_in[3];

    char* base = (char*)d_ws;
    size_t off = 0;
    auto alloc = [&](size_t bytes) {
        void* p = base + off;
        off = (off + bytes + 63) & ~(size_t)63;
        return p;
    };
    // Total footprint ~33.6 MB — must stay <= 34.34 MB (round-2 proven bound).
    int* flg   = (int*)alloc(64);
    int* bars  = (int*)alloc(NBARS * 4);
    u16* conv  = (u16*)alloc((size_t)7067000 * 2);
    u16* pre1  = (u16*)alloc((size_t)6272 * 256 * 2);   // t2 aliases after decoder
    u16* hze   = (u16*)alloc((size_t)4096 * 1280 * 2);
    u16* wTk4  = (u16*)alloc((size_t)2048 * 1280 * 2);  // t1 aliases after decoder
    u16* w1hT  = (u16*)alloc((size_t)256 * 512 * 2);
    u16* bfG   = (u16*)alloc((size_t)128 * 256 * 2);    // MFMA-ordered att_w2
    u16* h0b   = (u16*)alloc((size_t)32 * 512 * 2);
    float* zacc = (float*)alloc((size_t)2 * 32 * 528 * 4);  // atomic z exchange
    u16* t1 = wTk4;  // wTk4 dead after decoder; 5.24MB >= 2.93MB
    u16* t2 = pre1;  // pre1 dead after decoder; 3.21MB >= 2.93MB

    u16* c_a     = conv + 0;
    u16* c_h0    = conv + 3211264;
    u16* c_c0    = conv + 3227648;
    u16* c_attw1 = conv + 3244032;
    u16* c_attb1 = conv + 3506176;
    u16* c_attw2 = conv + 3506432;
    u16* c_attb2 = conv + 3539200;
    u16* c_attw3 = conv + 3539328;
    u16* c_wih   = conv + 3539456;
    u16* c_whh   = conv + 5112320;
    u16* c_bih   = conv + 6160896;
    u16* c_bhh   = conv + 6162944;
    u16* c_emb   = conv + 6164992;
    u16* c_ow1   = conv + 6296064;
    u16* c_ob1   = conv + 6754304;
    u16* c_ow2   = conv + 6754664;
    u16* c_ob2   = conv + 6882832;
    u16* c_ow3   = conv + 6883192;
    u16* c_ob3   = conv + 7066488;

    ConvPtrs cp;
    {
        const int idx[19] = {0, 1, 2, 4, 5, 6, 7, 8, 10, 11, 12, 13, 14, 15, 16, 17, 18, 19, 20};
        for (int i = 0; i < 19; ++i) cp.p[i] = d_in[idx[i]];
    }

    detect_kernel<<<1, 64, 0, stream>>>((const u16*)d_in[4], flg, bars);
    conv_kernel<<<6902, 256, 0, stream>>>(cp, flg, conv);
    prep_kernel<<<2432, 256, 0, stream>>>(c_wih, c_whh, c_attw1, c_attw2, wTk4, w1hT, bfG);
    embed_kernel<<<1024, 256, 0, stream>>>(y, c_emb, hze);
    gemm_kernel<false, 1><<<dim3(4, 49), 256, 0, stream>>>(
        c_a, 512, c_attw1, 256, c_attb1, pre1, 256, 6272, 256, 512, flg);

    DecArgs g;
    g.h0 = c_h0; g.c0 = c_c0; g.pre1 = pre1; g.bfG = bfG; g.att_b2 = c_attb2;
    g.att_w3 = c_attw3; g.w1hT = w1hT; g.wT = wTk4; g.bih = c_bih; g.bhh = c_bhh;
    g.a = c_a; g.hze = hze; g.h0b = h0b; g.zacc = zacc; g.bars = bars;
    decoder_kernel<<<GRID_, 512, 0, stream>>>(g);

    gemm_kernel<true, 1><<<dim3(6, 32), 256, 0, stream>>>(
        hze, 1280, c_ow1, 358, c_ob1, t1, 358, 4096, 358, 1280, flg);
    gemm_kernel<true, 1><<<dim3(6, 32), 256, 0, stream>>>(
        t1, 358, c_ow2, 358, c_ob2, t2, 358, 4096, 358, 358, flg);
    gemm_kernel<false, 2><<<dim3(8, 32), 256, 0, stream>>>(
        t2, 358, c_ow3, 512, c_ob3, d_out, 512, 4096, 512, 358, flg);
}

// Round 12
// 2054.907 us; speedup vs baseline: 2.4378x; 1.3880x over previous
//
#include <hip/hip_runtime.h>
#include <hip/hip_bf16.h>
#include <cstdint>

#define B_ 32
#define L_ 196
#define D_ 512
#define H_ 512
#define E_ 256
#define T_ 128
#define V_ 512
#define GRID_ 256
#define NBARS 12288
// bars layout (ints): slot(blk)=blk*16 [0..4095] (init grid barrier only);
// ZP slots: 4096 + gb*128 + j*16 (8 slots per group, own cacheline each);
// H  slots: 8192 + gb*128 + j*16.
#define ZPS 4096
#define HS 8192

using u16 = unsigned short;
typedef __attribute__((ext_vector_type(8))) short bfrag8;   // 8 bf16 (4 VGPRs)
typedef __attribute__((ext_vector_type(4))) float f32x4;    // MFMA accumulator

__device__ __forceinline__ float bf2f(u16 u) { return __uint_as_float(((unsigned)u) << 16); }
__device__ __forceinline__ u16 f2bf(float f) {
    unsigned u = __float_as_uint(f);
    return (u16)((u + 0x7FFFu + ((u >> 16) & 1u)) >> 16);
}
__device__ __forceinline__ float2 bfp(unsigned u) {
    return make_float2(__uint_as_float(u << 16), __uint_as_float(u & 0xffff0000u));
}
__device__ __forceinline__ float sigm(float x) { return 1.f / (1.f + __expf(-x)); }
__device__ __forceinline__ float tanh_fast(float x) { return 1.f - 2.f / (__expf(2.f * x) + 1.f); }

// v_dot2_f32_bf16: acc += a.lo*b.lo + a.hi*b.hi (bf16 pairs, f32 accumulate).
__device__ __forceinline__ void dot2bf(float& acc, unsigned a, unsigned b) {
    asm("v_dot2_f32_bf16 %0, %1, %2, %0" : "+v"(acc) : "v"(a), "v"(b));
}

// --- coherent (cache-bypass) payload access: relaxed agent-scope atomics.
__device__ __forceinline__ float ldcf(const float* p) {
    return __hip_atomic_load((float*)p, __ATOMIC_RELAXED, __HIP_MEMORY_SCOPE_AGENT);
}
__device__ __forceinline__ int ldci(const int* p) {
    return __hip_atomic_load((int*)p, __ATOMIC_RELAXED, __HIP_MEMORY_SCOPE_AGENT);
}
__device__ __forceinline__ unsigned ldc32(const void* p) {
    return __hip_atomic_load((unsigned*)p, __ATOMIC_RELAXED, __HIP_MEMORY_SCOPE_AGENT);
}
__device__ __forceinline__ double ldc64(const void* p) {
    return __hip_atomic_load((double*)p, __ATOMIC_RELAXED, __HIP_MEMORY_SCOPE_AGENT);
}
__device__ __forceinline__ void stcf(float* p, float v) {
    __hip_atomic_store(p, v, __ATOMIC_RELAXED, __HIP_MEMORY_SCOPE_AGENT);
}
__device__ __forceinline__ void stci(int* p, int v) {
    __hip_atomic_store(p, v, __ATOMIC_RELAXED, __HIP_MEMORY_SCOPE_AGENT);
}
__device__ __forceinline__ void stcu(unsigned* p, unsigned v) {
    __hip_atomic_store(p, v, __ATOMIC_RELAXED, __HIP_MEMORY_SCOPE_AGENT);
}
__device__ __forceinline__ void atadd(float* p, float v) {
    __hip_atomic_fetch_add(p, v, __ATOMIC_RELAXED, __HIP_MEMORY_SCOPE_AGENT);
}

// ---------------- dtype detect + barrier reset ----------------
__global__ void detect_kernel(const u16* __restrict__ w, int* __restrict__ flg,
                              int* __restrict__ bars) {
    for (int i = threadIdx.x; i < NBARS; i += 64) bars[i] = 0;
    if (threadIdx.x == 0) {
        int cnt = 0;
        for (int i = 0; i < 64; ++i) {
            int e = (w[i] >> 7) & 0xFF;
            cnt += (e >= 100 && e <= 130);
        }
        flg[0] = (cnt >= 56) ? 1 : 0;
    }
}

// ---------------- convert all float tensors to internal bf16 ----------------
struct ConvPtrs { const void* p[19]; };

__global__ __launch_bounds__(256) void conv_kernel(ConvPtrs cp, const int* __restrict__ flg,
                                                   u16* __restrict__ dst) {
    constexpr int NT = 19;
    constexpr unsigned off[NT + 1] = {
        0u, 3211264u, 3227648u, 3244032u, 3506176u, 3506432u, 3539200u, 3539328u,
        3539456u, 5112320u, 6160896u, 6162944u, 6164992u, 6296064u, 6754304u,
        6754664u, 6882832u, 6883192u, 7066488u, 7067000u};
    constexpr unsigned realN[NT] = {
        3211264u, 16384u, 16384u, 262144u, 256u, 32768u, 128u, 128u,
        1572864u, 1048576u, 2048u, 2048u, 131072u, 458240u, 358u,
        128164u, 358u, 183296u, 512u};
    unsigned pos = (blockIdx.x * 256u + threadIdx.x) * 4u;
    if (pos >= off[NT]) return;
    int t = 0;
#pragma unroll
    for (int i = 1; i < NT; ++i) t += (pos >= off[i]);
    unsigned local = pos - off[t];
    int bf = flg[0];
    const void* src = cp.p[t];
    u16* d = dst + off[t];
#pragma unroll
    for (int j = 0; j < 4; ++j) {
        unsigned l = local + j;
        u16 v = 0;
        if (l < realN[t]) v = bf ? ((const u16*)src)[l] : f2bf(((const float*)src)[l]);
        d[l] = v;
    }
}

// ---------------- weight prep: wTk4, w1hT, bfragG (MFMA-ordered att_w2) ------
// wTk4 u32 layout: word ((k8*2048 + col)*4 + w) holds bf16 pair (K=k8*8+2w, +1)
// of gate column col. K order: 0..511 z, 512..767 e, 768..1279 h.
// bfragG: mfma_f32_16x16x32_bf16 B-fragment order for att_w2[K=256][N=128]:
// value att_w2[k][n] at ((n>>4)*8 + (k>>5))*64*8 + ((n&15)|(((k&31)>>3)<<4))*8 + (k&7).
__global__ __launch_bounds__(256) void prep_kernel(const u16* __restrict__ w_ih,
                                                   const u16* __restrict__ w_hh,
                                                   const u16* __restrict__ att_w1,
                                                   const u16* __restrict__ att_w2,
                                                   u16* __restrict__ wTk4,
                                                   u16* __restrict__ w1hT,
                                                   u16* __restrict__ bfG) {
    int c = blockIdx.x, t = threadIdx.x;
    if (c < 2048) {
        if (t < 160) {
            unsigned* dst = (unsigned*)wTk4;
#pragma unroll
            for (int w = 0; w < 4; ++w) {
                int k0 = t * 8 + 2 * w;
                unsigned a = (k0 < 768) ? w_ih[(size_t)k0 * 2048 + c]
                                        : w_hh[(size_t)(k0 - 768) * 2048 + c];
                unsigned b = (k0 + 1 < 768) ? w_ih[(size_t)(k0 + 1) * 2048 + c]
                                            : w_hh[(size_t)(k0 + 1 - 768) * 2048 + c];
                dst[((size_t)t * 2048 + c) * 4 + w] = a | (b << 16);
            }
        }
    } else if (c < 2304) {
        int c2 = c - 2048;
#pragma unroll
        for (int i = 0; i < 2; ++i) {
            int k = i * 256 + t;
            w1hT[(size_t)c2 * 512 + k] = att_w1[(size_t)(512 + k) * 256 + c2];
        }
    } else {
        int n = c - 2304;  // att-hidden col 0..127
        int k = t;         // K 0..255
        int idx = ((((n >> 4) * 8 + (k >> 5)) * 64 +
                    ((n & 15) | (((k & 31) >> 3) << 4))) * 8) + (k & 7);
        bfG[idx] = att_w2[(size_t)k * 128 + n];
    }
}

// ---------------- embedding (shifted y) -> hze e-part ----------------
__global__ __launch_bounds__(256) void embed_kernel(const int* __restrict__ y,
                                                    const u16* __restrict__ emb,
                                                    u16* __restrict__ hze) {
    int t = threadIdx.x;
    int row0 = blockIdx.x * 4;
    for (int i = 0; i < 4; ++i) {
        int row = row0 + i;
        int b = row >> 7, tt = row & 127;
        int yin = tt ? y[b * T_ + tt - 1] : 0;
        hze[(size_t)row * 1280 + 1024 + t] = emb[yin * E_ + t];
    }
}

// ---------------- generic tiled GEMM: C = act(A @ Bw + bias) ----------------
template <bool TANH, int OMODE>
__global__ __launch_bounds__(256) void gemm_kernel(const u16* __restrict__ A, int lda,
                                                   const u16* __restrict__ Bw, int ldb,
                                                   const u16* __restrict__ bias,
                                                   void* __restrict__ Cv, int ldc,
                                                   int M, int N, int K,
                                                   const int* __restrict__ flg) {
    __shared__ float As[16][132];
    __shared__ float Bs[16][68];
    int t = threadIdx.x;
    int n0 = blockIdx.x * 64;
    int m0 = blockIdx.y * 128;
    int tx = t & 15, ty = t >> 4;
    float acc[8][4];
#pragma unroll
    for (int i = 0; i < 8; ++i)
#pragma unroll
        for (int j = 0; j < 4; ++j) acc[i][j] = 0.f;

    int ar = t >> 1, akb = (t & 1) * 8;
    int bn = t & 63, bkg = t >> 6;

    for (int k0 = 0; k0 < K; k0 += 16) {
        const u16* Ap = A + (size_t)(m0 + ar) * lda + k0 + akb;
        if (k0 + 16 <= K) {
#pragma unroll
            for (int i = 0; i < 8; ++i) As[akb + i][ar] = bf2f(Ap[i]);
        } else {
#pragma unroll
            for (int i = 0; i < 8; ++i) As[akb + i][ar] = (k0 + akb + i < K) ? bf2f(Ap[i]) : 0.f;
        }
#pragma unroll
        for (int i = 0; i < 4; ++i) {
            int kk = bkg * 4 + i;
            int kg = k0 + kk, ng = n0 + bn;
            Bs[kk][bn] = (kg < K && ng < N) ? bf2f(Bw[(size_t)kg * ldb + ng]) : 0.f;
        }
        __syncthreads();
#pragma unroll
        for (int kk = 0; kk < 16; ++kk) {
            float4 aA = *(const float4*)&As[kk][ty * 8];
            float4 aB = *(const float4*)&As[kk][ty * 8 + 4];
            float4 bv = *(const float4*)&Bs[kk][tx * 4];
            float av[8] = {aA.x, aA.y, aA.z, aA.w, aB.x, aB.y, aB.z, aB.w};
            float bb[4] = {bv.x, bv.y, bv.z, bv.w};
#pragma unroll
            for (int i = 0; i < 8; ++i)
#pragma unroll
                for (int j = 0; j < 4; ++j) acc[i][j] += av[i] * bb[j];
        }
        __syncthreads();
    }
    int obf = (OMODE == 2) ? flg[0] : 1;
    float bb[4];
#pragma unroll
    for (int j = 0; j < 4; ++j) {
        int n = n0 + tx * 4 + j;
        bb[j] = (n < N) ? bf2f(bias[n]) : 0.f;
    }
#pragma unroll
    for (int i = 0; i < 8; ++i) {
        int m = m0 + ty * 8 + i;
#pragma unroll
        for (int j = 0; j < 4; ++j) {
            int n = n0 + tx * 4 + j;
            if (n < N) {
                float v = acc[i][j] + bb[j];
                if (TANH) v = tanhf(v);
                if (OMODE == 1 || obf)
                    ((u16*)Cv)[(size_t)m * ldc + n] = f2bf(v);
                else
                    ((float*)Cv)[(size_t)m * ldc + n] = v;
            }
        }
    }
}

// ---------------- persistent decoder ----------------
struct DecArgs {
    const u16 *h0, *c0, *pre1, *bfG, *att_b2, *att_w3, *w1hT, *wT, *bih, *bhh, *a;
    u16 *hze, *h0b;
    float *zacc;  // [2 parities][32 groups][528]: 512 z-numerator + den (atomicAdd)
    float *htp;   // [32 groups][8 blocks][256]: producer-side hterm partials
    int* bars;
};

// Init-only grid barrier: all-poll (512 threads poll 256 slots, duplicated).
__device__ __forceinline__ void gridbar(int* bars, int blk, int t, int epoch) {
    __syncthreads();
    if (t == 0) stci(&bars[blk << 4], epoch);
    for (;;) {
        int v = ldci(&bars[(t & 255) << 4]);
        if (__syncthreads_count(v < epoch) == 0) break;
        __builtin_amdgcn_s_sleep(2);
    }
}

// Group barrier (8 blocks, one per XCD), all-poll slot form: each block stores
// its epoch to its OWN cacheline (8 parallel stores, no serialized fetch_add
// chain on one line); 8 threads poll the 8 slots. Payload safety: gpost's
// __syncthreads drains vmcnt before the slot store.
__device__ __forceinline__ void gpost(int* bars, int base, int ach, int t, int ep) {
    __syncthreads();
    if (t == 0) stci(&bars[base + (ach << 4)], ep);
}
__device__ __forceinline__ void gwait(int* bars, int base, int t, int ep) {
    for (;;) {
        int v = (t < 8) ? ldci(&bars[base + (t << 4)]) : ep;
        if (__syncthreads_count(v < ep) == 0) break;
        __builtin_amdgcn_s_sleep(2);
    }
}

// 512-thread blocks, 2 waves/SIMD. x2 attention GEMM via MFMA. hterm is
// PRODUCER-SIDE: after computing h, each block projects its own 64 h-dims onto
// all 256 att-hidden cols (32 dot2/thread) and stores to its htp slot; next
// step's stage A just sums 8 floats/thread — no hterm GEMV on the critical
// path, no h-staging dependency before the attention pipeline.

__global__ __launch_bounds__(512) void decoder_kernel(DecArgs g) {
    int blk = blockIdx.x, t = threadIdx.x;
    int tt = t & 255, half = t >> 8;
    __shared__ u16 bfl[8 * 8 * 64 * 8];  // 64KB B-fragments (8 N-tiles x 8 K-tiles)
    __shared__ u16 afl[2 * 8 * 64 * 8];  // 16KB A-fragments (2 M-tiles x 8 K-tiles)
    __shared__ float part2[32][9];       // per-wave score partials
    __shared__ float bsh[256];
    __shared__ unsigned hsp[256];   // h(t-1) packed bf16 pairs (for h-gate GEMV)
    __shared__ unsigned einp[128];  // e_t packed pairs
    __shared__ unsigned zinp[256];  // z_t packed pairs
    __shared__ float htf[256];      // summed hterm (per att-hidden col)
    __shared__ unsigned hpks[32];   // h(t) packed pairs (own 64 dims)
    __shared__ float gacc2[2][4][66];  // gate partials per K-half
    __shared__ float hsh[64];
    __shared__ float esh[28];       // exp(score) for this block's rows
    __shared__ float dsh[8];        // denominator broadcast

    int ab = blk >> 3;   // batch (group of 8 consecutive blocks, one per XCD)
    int ach = blk & 7;   // hidden-dim slice == XCD id (weight L2 locality)
    int zbase = ZPS + ab * 128, hbase = HS + ab * 128;

    // stage B-fragments (linear 64KB copy) + zero A-fragments
    {
        uint4* bd = (uint4*)bfl;
        const uint4* bs = (const uint4*)g.bfG;
#pragma unroll
        for (int i = 0; i < 16; ++i) bd[t + 512 * i] = bs[t + 512 * i];
        uint4 z4 = {0u, 0u, 0u, 0u};
        ((uint4*)afl)[t] = z4;
        ((uint4*)afl)[t + 512] = z4;
    }
    // per-lane attention epilogue constants: col = wave*16 + (lane&15)
    int lane = t & 63, wv8 = t >> 6;
    int colA = wv8 * 16 + (lane & 15);
    float b2r = bf2f(g.att_b2[colA]);
    float w3r = bf2f(g.att_w3[colA]);

    // gate column for this thread's half: col, K-half = half.
    int col = (tt >> 6) * 512 + ach * 64 + (tt & 63);
    if (half == 0) bsh[tt] = bf2f(g.bih[col]) + bf2f(g.bhh[col]);
    float creg = (t < 64) ? bf2f(g.c0[ab * 512 + ach * 64 + t]) : 0.f;

    if (blk < 32 && t < 256) {
        unsigned pk = (unsigned)g.h0[blk * 512 + 2 * t] |
                      ((unsigned)g.h0[blk * 512 + 2 * t + 1] << 16);
        stcu((unsigned*)(g.h0b + blk * 512 + 2 * t), pk);
    }
    // zero both zacc parities for this block's dim slice (+ den by ach 0)
    {
        float* z0 = g.zacc + (size_t)ab * 528;
        float* z1 = g.zacc + (size_t)(32 + ab) * 528;
        if (t < 64) {
            stcf(z0 + ach * 64 + t, 0.f);
            stcf(z1 + ach * 64 + t, 0.f);
        }
        if (t == 64 && ach == 0) {
            stcf(z0 + 512, 0.f);
            stcf(z1 + 512, 0.f);
        }
    }

    int anrows = (ach == 7) ? 21 : 25;
    int arow0 = ab * 196 + ach * 25;
    int c2l = (t & 127) * 2, rq = (t >> 7) * 7;  // column-pair / row-quarter split

    // w1h slice regs: col tt (t<256), own K dims [ach*64, +64) as 32 bf16 pairs.
    unsigned w1hr[32];
    if (t < 256) {
#pragma unroll
        for (int i = 0; i < 32; ++i)
            w1hr[i] = *(const unsigned*)(g.w1hT + (size_t)t * 512 + ach * 64 + 2 * i);
    }
    // seed htp slot from h0 (step-0 hterm contribution of our 64 dims)
    if (t < 256) {
        float s = 0.f;
#pragma unroll
        for (int i = 0; i < 32; ++i) {
            unsigned hp = *(const unsigned*)(g.h0 + ab * 512 + ach * 64 + 2 * i);
            dot2bf(s, hp, w1hr[i]);
        }
        stcf(g.htp + ((size_t)(ab * 8 + ach) << 8) + t, s);
    }

    // step-invariant register caches: pre1 (7 rows x 2 adjacent cols packed)
    // and areg2: a[row, dims 2tt..2tt+1] for this block's 25 rows (t<256 only).
    unsigned p1p[7];
#pragma unroll
    for (int i = 0; i < 7; ++i) {
        int r = min(arow0 + rq + i, 6271);
        unsigned lo = g.pre1[(size_t)r * 256 + c2l];
        unsigned hi = g.pre1[(size_t)r * 256 + c2l + 1];
        p1p[i] = lo | (hi << 16);
    }
    unsigned areg2[25];
    if (t < 256) {
#pragma unroll
        for (int r = 0; r < 25; ++r) {
            int rr = min(arow0 + r, 6271);  // clamped rows have esh==0 (no effect)
            areg2[r] = *(const unsigned*)(g.a + (size_t)rr * 512 + 2 * t);
        }
    }
    gridbar(g.bars, blk, t, 1);  // h0b + zacc zeros + htp seeds visible

    const uint4* wb = (const uint4*)g.wT;  // wTk4
    float acc4[4] = {0.f, 0.f, 0.f, 0.f};

    // afrag producer constants (k-pair c2l): lane-high and j within fragment
    int af_kt = c2l >> 5, af_lhi = ((c2l & 31) >> 3) << 4, af_jp = (c2l & 7) >> 1;

    // prologue: e-GEMV for step 0 (e is static); K-half split.
    if (t < 128) einp[t] = *(const unsigned*)(g.hze + (size_t)ab * T_ * 1280 + 1024 + 2 * t);
    __syncthreads();
#pragma unroll 4
    for (int k8 = 0; k8 < 16; ++k8) {
        int ke = half * 16 + k8;
        uint4 wv = wb[(size_t)(64 + ke) * 2048 + col];
        uint4 iv = *(const uint4*)&einp[ke * 4];
        dot2bf(acc4[0], iv.x, wv.x);
        dot2bf(acc4[1], iv.y, wv.y);
        dot2bf(acc4[2], iv.z, wv.z);
        dot2bf(acc4[3], iv.w, wv.w);
    }

    for (int step = 0; step < T_; ++step) {
        int ep = step + 1;
        size_t row = (size_t)ab * T_ + step;
        const u16* hz = g.hze + row * 1280;
        // zero the other zacc parity for step+2 (safe: all reads finished
        // before the h-bar we just passed).
        if (step) {
            float* zn = g.zacc + (size_t)(((step + 1) & 1) * 32 + ab) * 528;
            if (t < 64) stcf(zn + ach * 64 + t, 0.f);
            if (t == 64 && ach == 0) stcf(zn + 512, 0.f);
        }
        // ================= stage A: hterm sum + attention pipeline ============
        const u16* hsrcA = step ? (g.hze + (row - 1) * 1280) : (g.h0b + ab * 512);
        if (t < 256) hsp[t] = ldc32(hsrcA + 2 * t);  // consumed post-ZP (h-GEMV)
        if (t < 256) {
            const float* hp = g.htp + ((size_t)(ab * 8) << 8) + t;
            float s = 0.f;
#pragma unroll
            for (int j = 0; j < 8; ++j) s += ldcf(hp + (j << 8));
            htf[t] = s;
        }
        __syncthreads();
        // producers: x1 = tanh(pre1 + hterm) -> A-fragments (bf16 pairs)
        {
            float hv0 = htf[c2l], hv1 = htf[c2l + 1];
            unsigned* af32 = (unsigned*)afl;
#pragma unroll
            for (int i = 0; i < 7; ++i) {
                int r = rq + i;
                if (r < anrows) {
                    float2 pv = bfp(p1p[i]);
                    unsigned pk = (unsigned)f2bf(tanh_fast(pv.x + hv0)) |
                                  ((unsigned)f2bf(tanh_fast(pv.y + hv1)) << 16);
                    int mt = r >> 4;
                    af32[((mt * 8 + af_kt) * 64 + ((r & 15) | af_lhi)) * 4 + af_jp] = pk;
                }
            }
        }
        __syncthreads();
        // x2 GEMM via MFMA: wave wv8 owns N-tile wv8 (16 cols), both M-tiles.
        {
            f32x4 acc0 = {0.f, 0.f, 0.f, 0.f};
            f32x4 acc1 = {0.f, 0.f, 0.f, 0.f};
            const bfrag8* bp = (const bfrag8*)bfl;
            const bfrag8* ap = (const bfrag8*)afl;
#pragma unroll
            for (int kt = 0; kt < 8; ++kt) {
                bfrag8 bv = bp[(wv8 * 8 + kt) * 64 + lane];
                bfrag8 a0 = ap[kt * 64 + lane];
                bfrag8 a1 = ap[(8 + kt) * 64 + lane];
                acc0 = __builtin_amdgcn_mfma_f32_16x16x32_bf16(a0, bv, acc0, 0, 0, 0);
                acc1 = __builtin_amdgcn_mfma_f32_16x16x32_bf16(a1, bv, acc1, 0, 0, 0);
            }
#pragma unroll
            for (int q = 0; q < 4; ++q) {
                float p0 = tanh_fast(acc0[q] + b2r) * w3r;
                float p1 = tanh_fast(acc1[q] + b2r) * w3r;
#pragma unroll
                for (int off = 1; off < 16; off <<= 1) {
                    p0 += __shfl_xor(p0, off);
                    p1 += __shfl_xor(p1, off);
                }
                if ((lane & 15) == 0) {
                    int r0 = (lane >> 4) * 4 + q;
                    part2[r0][wv8] = p0;
                    part2[16 + r0][wv8] = p1;
                }
            }
        }
        __syncthreads();
        // scores -> exp (no max: |s| bounded ~2; softmax shift-invariant)
        if (t < 25) {
            if (t < anrows) {
                const float* pr = part2[t];
                float s = ((pr[0] + pr[1]) + (pr[2] + pr[3])) +
                          ((pr[4] + pr[5]) + (pr[6] + pr[7]));
                esh[t] = __expf(s);
            } else {
                esh[t] = 0.f;
            }
        }
        __syncthreads();
        // partial z numerator (dims 2t, 2t+1) + denominator -> zacc atomicAdd
        if (t < 256) {
            float zpx = 0.f, zpy = 0.f, dp = 0.f;
#pragma unroll
            for (int r = 0; r < 25; ++r) {
                float er = esh[r];
                float2 av = bfp(areg2[r]);
                zpx += er * av.x;
                zpy += er * av.y;
                dp += er;
            }
            float* za = g.zacc + (size_t)((step & 1) * 32 + ab) * 528;
            atadd(za + 2 * t, zpx);
            atadd(za + 2 * t + 1, zpy);
            if (t == 0) atadd(za + 512, dp);
        }
        // --- ZP-bar post (slot store; atomics drained by gpost's syncthreads) ---
        gpost(g.bars, zbase, ach, t, ep);
        // --- hidden work: gate-GEMV h segment, K-half split ---
#pragma unroll 4
        for (int k8 = 0; k8 < 32; ++k8) {
            int kh = half * 32 + k8;
            uint4 wv = wb[(size_t)(96 + kh) * 2048 + col];
            uint4 iv = *(const uint4*)&hsp[kh * 4];
            dot2bf(acc4[0], iv.x, wv.x);
            dot2bf(acc4[1], iv.y, wv.y);
            dot2bf(acc4[2], iv.z, wv.z);
            dot2bf(acc4[3], iv.w, wv.w);
        }
        // prefetch first 8 z-GEMV weight vectors (hides L2 latency behind wait)
        uint4 wz[8];
#pragma unroll
        for (int k8 = 0; k8 < 8; ++k8)
            wz[k8] = wb[(size_t)(half * 32 + k8) * 2048 + col];
        // --- ZP-bar wait ---
        gwait(g.bars, zbase, t, ep);
        // ================= stage B: read combined zacc -> z ===================
        {
            const float* za = g.zacc + (size_t)((step & 1) * 32 + ab) * 528;
            if (t == 0) dsh[0] = ldcf(za + 512);
            float zx = 0.f, zy = 0.f;
            if (t < 256) {
                union { double d; float2 f; } u;
                u.d = ldc64(za + 2 * t);
                zx = u.f.x;
                zy = u.f.y;
            }
            __syncthreads();
            if (t < 256) {
                float inv = 1.f / dsh[0];
                unsigned pk = (unsigned)f2bf(zx * inv) | ((unsigned)f2bf(zy * inv) << 16);
                zinp[t] = pk;
                if ((t >> 5) == ach) stcu((unsigned*)(hz + 512 + 2 * t), pk);
            }
        }
        __syncthreads();
        // ================= stage C: z-segment GEMV + LSTM update ==============
#pragma unroll
        for (int k8 = 0; k8 < 8; ++k8) {
            uint4 wv = wz[k8];
            uint4 iv = *(const uint4*)&zinp[(half * 32 + k8) * 4];
            dot2bf(acc4[0], iv.x, wv.x);
            dot2bf(acc4[1], iv.y, wv.y);
            dot2bf(acc4[2], iv.z, wv.z);
            dot2bf(acc4[3], iv.w, wv.w);
        }
#pragma unroll 4
        for (int k8 = 8; k8 < 32; ++k8) {
            int kz = half * 32 + k8;
            uint4 wv = wb[(size_t)kz * 2048 + col];
            uint4 iv = *(const uint4*)&zinp[kz * 4];
            dot2bf(acc4[0], iv.x, wv.x);
            dot2bf(acc4[1], iv.y, wv.y);
            dot2bf(acc4[2], iv.z, wv.z);
            dot2bf(acc4[3], iv.w, wv.w);
        }
        gacc2[half][tt >> 6][tt & 63] = (acc4[0] + acc4[1]) + (acc4[2] + acc4[3]);
        __syncthreads();
        if (t < 64) {
            float gg[4];
#pragma unroll
            for (int q = 0; q < 4; ++q)
                gg[q] = gacc2[0][q][t] + gacc2[1][q][t] + bsh[q * 64 + t];
            float gi = sigm(gg[0]), gf = sigm(gg[1]);
            float gn = tanh_fast(gg[2]), go = sigm(gg[3]);
            float cn = gf * creg + gi * gn;
            creg = cn;  // c-state lives in a register (block-private)
            hsh[t] = go * tanh_fast(cn);
        }
        __syncthreads();
        if (t < 32) {
            unsigned pk = (unsigned)f2bf(hsh[2 * t]) | ((unsigned)f2bf(hsh[2 * t + 1]) << 16);
            stcu((unsigned*)(hz + ach * 64 + 2 * t), pk);
            hpks[t] = pk;
        }
        // --- h-bar window: producer-side hterm + next e-GEMV; skip last step ---
        if (step + 1 < T_) {
            __syncthreads();  // hpks + h stores staged
            // hterm partial for step+1: project own 64 h-dims onto col tt
            if (t < 256) {
                float s = 0.f;
#pragma unroll
                for (int i = 0; i < 32; ++i) dot2bf(s, hpks[i], w1hr[i]);
                stcf(g.htp + ((size_t)(ab * 8 + ach) << 8) + t, s);
            }
            gpost(g.bars, hbase, ach, t, ep);  // syncthreads drains stcf + h stores
#pragma unroll
            for (int i = 0; i < 4; ++i) acc4[i] = 0.f;
            if (t < 128) einp[t] = *(const unsigned*)(hz + 1280 + 1024 + 2 * t);
            __syncthreads();
#pragma unroll 4
            for (int k8 = 0; k8 < 16; ++k8) {
                int ke = half * 16 + k8;
                uint4 wv = wb[(size_t)(64 + ke) * 2048 + col];
                uint4 iv = *(const uint4*)&einp[ke * 4];
                dot2bf(acc4[0], iv.x, wv.x);
                dot2bf(acc4[1], iv.y, wv.y);
                dot2bf(acc4[2], iv.z, wv.z);
                dot2bf(acc4[3], iv.w, wv.w);
            }
            gwait(g.bars, hbase, t, ep);
        }
    }
}

extern "C" void kernel_launch(void* const* d_in, const int* in_sizes, int n_in,
                              void* d_out, int out_size, void* d_ws, size_t ws_size,
                              hipStream_t stream) {
    (void)in_sizes; (void)n_in; (void)out_size; (void)ws_size;
    const int* y = (const int*)d_in[3];

    char* base = (char*)d_ws;
    size_t off = 0;
    auto alloc = [&](size_t bytes) {
        void* p = base + off;
        off = (off + bytes + 63) & ~(size_t)63;
        return p;
    };
    // Total footprint ~33.9 MB — must stay <= 34.34 MB (round-2 proven bound).
    int* flg   = (int*)alloc(64);
    int* bars  = (int*)alloc(NBARS * 4);
    u16* conv  = (u16*)alloc((size_t)7067000 * 2);
    u16* pre1  = (u16*)alloc((size_t)6272 * 256 * 2);   // t2 aliases after decoder
    u16* hze   = (u16*)alloc((size_t)4096 * 1280 * 2);
    u16* wTk4  = (u16*)alloc((size_t)2048 * 1280 * 2);  // t1 aliases after decoder
    u16* w1hT  = (u16*)alloc((size_t)256 * 512 * 2);
    u16* bfG   = (u16*)alloc((size_t)128 * 256 * 2);    // MFMA-ordered att_w2
    u16* h0b   = (u16*)alloc((size_t)32 * 512 * 2);
    float* zacc = (float*)alloc((size_t)2 * 32 * 528 * 4);  // atomic z exchange
    float* htpg = (float*)alloc((size_t)32 * 8 * 256 * 4);  // hterm partial slots
    u16* t1 = wTk4;  // wTk4 dead after decoder; 5.24MB >= 2.93MB
    u16* t2 = pre1;  // pre1 dead after decoder; 3.21MB >= 2.93MB

    u16* c_a     = conv + 0;
    u16* c_h0    = conv + 3211264;
    u16* c_c0    = conv + 3227648;
    u16* c_attw1 = conv + 3244032;
    u16* c_attb1 = conv + 3506176;
    u16* c_attw2 = conv + 3506432;
    u16* c_attb2 = conv + 3539200;
    u16* c_attw3 = conv + 3539328;
    u16* c_wih   = conv + 3539456;
    u16* c_whh   = conv + 5112320;
    u16* c_bih   = conv + 6160896;
    u16* c_bhh   = conv + 6162944;
    u16* c_emb   = conv + 6164992;
    u16* c_ow1   = conv + 6296064;
    u16* c_ob1   = conv + 6754304;
    u16* c_ow2   = conv + 6754664;
    u16* c_ob2   = conv + 6882832;
    u16* c_ow3   = conv + 6883192;
    u16* c_ob3   = conv + 7066488;

    ConvPtrs cp;
    {
        const int idx[19] = {0, 1, 2, 4, 5, 6, 7, 8, 10, 11, 12, 13, 14, 15, 16, 17, 18, 19, 20};
        for (int i = 0; i < 19; ++i) cp.p[i] = d_in[idx[i]];
    }

    detect_kernel<<<1, 64, 0, stream>>>((const u16*)d_in[4], flg, bars);
    conv_kernel<<<6902, 256, 0, stream>>>(cp, flg, conv);
    prep_kernel<<<2432, 256, 0, stream>>>(c_wih, c_whh, c_attw1, c_attw2, wTk4, w1hT, bfG);
    embed_kernel<<<1024, 256, 0, stream>>>(y, c_emb, hze);
    gemm_kernel<false, 1><<<dim3(4, 49), 256, 0, stream>>>(
        c_a, 512, c_attw1, 256, c_attb1, pre1, 256, 6272, 256, 512, flg);

    DecArgs g;
    g.h0 = c_h0; g.c0 = c_c0; g.pre1 = pre1; g.bfG = bfG; g.att_b2 = c_attb2;
    g.att_w3 = c_attw3; g.w1hT = w1hT; g.wT = wTk4; g.bih = c_bih; g.bhh = c_bhh;
    g.a = c_a; g.hze = hze; g.h0b = h0b; g.zacc = zacc; g.htp = htpg; g.bars = bars;
    decoder_kernel<<<GRID_, 512, 0, stream>>>(g);

    gemm_kernel<true, 1><<<dim3(6, 32), 256, 0, stream>>>(
        hze, 1280, c_ow1, 358, c_ob1, t1, 358, 4096, 358, 1280, flg);
    gemm_kernel<true, 1><<<dim3(6, 32), 256, 0, stream>>>(
        t1, 358, c_ow2, 358, c_ob2, t2, 358, 4096, 358, 358, flg);
    gemm_kernel<false, 2><<<dim3(8, 32), 256, 0, stream>>>(
        t2, 358, c_ow3, 512, c_ob3, d_out, 512, 4096, 512, 358, flg);
}